// Round 1
// baseline (3662.206 us; speedup 1.0000x reference)
//
#include <hip/hip_runtime.h>
#include <math.h>
#include <stddef.h>

// Problem constants (from reference)
#define BB   4
#define SS   1024
#define DD   1024
#define HH   16
#define HDD  64
#define NT   (BB*SS)      // 4096 tokens
#define MFF  2736
#define EPSF 1e-6f

// ---------------------------------------------------------------------------
// Workspace layout (floats). Total ~43.4M floats = ~166 MB.
// ---------------------------------------------------------------------------
static const size_t OFF_A     = 0;                       // attn_in / attn_out  [NT*DD]
static const size_t OFF_Q     = OFF_A  + (size_t)NT*DD;  // q / mlp_in          [NT*DD]
static const size_t OFF_K     = OFF_Q  + (size_t)NT*DD;  // k                   [NT*DD]
static const size_t OFF_V     = OFF_K  + (size_t)NT*DD;  // v                   [NT*DD]
static const size_t OFF_X2    = OFF_V  + (size_t)NT*DD;  // x + attn residual   [NT*DD]
static const size_t OFF_G     = OFF_X2 + (size_t)NT*DD;  // gate / h            [NT*MFF]
static const size_t OFF_U     = OFF_G  + (size_t)NT*MFF; // up                  [NT*MFF]
static const size_t OFF_VV    = OFF_U  + (size_t)NT*MFF; // power-iter v vecs   [7*2736]
static const size_t OFF_UU    = OFF_VV + 7*2736;         // power-iter u vecs   [7*2736]
static const size_t OFF_ACC   = OFF_UU + 7*2736;         // norm^2 accumulators [7*12] (pad 96)
static const size_t OFF_SCALE = OFF_ACC + 96;            // sigma_p/sigma       [7]

// ---------------------------------------------------------------------------
// Power iteration: fused across the 7 weight matrices.
// Matrices (n_in x n_out): 0 wq(1024,1024) 1 wk 2 wv 3 wo(1024,1024)
//                          4 wg(1024,2736) 5 wu(1024,2736) 6 wd(2736,1024)
// step s: even -> v_hat = W @ u_norm ; odd -> u_hat = W^T @ v_norm
// acc[m*12+s] = ||y_hat||^2 for that step; normalization deferred to next step.
// ---------------------------------------------------------------------------
struct PowArgs {
  const float* W[7];
  float* vvec;   // 7 * 2736
  float* uvec;   // 7 * 2736
  float* acc;    // 7 * 12
  int step;
};

__global__ void zero_acc_kernel(float* acc){
  if (threadIdx.x < 96) acc[threadIdx.x] = 0.f;
}

__global__ __launch_bounds__(256) void mv_notrans(PowArgs pa){
  const int NIN [7] = {1024,1024,1024,1024,1024,1024,2736};
  const int NOUT[7] = {1024,1024,1024,1024,2736,2736,1024};
  const int BST [8] = {0,256,512,768,1024,1280,1536,2220};
  int blk = blockIdx.x;
  int m = 0;
  #pragma unroll
  for (int i=1;i<7;i++) if (blk >= BST[i]) m = i;
  int nin = NIN[m], nout = NOUT[m];
  int wave = threadIdx.x >> 6, lane = threadIdx.x & 63;
  int row = (blk - BST[m])*4 + wave;
  if (row >= nin) return;
  const float* W = pa.W[m];
  int st = pa.step;
  float inv;
  const float* x = nullptr;
  if (st == 0){
    inv = 1.f/(sqrtf((float)nout)+EPSF);  // u0 = ones/(||ones||+eps)
  } else {
    inv = 1.f/(sqrtf(pa.acc[m*12+st-1])+EPSF);
    x = pa.uvec + m*2736;
  }
  float sum = 0.f;
  for (int j=lane; j<nout; j+=64){
    float xv = x ? x[j] : 1.f;
    sum += W[(size_t)row*nout + j]*xv;
  }
  #pragma unroll
  for (int off=32; off>=1; off>>=1) sum += __shfl_down(sum, off);
  if (lane == 0){
    float yv = sum*inv;
    pa.vvec[m*2736+row] = yv;
    atomicAdd(&pa.acc[m*12+st], yv*yv);
  }
}

__global__ __launch_bounds__(256) void mv_trans(PowArgs pa){
  const int NIN [7] = {1024,1024,1024,1024,1024,1024,2736};
  const int NOUT[7] = {1024,1024,1024,1024,2736,2736,1024};
  const int BST [8] = {0,4,8,12,16,27,38,42};
  __shared__ float xs[256];
  int blk = blockIdx.x;
  int m = 0;
  #pragma unroll
  for (int i=1;i<7;i++) if (blk >= BST[i]) m = i;
  int nin = NIN[m], nout = NOUT[m];
  int tid = threadIdx.x;
  int col = (blk - BST[m])*256 + tid;
  int st = pa.step;
  float inv = 1.f/(sqrtf(pa.acc[m*12+st-1])+EPSF);
  const float* x = pa.vvec + m*2736;
  const float* W = pa.W[m];
  float sum = 0.f;
  for (int i0=0; i0<nin; i0+=256){
    int ii = i0 + tid;
    xs[tid] = (ii < nin) ? x[ii] : 0.f;
    __syncthreads();
    int lim = nin - i0; if (lim > 256) lim = 256;
    if (col < nout){
      for (int i=0;i<lim;i++) sum += W[(size_t)(i0+i)*nout + col]*xs[i];
    }
    __syncthreads();
  }
  float yv = (col < nout) ? sum*inv : 0.f;
  if (col < nout) pa.uvec[m*2736+col] = yv;
  float sq = yv*yv;
  #pragma unroll
  for (int off=32; off>=1; off>>=1) sq += __shfl_down(sq, off);
  if ((tid & 63) == 0) atomicAdd(&pa.acc[m*12+st], sq);
}

struct SigArgs {
  float* acc; float* scale;
  const float* sp[7];
};
__global__ void sigma_scale_kernel(SigArgs sa){
  int m = threadIdx.x;
  if (m < 7){
    float a = sa.acc[m*12+10];          // ||W u_final||^2
    float S = sqrtf(a);
    float sig = a/(S+EPSF);             // v . (W u), v = Wu/(||Wu||+eps)
    sig = fmaxf(sig, EPSF);
    sa.scale[m] = sa.sp[m][0]/sig;
  }
}

// ---------------------------------------------------------------------------
// RMSNorm over D=1024 (one block = one row)
// ---------------------------------------------------------------------------
__global__ __launch_bounds__(256) void rmsnorm_row(const float* __restrict__ in,
                                                   const float* __restrict__ scale,
                                                   float* __restrict__ out){
  int row = blockIdx.x;
  int tid = threadIdx.x;
  const float* p = in + (size_t)row*DD;
  float4 vx = *(const float4*)(p + tid*4);
  float ss = vx.x*vx.x + vx.y*vx.y + vx.z*vx.z + vx.w*vx.w;
  int lane = tid & 63, wave = tid >> 6;
  #pragma unroll
  for (int off=32; off>=1; off>>=1) ss += __shfl_down(ss, off);
  __shared__ float red[4];
  if (lane == 0) red[wave] = ss;
  __syncthreads();
  float tot = red[0]+red[1]+red[2]+red[3];
  float r = rsqrtf(tot*(1.f/DD)+EPSF);
  float4 sc = *(const float4*)(scale + tid*4);
  float4 o;
  o.x = vx.x*r*sc.x; o.y = vx.y*r*sc.y; o.z = vx.z*r*sc.z; o.w = vx.w*r*sc.w;
  *(float4*)(out + (size_t)row*DD + tid*4) = o;
}

// ---------------------------------------------------------------------------
// Per-head RMSNorm over HD=64 (one wave = one row), in-place
// ---------------------------------------------------------------------------
__global__ __launch_bounds__(256) void headnorm(float* __restrict__ p,
                                                const float* __restrict__ scale,
                                                int nrows){
  int wave = threadIdx.x >> 6, lane = threadIdx.x & 63;
  int row = blockIdx.x*4 + wave;
  if (row >= nrows) return;
  float v = p[(size_t)row*HDD + lane];
  float ss = v*v;
  #pragma unroll
  for (int off=32; off>=1; off>>=1) ss += __shfl_down(ss, off);
  ss = __shfl(ss, 0);
  float r = rsqrtf(ss*(1.f/HDD)+EPSF);
  p[(size_t)row*HDD + lane] = v*r*scale[lane];
}

// ---------------------------------------------------------------------------
// Generic fp32 GEMM:  C[M,N] = scale*(A[M,K]@B[K,N]) + bias[N] (+ resid)
// M = 4096 (multiple of 128). N,K arbitrary with N-edge guards, K%8==0.
// 128x128 tile, 256 threads, 8x8 microtile (cols split tx*4 and 64+tx*4).
// ---------------------------------------------------------------------------
template<bool RESID>
__global__ __launch_bounds__(256) void gemm_f32(const float* __restrict__ A,
                                                const float* __restrict__ B,
                                                float* __restrict__ C,
                                                const float* __restrict__ bias,
                                                const float* __restrict__ scalePtr,
                                                const float* __restrict__ resid,
                                                int Nd, int Kd){
  __shared__ float As[8][128];   // [k][m] (transposed on store)
  __shared__ float Bs[8][128];   // [k][n]
  int tid = threadIdx.x;
  int bm = blockIdx.y*128, bn = blockIdx.x*128;
  int ty = tid >> 4, tx = tid & 15;
  float acc[8][8];
  #pragma unroll
  for (int i=0;i<8;i++)
    #pragma unroll
    for (int j=0;j<8;j++) acc[i][j] = 0.f;

  int ar = tid >> 1, ac = (tid & 1)*4;     // A stage: 2 threads/row
  int br = tid >> 5, bc = (tid & 31)*4;    // B stage: 32 threads/row
  const float* Ap  = A + (size_t)(bm+ar)*Kd + ac;
  int bCol = bn + bc;
  const float* Bp0 = B + bCol;

  for (int k0=0; k0<Kd; k0+=8){
    float4 av = *(const float4*)(Ap + k0);
    const float* Bp = Bp0 + (size_t)(k0+br)*Nd;
    float4 bv;
    if (bCol+3 < Nd){
      bv = *(const float4*)Bp;
    } else {
      bv.x = (bCol+0<Nd)?Bp[0]:0.f;
      bv.y = (bCol+1<Nd)?Bp[1]:0.f;
      bv.z = (bCol+2<Nd)?Bp[2]:0.f;
      bv.w = (bCol+3<Nd)?Bp[3]:0.f;
    }
    __syncthreads();
    As[ac+0][ar]=av.x; As[ac+1][ar]=av.y; As[ac+2][ar]=av.z; As[ac+3][ar]=av.w;
    *(float4*)&Bs[br][bc] = bv;
    __syncthreads();
    #pragma unroll
    for (int kk=0;kk<8;kk++){
      float4 a0 = *(const float4*)&As[kk][ty*8];
      float4 a1 = *(const float4*)&As[kk][ty*8+4];
      float4 b0 = *(const float4*)&Bs[kk][tx*4];
      float4 b1 = *(const float4*)&Bs[kk][64+tx*4];
      float a[8] = {a0.x,a0.y,a0.z,a0.w,a1.x,a1.y,a1.z,a1.w};
      float b[8] = {b0.x,b0.y,b0.z,b0.w,b1.x,b1.y,b1.z,b1.w};
      #pragma unroll
      for (int i=0;i<8;i++)
        #pragma unroll
        for (int j=0;j<8;j++)
          acc[i][j] += a[i]*b[j];
    }
  }

  float scale = *scalePtr;
  int j0 = bn + tx*4, j1 = bn + 64 + tx*4;
  #pragma unroll
  for (int i=0;i<8;i++){
    size_t rowoff = (size_t)(bm + ty*8 + i)*Nd;
    #pragma unroll
    for (int half=0; half<2; half++){
      int j = half ? j1 : j0;
      const float* ap = &acc[i][half*4];
      if (j+3 < Nd){
        float4 bsv = *(const float4*)&bias[j];
        float4 r4;
        r4.x = scale*ap[0] + bsv.x;
        r4.y = scale*ap[1] + bsv.y;
        r4.z = scale*ap[2] + bsv.z;
        r4.w = scale*ap[3] + bsv.w;
        if (RESID){
          float4 rv = *(const float4*)&resid[rowoff + j];
          r4.x += rv.x; r4.y += rv.y; r4.z += rv.z; r4.w += rv.w;
        }
        *(float4*)&C[rowoff + j] = r4;
      } else {
        #pragma unroll
        for (int c=0;c<4;c++){
          if (j+c < Nd){
            float vvv = scale*ap[c] + bias[j+c];
            if (RESID) vvv += resid[rowoff + j + c];
            C[rowoff + j + c] = vvv;
          }
        }
      }
    }
  }
}

// ---------------------------------------------------------------------------
// Flash-style fp32 attention with tanh softcap.
// Softcap bounds logits to +-50, so exp() cannot overflow -> no online max.
// Block = (qtile=64 rows) x (head) x (batch). 256 threads, 4x4 microtiles.
// ---------------------------------------------------------------------------
__global__ __launch_bounds__(256) void attn_f32(const float* __restrict__ q,
                                                const float* __restrict__ k,
                                                const float* __restrict__ v,
                                                float* __restrict__ o){
  int qt = blockIdx.x, h = blockIdx.y, b = blockIdx.z;
  __shared__ float Qs[64][68];   // [hd][row]
  __shared__ float Bs[64][68];   // K: [hd][col] ; V: [row][hd]
  __shared__ float Ps[64][68];   // [col][row]
  int tid = threadIdx.x;
  int ty = tid >> 4, tx = tid & 15;
  int lr = tid >> 2, lc = (tid & 3)*16;

  const float* qbase = q + ((size_t)(b*SS + qt*64 + lr)*HH + h)*HDD;
  #pragma unroll
  for (int i=0;i<4;i++){
    float4 t = *(const float4*)(qbase + lc + i*4);
    Qs[lc+i*4+0][lr]=t.x; Qs[lc+i*4+1][lr]=t.y; Qs[lc+i*4+2][lr]=t.z; Qs[lc+i*4+3][lr]=t.w;
  }

  float acc[4][4] = {{0.f}};
  float lsum[4] = {0.f,0.f,0.f,0.f};

  for (int kt=0; kt<SS/64; kt++){
    __syncthreads();   // prev PV done; Bs free
    const float* kbase = k + ((size_t)(b*SS + kt*64 + lr)*HH + h)*HDD;
    #pragma unroll
    for (int i=0;i<4;i++){
      float4 t = *(const float4*)(kbase + lc + i*4);
      Bs[lc+i*4+0][lr]=t.x; Bs[lc+i*4+1][lr]=t.y; Bs[lc+i*4+2][lr]=t.z; Bs[lc+i*4+3][lr]=t.w;
    }
    __syncthreads();

    // S = Q @ K^T  (64x64, k-dim = HD)
    float s[4][4] = {{0.f}};
    #pragma unroll 8
    for (int kk=0; kk<64; kk++){
      float4 a  = *(const float4*)&Qs[kk][ty*4];
      float4 bb = *(const float4*)&Bs[kk][tx*4];
      s[0][0]+=a.x*bb.x; s[0][1]+=a.x*bb.y; s[0][2]+=a.x*bb.z; s[0][3]+=a.x*bb.w;
      s[1][0]+=a.y*bb.x; s[1][1]+=a.y*bb.y; s[1][2]+=a.y*bb.z; s[1][3]+=a.y*bb.w;
      s[2][0]+=a.z*bb.x; s[2][1]+=a.z*bb.y; s[2][2]+=a.z*bb.z; s[2][3]+=a.z*bb.w;
      s[3][0]+=a.w*bb.x; s[3][1]+=a.w*bb.y; s[3][2]+=a.w*bb.z; s[3][3]+=a.w*bb.w;
    }
    float p[4][4];
    #pragma unroll
    for (int r=0;r<4;r++)
      #pragma unroll
      for (int c=0;c<4;c++){
        float logits = s[r][c]*0.125f;                 // / sqrt(64)
        float pv = __expf(50.f*tanhf(logits*0.02f));   // softcap then exp
        p[r][c] = pv;
        lsum[r] += pv;
      }
    __syncthreads();   // S-GEMM reads of Bs done

    // store P^T, load V
    #pragma unroll
    for (int c=0;c<4;c++){
      float4 pc = make_float4(p[0][c],p[1][c],p[2][c],p[3][c]);
      *(float4*)&Ps[tx*4+c][ty*4] = pc;
    }
    const float* vbase = v + ((size_t)(b*SS + kt*64 + lr)*HH + h)*HDD;
    #pragma unroll
    for (int i=0;i<4;i++){
      float4 t = *(const float4*)(vbase + lc + i*4);
      *(float4*)&Bs[lr][lc+i*4] = t;
    }
    __syncthreads();

    // O += P @ V (k-dim = 64 key positions)
    #pragma unroll 8
    for (int jj=0; jj<64; jj++){
      float4 a  = *(const float4*)&Ps[jj][ty*4];
      float4 bb = *(const float4*)&Bs[jj][tx*4];
      acc[0][0]+=a.x*bb.x; acc[0][1]+=a.x*bb.y; acc[0][2]+=a.x*bb.z; acc[0][3]+=a.x*bb.w;
      acc[1][0]+=a.y*bb.x; acc[1][1]+=a.y*bb.y; acc[1][2]+=a.y*bb.z; acc[1][3]+=a.y*bb.w;
      acc[2][0]+=a.z*bb.x; acc[2][1]+=a.z*bb.y; acc[2][2]+=a.z*bb.z; acc[2][3]+=a.z*bb.w;
      acc[3][0]+=a.w*bb.x; acc[3][1]+=a.w*bb.y; acc[3][2]+=a.w*bb.z; acc[3][3]+=a.w*bb.w;
    }
  }

  // reduce row sums across the 16 tx threads (reuse Ps)
  __syncthreads();
  #pragma unroll
  for (int r=0;r<4;r++) Ps[ty*4+r][tx] = lsum[r];
  __syncthreads();
  #pragma unroll
  for (int r=0;r<4;r++){
    float lt = 0.f;
    #pragma unroll
    for (int t=0;t<16;t++) lt += Ps[ty*4+r][t];
    float inv = 1.f/lt;
    float4 o4 = make_float4(acc[r][0]*inv, acc[r][1]*inv, acc[r][2]*inv, acc[r][3]*inv);
    *(float4*)(o + ((size_t)(b*SS + qt*64 + ty*4 + r)*HH + h)*HDD + tx*4) = o4;
  }
}

// ---------------------------------------------------------------------------
// h = silu(gate) * up   (in-place into gate buffer)
// ---------------------------------------------------------------------------
__global__ __launch_bounds__(256) void silu_mul(float* __restrict__ g,
                                                const float* __restrict__ u,
                                                long n4){
  long idx = (long)blockIdx.x*blockDim.x + threadIdx.x;
  long stride = (long)gridDim.x*blockDim.x;
  for (; idx<n4; idx+=stride){
    float4 gv = ((const float4*)g)[idx];
    float4 uv = ((const float4*)u)[idx];
    float4 o;
    o.x = gv.x/(1.f+__expf(-gv.x))*uv.x;
    o.y = gv.y/(1.f+__expf(-gv.y))*uv.y;
    o.z = gv.z/(1.f+__expf(-gv.z))*uv.z;
    o.w = gv.w/(1.f+__expf(-gv.w))*uv.w;
    ((float4*)g)[idx] = o;
  }
}

// ---------------------------------------------------------------------------
extern "C" void kernel_launch(void* const* d_in, const int* in_sizes, int n_in,
                              void* d_out, int out_size, void* d_ws, size_t ws_size,
                              hipStream_t stream) {
  const float* x   = (const float*)d_in[0];
  const float* ln1 = (const float*)d_in[1];
  const float* wq  = (const float*)d_in[2];
  const float* sq  = (const float*)d_in[3];
  const float* bq  = (const float*)d_in[4];
  const float* wk  = (const float*)d_in[5];
  const float* sk  = (const float*)d_in[6];
  const float* bk  = (const float*)d_in[7];
  const float* wv  = (const float*)d_in[8];
  const float* sv  = (const float*)d_in[9];
  const float* bv  = (const float*)d_in[10];
  const float* qn  = (const float*)d_in[11];
  const float* kn  = (const float*)d_in[12];
  const float* wo  = (const float*)d_in[13];
  const float* so  = (const float*)d_in[14];
  const float* bo  = (const float*)d_in[15];
  const float* ln2 = (const float*)d_in[16];
  const float* wg  = (const float*)d_in[17];
  const float* sg  = (const float*)d_in[18];
  const float* bg  = (const float*)d_in[19];
  const float* wu  = (const float*)d_in[20];
  const float* su  = (const float*)d_in[21];
  const float* bu  = (const float*)d_in[22];
  const float* wd  = (const float*)d_in[23];
  const float* sd  = (const float*)d_in[24];
  const float* bd  = (const float*)d_in[25];

  float* ws  = (float*)d_ws;
  float* out = (float*)d_out;

  float* bufA  = ws + OFF_A;
  float* bufQ  = ws + OFF_Q;
  float* bufK  = ws + OFF_K;
  float* bufV  = ws + OFF_V;
  float* bufX2 = ws + OFF_X2;
  float* bufG  = ws + OFF_G;
  float* bufU  = ws + OFF_U;
  float* accP  = ws + OFF_ACC;
  float* scaleArr = ws + OFF_SCALE;

  // ---- spectral sigma (power iteration, fused over 7 matrices) ----
  zero_acc_kernel<<<1, 128, 0, stream>>>(accP);
  PowArgs pa;
  pa.W[0]=wq; pa.W[1]=wk; pa.W[2]=wv; pa.W[3]=wo; pa.W[4]=wg; pa.W[5]=wu; pa.W[6]=wd;
  pa.vvec = ws + OFF_VV; pa.uvec = ws + OFF_UU; pa.acc = accP;
  for (int s=0; s<11; s++){
    pa.step = s;
    if ((s & 1) == 0) mv_notrans<<<2220, 256, 0, stream>>>(pa);
    else              mv_trans  <<<  42, 256, 0, stream>>>(pa);
  }
  SigArgs sa;
  sa.acc = accP; sa.scale = scaleArr;
  sa.sp[0]=sq; sa.sp[1]=sk; sa.sp[2]=sv; sa.sp[3]=so; sa.sp[4]=sg; sa.sp[5]=su; sa.sp[6]=sd;
  sigma_scale_kernel<<<1, 32, 0, stream>>>(sa);

  // ---- attention ----
  rmsnorm_row<<<NT, 256, 0, stream>>>(x, ln1, bufA);

  dim3 g1024((DD+127)/128, NT/128);
  gemm_f32<false><<<g1024, 256, 0, stream>>>(bufA, wq, bufQ, bq, scaleArr+0, nullptr, DD, DD);
  gemm_f32<false><<<g1024, 256, 0, stream>>>(bufA, wk, bufK, bk, scaleArr+1, nullptr, DD, DD);
  gemm_f32<false><<<g1024, 256, 0, stream>>>(bufA, wv, bufV, bv, scaleArr+2, nullptr, DD, DD);

  headnorm<<<(NT*HH)/4, 256, 0, stream>>>(bufQ, qn, NT*HH);
  headnorm<<<(NT*HH)/4, 256, 0, stream>>>(bufK, kn, NT*HH);

  attn_f32<<<dim3(SS/64, HH, BB), 256, 0, stream>>>(bufQ, bufK, bufV, bufA);

  gemm_f32<true><<<g1024, 256, 0, stream>>>(bufA, wo, bufX2, bo, scaleArr+3, x, DD, DD);

  // ---- MLP ----
  rmsnorm_row<<<NT, 256, 0, stream>>>(bufX2, ln2, bufQ);

  dim3 gMFF((MFF+127)/128, NT/128);
  gemm_f32<false><<<gMFF, 256, 0, stream>>>(bufQ, wg, bufG, bg, scaleArr+4, nullptr, MFF, DD);
  gemm_f32<false><<<gMFF, 256, 0, stream>>>(bufQ, wu, bufU, bu, scaleArr+5, nullptr, MFF, DD);

  silu_mul<<<2048, 256, 0, stream>>>(bufG, bufU, (long)NT*MFF/4);

  gemm_f32<true><<<g1024, 256, 0, stream>>>(bufG, wd, out, bd, scaleArr+6, bufX2, DD, MFF);
}

// Round 2
// 2492.372 us; speedup vs baseline: 1.4694x; 1.4694x over previous
//
#include <hip/hip_runtime.h>
#include <math.h>
#include <stddef.h>
#include <stdint.h>

// Problem constants (from reference)
#define BB   4
#define SS   1024
#define DD   1024
#define HH   16
#define HDD  64
#define NT   (BB*SS)      // 4096 tokens
#define MFF  2736
#define MFFP 2752         // MFF padded to multiple of 32 (K for wd GEMM)
#define EPSF 1e-6f

typedef unsigned int   u32;
typedef unsigned short ushort_t;
typedef float  f32x4  __attribute__((ext_vector_type(4)));
typedef short  s16x8  __attribute__((ext_vector_type(8)));
typedef unsigned short u16x4 __attribute__((ext_vector_type(4)));

typedef const __attribute__((address_space(1))) u32 glb_u32;
typedef __attribute__((address_space(3))) u32 lds_u32;

// ---------------------------------------------------------------------------
// Workspace layout (float units). Proven budget from round 1: ~173.7 MB.
// This layout: 41,063,952 floats = 164.3 MB.
//   R0  [0,22413312)            : qkv fp32 [4096][3072] (until attn) THEN gu fp32 [4096][5472]
//   X2  [22413312,+4194304)     : x + attn residual [4096][1024]
//   P0  [26607616,+11272192)    : actH (a/o/m hi+lo bf16 [4096][1024]x2) THEN h hi/lo [4096][2752]x2
//   BP  [37879808,+3145728)     : transposed-weight bf16 pool (hi+lo), reused per-GEMM
//   misc: power-iter vectors / accumulators / scales
// ---------------------------------------------------------------------------
static const size_t OFF_R0    = 0;
static const size_t OFF_X2    = 22413312;
static const size_t OFF_P0    = 26607616;
static const size_t OFF_BP    = 37879808;
static const size_t OFF_VV    = 41025536;
static const size_t OFF_UU    = 41044688;
static const size_t OFF_ACC   = 41063840;
static const size_t OFF_SCALE = 41063936;

// ---------------------------------------------------------------------------
// fp32 -> bf16 (RNE) split helpers
// ---------------------------------------------------------------------------
__device__ inline ushort_t f2bf(float x){
  u32 u = __float_as_uint(x);
  u32 r = (u + 0x7fffu + ((u >> 16) & 1u)) >> 16;
  return (ushort_t)r;
}
__device__ inline void split_bf(float x, ushort_t& hi, ushort_t& lo){
  hi = f2bf(x);
  float hf = __uint_as_float(((u32)hi) << 16);
  lo = f2bf(x - hf);
}

// ---------------------------------------------------------------------------
// Power iteration (unchanged from round 1 — verified correct)
// ---------------------------------------------------------------------------
struct PowArgs {
  const float* W[7];
  float* vvec; float* uvec; float* acc; int step;
};

__global__ void zero_acc_kernel(float* acc){
  if (threadIdx.x < 96) acc[threadIdx.x] = 0.f;
}

__global__ __launch_bounds__(256) void mv_notrans(PowArgs pa){
  const int NIN [7] = {1024,1024,1024,1024,1024,1024,2736};
  const int NOUT[7] = {1024,1024,1024,1024,2736,2736,1024};
  const int BST [8] = {0,256,512,768,1024,1280,1536,2220};
  int blk = blockIdx.x;
  int m = 0;
  #pragma unroll
  for (int i=1;i<7;i++) if (blk >= BST[i]) m = i;
  int nin = NIN[m], nout = NOUT[m];
  int wave = threadIdx.x >> 6, lane = threadIdx.x & 63;
  int row = (blk - BST[m])*4 + wave;
  if (row >= nin) return;
  const float* W = pa.W[m];
  int st = pa.step;
  float inv;
  const float* x = nullptr;
  if (st == 0){
    inv = 1.f/(sqrtf((float)nout)+EPSF);
  } else {
    inv = 1.f/(sqrtf(pa.acc[m*12+st-1])+EPSF);
    x = pa.uvec + m*2736;
  }
  float sum = 0.f;
  for (int j=lane; j<nout; j+=64){
    float xv = x ? x[j] : 1.f;
    sum += W[(size_t)row*nout + j]*xv;
  }
  #pragma unroll
  for (int off=32; off>=1; off>>=1) sum += __shfl_down(sum, off);
  if (lane == 0){
    float yv = sum*inv;
    pa.vvec[m*2736+row] = yv;
    atomicAdd(&pa.acc[m*12+st], yv*yv);
  }
}

__global__ __launch_bounds__(256) void mv_trans(PowArgs pa){
  const int NIN [7] = {1024,1024,1024,1024,1024,1024,2736};
  const int NOUT[7] = {1024,1024,1024,1024,2736,2736,1024};
  const int BST [8] = {0,4,8,12,16,27,38,42};
  __shared__ float xs[256];
  int blk = blockIdx.x;
  int m = 0;
  #pragma unroll
  for (int i=1;i<7;i++) if (blk >= BST[i]) m = i;
  int nin = NIN[m], nout = NOUT[m];
  int tid = threadIdx.x;
  int col = (blk - BST[m])*256 + tid;
  int st = pa.step;
  float inv = 1.f/(sqrtf(pa.acc[m*12+st-1])+EPSF);
  const float* x = pa.vvec + m*2736;
  const float* W = pa.W[m];
  float sum = 0.f;
  for (int i0=0; i0<nin; i0+=256){
    int ii = i0 + tid;
    xs[tid] = (ii < nin) ? x[ii] : 0.f;
    __syncthreads();
    int lim = nin - i0; if (lim > 256) lim = 256;
    if (col < nout){
      for (int i=0;i<lim;i++) sum += W[(size_t)(i0+i)*nout + col]*xs[i];
    }
    __syncthreads();
  }
  float yv = (col < nout) ? sum*inv : 0.f;
  if (col < nout) pa.uvec[m*2736+col] = yv;
  float sq = yv*yv;
  #pragma unroll
  for (int off=32; off>=1; off>>=1) sq += __shfl_down(sq, off);
  if ((tid & 63) == 0) atomicAdd(&pa.acc[m*12+st], sq);
}

struct SigArgs {
  float* acc; float* scale;
  const float* sp[7];
};
__global__ void sigma_scale_kernel(SigArgs sa){
  int m = threadIdx.x;
  if (m < 7){
    float a = sa.acc[m*12+10];
    float S = sqrtf(a);
    float sig = a/(S+EPSF);
    sig = fmaxf(sig, EPSF);
    sa.scale[m] = sa.sp[m][0]/sig;
  }
}

// ---------------------------------------------------------------------------
// Transpose + convert: src fp32 [K][N] -> dst hi/lo bf16 [n][k] with zero pad
// for k in [K,Kpad). Grid: (Kpad/32, ROWS/32), ROWS multiple of 32 (>= N ok,
// rows >= N are zero-filled).
// ---------------------------------------------------------------------------
__global__ __launch_bounds__(256) void trans_cvt(const float* __restrict__ src,
                                                 ushort_t* __restrict__ dh,
                                                 ushort_t* __restrict__ dl,
                                                 int K, int N, int Kpad){
  __shared__ float t[32][33];
  int k0 = blockIdx.x*32, n0 = blockIdx.y*32;
  int c = threadIdx.x & 31, rb = threadIdx.x >> 5;
  #pragma unroll
  for (int i=0;i<4;i++){
    int r = rb + i*8;
    int kk = k0 + r, nn = n0 + c;
    t[r][c] = (kk<K && nn<N) ? src[(size_t)kk*N + nn] : 0.f;
  }
  __syncthreads();
  #pragma unroll
  for (int i=0;i<4;i++){
    int r = rb + i*8;              // n offset in tile
    int nn = n0 + r, kk = k0 + c;  // output coords
    float v = t[c][r];
    ushort_t hi, lo; split_bf(v, hi, lo);
    size_t o = (size_t)nn*Kpad + kk;
    dh[o] = hi; dl[o] = lo;
  }
}

// ---------------------------------------------------------------------------
// RMSNorm over D=1024, emitting bf16 hi/lo (one block = one row)
// ---------------------------------------------------------------------------
__global__ __launch_bounds__(256) void rms_cvt(const float* __restrict__ in,
                                               const float* __restrict__ scale,
                                               ushort_t* __restrict__ oh,
                                               ushort_t* __restrict__ ol){
  int row = blockIdx.x;
  int tid = threadIdx.x;
  const float* p = in + (size_t)row*DD;
  float4 vx = *(const float4*)(p + tid*4);
  float ss = vx.x*vx.x + vx.y*vx.y + vx.z*vx.z + vx.w*vx.w;
  int lane = tid & 63, wave = tid >> 6;
  #pragma unroll
  for (int off=32; off>=1; off>>=1) ss += __shfl_down(ss, off);
  __shared__ float red[4];
  if (lane == 0) red[wave] = ss;
  __syncthreads();
  float tot = red[0]+red[1]+red[2]+red[3];
  float r = rsqrtf(tot*(1.f/DD)+EPSF);
  float4 sc = *(const float4*)(scale + tid*4);
  float o0 = vx.x*r*sc.x, o1 = vx.y*r*sc.y, o2 = vx.z*r*sc.z, o3 = vx.w*r*sc.w;
  u16x4 h4, l4;
  split_bf(o0, ((ushort_t*)&h4)[0], ((ushort_t*)&l4)[0]);
  split_bf(o1, ((ushort_t*)&h4)[1], ((ushort_t*)&l4)[1]);
  split_bf(o2, ((ushort_t*)&h4)[2], ((ushort_t*)&l4)[2]);
  split_bf(o3, ((ushort_t*)&h4)[3], ((ushort_t*)&l4)[3]);
  size_t o = (size_t)row*DD + tid*4;
  *(u16x4*)(oh + o) = h4;
  *(u16x4*)(ol + o) = l4;
}

// ---------------------------------------------------------------------------
// Per-head RMSNorm over HD=64 in the fused qkv buffer [NT][3072]
// ---------------------------------------------------------------------------
__global__ __launch_bounds__(256) void headnorm(float* __restrict__ qkv,
                                                const float* __restrict__ scale,
                                                int partOff){
  int wave = threadIdx.x >> 6, lane = threadIdx.x & 63;
  int row = blockIdx.x*4 + wave;          // row in [0, NT*HH)
  int t = row >> 4, hh = row & 15;
  float* p = qkv + (size_t)t*3072 + partOff + hh*64;
  float v = p[lane];
  float ss = v*v;
  #pragma unroll
  for (int off=32; off>=1; off>>=1) ss += __shfl_down(ss, off);
  ss = __shfl(ss, 0);
  float r = rsqrtf(ss*(1.f/HDD)+EPSF);
  p[lane] = v*r*scale[lane];
}

// ---------------------------------------------------------------------------
// bf16x3 split MFMA GEMM.
//   C[M][Cstride] (+bias, xscale, +resid) = scale * (A @ B)
//   A given as hi/lo bf16 [M][Kd]; B given as hi/lo bf16 [rows][Kd] where
//   rows = transposed weight (n-major). Product uses AhBh + AhBl + AlBh.
// Tile: BM=128, BN=FN*32, BK=32, 256 threads (4 waves, 2x2 wave grid),
// per-wave frags: 4 (m) x FN (n) of 16x16.
// Staging: global_load_lds width 16 with inverse-swizzled source; reads use
// swizzle chunk' = chunk ^ ((row>>1)&3)  -> conflict-free ds_read_b128.
// ---------------------------------------------------------------------------
struct GemmArgs {
  const ushort_t* Ah; const ushort_t* Al;
  const ushort_t* Bh; const ushort_t* Bl;
  float* C;
  const float* bias0; const float* bias1; const float* bias2;
  const float* scaleBase;       // scale per matrix (scaleArr + base)
  const float* resid;           // nullable, stride = Cstride
  int Kd; int matN; int bpm; int Cstride; int colOff;
};

template<int FN>
__global__ __launch_bounds__(256) void gemm_bf3(GemmArgs g){
  constexpr int BN   = FN*32;
  constexpr int SEGB = BN/16;           // 64-chunk segments per B buffer
  constexpr int NSEG = 16 + 2*SEGB;     // A(hi,lo): 8+8, B(hi,lo): SEGB+SEGB
  constexpr int NSEGT = NSEG/4;         // segments per wave
  constexpr int LDSB = 16384 + 2*BN*64; // bytes
  __shared__ char lds[LDSB];

  const int tid = threadIdx.x;
  const int w = tid >> 6, l = tid & 63;
  const int bm = blockIdx.y*128;
  const int mat = blockIdx.x / g.bpm;
  const int n0m = (blockIdx.x % g.bpm) * BN;
  const int nrow0 = mat*g.matN + n0m;   // row base into fused Bt buffer

  // --- staging setup: per-thread source pointers + LDS offsets ---
  const ushort_t* sp[NSEGT];
  u32 loff[NSEGT];
  #pragma unroll
  for (int i=0;i<NSEGT;i++){
    int s = w + i*4;
    int ci, r, c, csrc;
    if (s < 16){
      int abuf = s >> 3, segi = s & 7;
      ci = segi*64 + l; r = ci >> 2; c = ci & 3;
      csrc = c ^ ((r >> 1) & 3);
      sp[i] = (abuf ? g.Al : g.Ah) + (size_t)(bm + r)*g.Kd + csrc*8;
      loff[i] = (u32)(abuf*8192 + ci*16);
    } else {
      int tt = s - 16;
      int bbuf = tt / SEGB, segi = tt % SEGB;
      ci = segi*64 + l; r = ci >> 2; c = ci & 3;
      csrc = c ^ ((r >> 1) & 3);
      sp[i] = (bbuf ? g.Bl : g.Bh) + (size_t)(nrow0 + r)*g.Kd + csrc*8;
      loff[i] = (u32)(16384 + bbuf*(BN*64) + ci*16);
    }
  }

  // --- fragment read addressing ---
  const int wm = w >> 1, wn = w & 1;
  const int li = l & 15, kq = l >> 4;
  const int sx = kq ^ ((li >> 1) & 3);
  const char* lb = (const char*)lds;
  const u32 aOff = (u32)((wm*64 + li)*64 + sx*16);
  const u32 bOff = (u32)(16384 + (wn*(FN*16) + li)*64 + sx*16);

  f32x4 acc[4][FN];
  #pragma unroll
  for (int mi=0;mi<4;mi++)
    #pragma unroll
    for (int ni=0;ni<FN;ni++)
      acc[mi][ni] = (f32x4){0.f,0.f,0.f,0.f};

  for (int k0=0; k0<g.Kd; k0+=32){
    #pragma unroll
    for (int i=0;i<NSEGT;i++){
      __builtin_amdgcn_global_load_lds((glb_u32*)sp[i], (lds_u32*)(lds + loff[i]), 16, 0, 0);
      sp[i] += 32;
    }
    __syncthreads();

    s16x8 ah[4], al[4];
    #pragma unroll
    for (int mi=0;mi<4;mi++){
      ah[mi] = *(const s16x8*)(lb + aOff + mi*1024);
      al[mi] = *(const s16x8*)(lb + 8192 + aOff + mi*1024);
    }
    #pragma unroll
    for (int ni=0;ni<FN;ni++){
      s16x8 bh = *(const s16x8*)(lb + bOff + ni*1024);
      s16x8 bl = *(const s16x8*)(lb + BN*64 + bOff + ni*1024);
      #pragma unroll
      for (int mi=0;mi<4;mi++){
        f32x4 t = acc[mi][ni];
        t = __builtin_amdgcn_mfma_f32_16x16x32_bf16(ah[mi], bh, t, 0, 0, 0);
        t = __builtin_amdgcn_mfma_f32_16x16x32_bf16(ah[mi], bl, t, 0, 0, 0);
        t = __builtin_amdgcn_mfma_f32_16x16x32_bf16(al[mi], bh, t, 0, 0, 0);
        acc[mi][ni] = t;
      }
    }
    __syncthreads();
  }

  // --- epilogue ---
  const float s = g.scaleBase[mat];
  const float* bias = (mat==0) ? g.bias0 : (mat==1 ? g.bias1 : g.bias2);
  const int colBase = n0m + wn*(FN*16);
  #pragma unroll
  for (int ni=0;ni<FN;ni++){
    int cm = colBase + ni*16 + li;
    if (cm < g.matN){
      int cg = mat*g.matN + cm + g.colOff;
      float bv = bias[cm];
      #pragma unroll
      for (int mi=0;mi<4;mi++){
        f32x4 a = acc[mi][ni];
        int r0 = bm + wm*64 + mi*16 + kq*4;
        #pragma unroll
        for (int j=0;j<4;j++){
          float v = s*a[j] + bv;
          size_t off = (size_t)(r0+j)*g.Cstride + cg;
          if (g.resid) v += g.resid[off];
          g.C[off] = v;
        }
      }
    }
  }
}

// ---------------------------------------------------------------------------
// Flash-style fp32 attention with tanh softcap, fused qkv layout [NT][3072],
// epilogue emits bf16 hi/lo for the wo GEMM.
// ---------------------------------------------------------------------------
__global__ __launch_bounds__(256) void attn_f32(const float* __restrict__ qkv,
                                                ushort_t* __restrict__ oh,
                                                ushort_t* __restrict__ ol){
  int qt = blockIdx.x, h = blockIdx.y, b = blockIdx.z;
  __shared__ float Qs[64][68];
  __shared__ float Bs[64][68];
  __shared__ float Ps[64][68];
  int tid = threadIdx.x;
  int ty = tid >> 4, tx = tid & 15;
  int lr = tid >> 2, lc = (tid & 3)*16;

  const float* qbase = qkv + (size_t)(b*SS + qt*64 + lr)*3072 + h*64;
  #pragma unroll
  for (int i=0;i<4;i++){
    float4 t = *(const float4*)(qbase + lc + i*4);
    Qs[lc+i*4+0][lr]=t.x; Qs[lc+i*4+1][lr]=t.y; Qs[lc+i*4+2][lr]=t.z; Qs[lc+i*4+3][lr]=t.w;
  }

  float acc[4][4] = {{0.f}};
  float lsum[4] = {0.f,0.f,0.f,0.f};

  for (int kt=0; kt<SS/64; kt++){
    __syncthreads();
    const float* kbase = qkv + (size_t)(b*SS + kt*64 + lr)*3072 + 1024 + h*64;
    #pragma unroll
    for (int i=0;i<4;i++){
      float4 t = *(const float4*)(kbase + lc + i*4);
      Bs[lc+i*4+0][lr]=t.x; Bs[lc+i*4+1][lr]=t.y; Bs[lc+i*4+2][lr]=t.z; Bs[lc+i*4+3][lr]=t.w;
    }
    __syncthreads();

    float sreg[4][4] = {{0.f}};
    #pragma unroll 8
    for (int kk=0; kk<64; kk++){
      float4 a  = *(const float4*)&Qs[kk][ty*4];
      float4 bb = *(const float4*)&Bs[kk][tx*4];
      sreg[0][0]+=a.x*bb.x; sreg[0][1]+=a.x*bb.y; sreg[0][2]+=a.x*bb.z; sreg[0][3]+=a.x*bb.w;
      sreg[1][0]+=a.y*bb.x; sreg[1][1]+=a.y*bb.y; sreg[1][2]+=a.y*bb.z; sreg[1][3]+=a.y*bb.w;
      sreg[2][0]+=a.z*bb.x; sreg[2][1]+=a.z*bb.y; sreg[2][2]+=a.z*bb.z; sreg[2][3]+=a.z*bb.w;
      sreg[3][0]+=a.w*bb.x; sreg[3][1]+=a.w*bb.y; sreg[3][2]+=a.w*bb.z; sreg[3][3]+=a.w*bb.w;
    }
    float p[4][4];
    #pragma unroll
    for (int r=0;r<4;r++)
      #pragma unroll
      for (int c=0;c<4;c++){
        float logits = sreg[r][c]*0.125f;
        float pv = __expf(50.f*tanhf(logits*0.02f));
        p[r][c] = pv;
        lsum[r] += pv;
      }
    __syncthreads();

    #pragma unroll
    for (int c=0;c<4;c++){
      float4 pc = make_float4(p[0][c],p[1][c],p[2][c],p[3][c]);
      *(float4*)&Ps[tx*4+c][ty*4] = pc;
    }
    const float* vbase = qkv + (size_t)(b*SS + kt*64 + lr)*3072 + 2048 + h*64;
    #pragma unroll
    for (int i=0;i<4;i++){
      float4 t = *(const float4*)(vbase + lc + i*4);
      *(float4*)&Bs[lr][lc+i*4] = t;
    }
    __syncthreads();

    #pragma unroll 8
    for (int jj=0; jj<64; jj++){
      float4 a  = *(const float4*)&Ps[jj][ty*4];
      float4 bb = *(const float4*)&Bs[jj][tx*4];
      acc[0][0]+=a.x*bb.x; acc[0][1]+=a.x*bb.y; acc[0][2]+=a.x*bb.z; acc[0][3]+=a.x*bb.w;
      acc[1][0]+=a.y*bb.x; acc[1][1]+=a.y*bb.y; acc[1][2]+=a.y*bb.z; acc[1][3]+=a.y*bb.w;
      acc[2][0]+=a.z*bb.x; acc[2][1]+=a.z*bb.y; acc[2][2]+=a.z*bb.z; acc[2][3]+=a.z*bb.w;
      acc[3][0]+=a.w*bb.x; acc[3][1]+=a.w*bb.y; acc[3][2]+=a.w*bb.z; acc[3][3]+=a.w*bb.w;
    }
  }

  __syncthreads();
  #pragma unroll
  for (int r=0;r<4;r++) Ps[ty*4+r][tx] = lsum[r];
  __syncthreads();
  #pragma unroll
  for (int r=0;r<4;r++){
    float lt = 0.f;
    #pragma unroll
    for (int t=0;t<16;t++) lt += Ps[ty*4+r][t];
    float inv = 1.f/lt;
    u16x4 h4, l4;
    split_bf(acc[r][0]*inv, ((ushort_t*)&h4)[0], ((ushort_t*)&l4)[0]);
    split_bf(acc[r][1]*inv, ((ushort_t*)&h4)[1], ((ushort_t*)&l4)[1]);
    split_bf(acc[r][2]*inv, ((ushort_t*)&h4)[2], ((ushort_t*)&l4)[2]);
    split_bf(acc[r][3]*inv, ((ushort_t*)&h4)[3], ((ushort_t*)&l4)[3]);
    size_t o = (size_t)(b*SS + qt*64 + ty*4 + r)*1024 + h*64 + tx*4;
    *(u16x4*)(oh + o) = h4;
    *(u16x4*)(ol + o) = l4;
  }
}

// ---------------------------------------------------------------------------
// h = silu(gate)*up, from fused gu [NT][5472] -> h hi/lo [NT][2752] (zero pad)
// ---------------------------------------------------------------------------
__global__ __launch_bounds__(256) void silu_cvt(const float* __restrict__ gu,
                                                ushort_t* __restrict__ hh,
                                                ushort_t* __restrict__ hl){
  int q = blockIdx.x*256 + threadIdx.x;
  int row = blockIdx.y;
  if (q >= 688) return;
  int j = q*4;
  u16x4 h4 = (u16x4){0,0,0,0}, l4 = (u16x4){0,0,0,0};
  if (j < MFF){
    float4 g4 = *(const float4*)(gu + (size_t)row*5472 + j);
    float4 u4 = *(const float4*)(gu + (size_t)row*5472 + MFF + j);
    float v0 = g4.x/(1.f+__expf(-g4.x))*u4.x;
    float v1 = g4.y/(1.f+__expf(-g4.y))*u4.y;
    float v2 = g4.z/(1.f+__expf(-g4.z))*u4.z;
    float v3 = g4.w/(1.f+__expf(-g4.w))*u4.w;
    split_bf(v0, ((ushort_t*)&h4)[0], ((ushort_t*)&l4)[0]);
    split_bf(v1, ((ushort_t*)&h4)[1], ((ushort_t*)&l4)[1]);
    split_bf(v2, ((ushort_t*)&h4)[2], ((ushort_t*)&l4)[2]);
    split_bf(v3, ((ushort_t*)&h4)[3], ((ushort_t*)&l4)[3]);
  }
  size_t o = (size_t)row*MFFP + j;
  *(u16x4*)(hh + o) = h4;
  *(u16x4*)(hl + o) = l4;
}

// ---------------------------------------------------------------------------
extern "C" void kernel_launch(void* const* d_in, const int* in_sizes, int n_in,
                              void* d_out, int out_size, void* d_ws, size_t ws_size,
                              hipStream_t stream) {
  const float* x   = (const float*)d_in[0];
  const float* ln1 = (const float*)d_in[1];
  const float* wq  = (const float*)d_in[2];
  const float* sq  = (const float*)d_in[3];
  const float* bq  = (const float*)d_in[4];
  const float* wk  = (const float*)d_in[5];
  const float* sk  = (const float*)d_in[6];
  const float* bk  = (const float*)d_in[7];
  const float* wv  = (const float*)d_in[8];
  const float* sv  = (const float*)d_in[9];
  const float* bv  = (const float*)d_in[10];
  const float* qn  = (const float*)d_in[11];
  const float* kn  = (const float*)d_in[12];
  const float* wo  = (const float*)d_in[13];
  const float* so  = (const float*)d_in[14];
  const float* bo  = (const float*)d_in[15];
  const float* ln2 = (const float*)d_in[16];
  const float* wg  = (const float*)d_in[17];
  const float* sg  = (const float*)d_in[18];
  const float* bg  = (const float*)d_in[19];
  const float* wu  = (const float*)d_in[20];
  const float* su  = (const float*)d_in[21];
  const float* bu  = (const float*)d_in[22];
  const float* wd  = (const float*)d_in[23];
  const float* sd  = (const float*)d_in[24];
  const float* bd  = (const float*)d_in[25];

  float* ws  = (float*)d_ws;
  float* out = (float*)d_out;

  float* qkv = ws + OFF_R0;             // [4096][3072] fp32
  float* gu  = ws + OFF_R0;             // [4096][5472] fp32 (after attn)
  float* x2  = ws + OFF_X2;             // [4096][1024] fp32
  ushort_t* actH = (ushort_t*)(ws + OFF_P0);            // a/o/m hi
  ushort_t* actL = actH + (size_t)NT*DD;                // a/o/m lo
  ushort_t* hH   = (ushort_t*)(ws + OFF_P0);            // h hi [4096][2752]
  ushort_t* hL   = hH + (size_t)NT*MFFP;                // h lo
  ushort_t* bpH  = (ushort_t*)(ws + OFF_BP);            // weight pool hi
  float* accP  = ws + OFF_ACC;
  float* scaleArr = ws + OFF_SCALE;

  // ---- spectral sigma (power iteration) ----
  zero_acc_kernel<<<1, 128, 0, stream>>>(accP);
  PowArgs pa;
  pa.W[0]=wq; pa.W[1]=wk; pa.W[2]=wv; pa.W[3]=wo; pa.W[4]=wg; pa.W[5]=wu; pa.W[6]=wd;
  pa.vvec = ws + OFF_VV; pa.uvec = ws + OFF_UU; pa.acc = accP;
  for (int s=0; s<11; s++){
    pa.step = s;
    if ((s & 1) == 0) mv_notrans<<<2220, 256, 0, stream>>>(pa);
    else              mv_trans  <<<  42, 256, 0, stream>>>(pa);
  }
  SigArgs sa;
  sa.acc = accP; sa.scale = scaleArr;
  sa.sp[0]=sq; sa.sp[1]=sk; sa.sp[2]=sv; sa.sp[3]=so; sa.sp[4]=sg; sa.sp[5]=su; sa.sp[6]=sd;
  sigma_scale_kernel<<<1, 32, 0, stream>>>(sa);

  // ---- attn_in = RMSNorm(x) -> bf16 hi/lo ----
  rms_cvt<<<NT, 256, 0, stream>>>(x, ln1, actH, actL);

  // ---- QKV fused GEMM (weights -> pool, transposed bf16 hi/lo) ----
  {
    ushort_t* bpL = bpH + (size_t)3072*1024;
    trans_cvt<<<dim3(32,32), 256, 0, stream>>>(wq, bpH,              bpL,              1024, 1024, 1024);
    trans_cvt<<<dim3(32,32), 256, 0, stream>>>(wk, bpH+1024*1024,    bpL+1024*1024,    1024, 1024, 1024);
    trans_cvt<<<dim3(32,32), 256, 0, stream>>>(wv, bpH+2*1024*1024,  bpL+2*1024*1024,  1024, 1024, 1024);
    GemmArgs ga;
    ga.Ah = actH; ga.Al = actL; ga.Bh = bpH; ga.Bl = bpL;
    ga.C = qkv; ga.bias0 = bq; ga.bias1 = bk; ga.bias2 = bv;
    ga.scaleBase = scaleArr + 0; ga.resid = nullptr;
    ga.Kd = 1024; ga.matN = 1024; ga.bpm = 8; ga.Cstride = 3072; ga.colOff = 0;
    gemm_bf3<4><<<dim3(24,32), 256, 0, stream>>>(ga);
  }

  headnorm<<<(NT*HH)/4, 256, 0, stream>>>(qkv, qn, 0);
  headnorm<<<(NT*HH)/4, 256, 0, stream>>>(qkv, kn, 1024);

  // ---- attention: writes o hi/lo into actH/actL (attn_in is dead) ----
  attn_f32<<<dim3(SS/64, HH, BB), 256, 0, stream>>>(qkv, actH, actL);

  // ---- out projection + residual ----
  {
    ushort_t* bpL = bpH + (size_t)1024*1024;
    trans_cvt<<<dim3(32,32), 256, 0, stream>>>(wo, bpH, bpL, 1024, 1024, 1024);
    GemmArgs ga;
    ga.Ah = actH; ga.Al = actL; ga.Bh = bpH; ga.Bl = bpL;
    ga.C = x2; ga.bias0 = bo; ga.bias1 = bo; ga.bias2 = bo;
    ga.scaleBase = scaleArr + 3; ga.resid = x;
    ga.Kd = 1024; ga.matN = 1024; ga.bpm = 16; ga.Cstride = 1024; ga.colOff = 0;
    gemm_bf3<2><<<dim3(16,32), 256, 0, stream>>>(ga);
  }

  // ---- mlp_in = RMSNorm(x2) -> bf16 hi/lo (reuses actH/actL) ----
  rms_cvt<<<NT, 256, 0, stream>>>(x2, ln2, actH, actL);

  // ---- gate GEMM ----
  {
    ushort_t* bpL = bpH + (size_t)2816*1024;
    trans_cvt<<<dim3(32,88), 256, 0, stream>>>(wg, bpH, bpL, 1024, MFF, 1024);
    GemmArgs ga;
    ga.Ah = actH; ga.Al = actL; ga.Bh = bpH; ga.Bl = bpL;
    ga.C = gu; ga.bias0 = bg; ga.bias1 = bg; ga.bias2 = bg;
    ga.scaleBase = scaleArr + 4; ga.resid = nullptr;
    ga.Kd = 1024; ga.matN = MFF; ga.bpm = 22; ga.Cstride = 5472; ga.colOff = 0;
    gemm_bf3<4><<<dim3(22,32), 256, 0, stream>>>(ga);
  }
  // ---- up GEMM ----
  {
    ushort_t* bpL = bpH + (size_t)2816*1024;
    trans_cvt<<<dim3(32,88), 256, 0, stream>>>(wu, bpH, bpL, 1024, MFF, 1024);
    GemmArgs ga;
    ga.Ah = actH; ga.Al = actL; ga.Bh = bpH; ga.Bl = bpL;
    ga.C = gu; ga.bias0 = bu; ga.bias1 = bu; ga.bias2 = bu;
    ga.scaleBase = scaleArr + 5; ga.resid = nullptr;
    ga.Kd = 1024; ga.matN = MFF; ga.bpm = 22; ga.Cstride = 5472; ga.colOff = MFF;
    gemm_bf3<4><<<dim3(22,32), 256, 0, stream>>>(ga);
  }

  // ---- h = silu(gate)*up -> bf16 hi/lo [4096][2752] (overwrites actH region) ----
  silu_cvt<<<dim3(3, NT), 256, 0, stream>>>(gu, hH, hL);

  // ---- down GEMM + residual -> d_out ----
  {
    ushort_t* bpL = bpH + (size_t)1024*MFFP;
    trans_cvt<<<dim3(MFFP/32, 32), 256, 0, stream>>>(wd, bpH, bpL, MFF, 1024, MFFP);
    GemmArgs ga;
    ga.Ah = hH; ga.Al = hL; ga.Bh = bpH; ga.Bl = bpL;
    ga.C = out; ga.bias0 = bd; ga.bias1 = bd; ga.bias2 = bd;
    ga.scaleBase = scaleArr + 6; ga.resid = x2;
    ga.Kd = MFFP; ga.matN = 1024; ga.bpm = 16; ga.Cstride = 1024; ga.colOff = 0;
    gemm_bf3<2><<<dim3(16,32), 256, 0, stream>>>(ga);
  }
}

// Round 3
// 1133.635 us; speedup vs baseline: 3.2305x; 2.1986x over previous
//
#include <hip/hip_runtime.h>
#include <math.h>
#include <stddef.h>
#include <stdint.h>

// Problem constants
#define BB   4
#define SS   1024
#define DD   1024
#define HH   16
#define HDD  64
#define NT   (BB*SS)      // 4096 tokens
#define MFF  2736
#define MFFP 2752
#define EPSF 1e-6f

typedef unsigned int   u32;
typedef unsigned short ushort_t;
typedef float  f32x4   __attribute__((ext_vector_type(4)));
typedef float  f32x16  __attribute__((ext_vector_type(16)));
typedef short  s16x8   __attribute__((ext_vector_type(8)));

typedef const __attribute__((address_space(1))) u32 glb_u32;
typedef __attribute__((address_space(3))) u32 lds_u32;

// ---------------------------------------------------------------------------
// Workspace layout (float units). Total 40,801,712 fl = 163.2 MB (<= proven 164.26).
// Timeline: act(2-4,8-9) qh/kh(3-6) vt(4-6) o(6-7) x2(7-11) gu(9-10) h(10-11)
// ---------------------------------------------------------------------------
static const size_t OFF_X2    = 0;                    // fp32 [4096][1024]
static const size_t OFF_GU    = 4194304;              // fp32 [4096][5472]   (alive 9-10)
static const size_t OFF_VT    = 4194304;              // vtH/vtL u16 [1024][4096] (alive 4-6)
static const size_t OFF_QH    = 8388608;              // qhH,qhL,khH,khL u16 [4096][64*16] (3-6)
static const size_t OFF_O     = 16777216;             // oH,oL u16 [4096][1024] (6-7)
static const size_t OFF_H     = 26607616;             // hH,hL u16 [4096][2752] (10-11)
static const size_t OFF_ACT   = 26607616;             // actH,actL u16 [4096][1024] (2-4,8-9)
static const size_t OFF_POOL  = 37879808;             // weight pool (2,883,584 fl)
static const size_t OFF_VV    = 40763392;             // 7*2736
static const size_t OFF_UU    = 40782544;             // 7*2736
static const size_t OFF_SCALE = 40801696;             // 7 (+pad)

// ---------------------------------------------------------------------------
__device__ inline ushort_t f2bf(float x){
  u32 u = __float_as_uint(x);
  u32 r = (u + 0x7fffu + ((u >> 16) & 1u)) >> 16;
  return (ushort_t)r;
}
__device__ inline void split_bf(float x, ushort_t& hi, ushort_t& lo){
  hi = f2bf(x);
  float hf = __uint_as_float(((u32)hi) << 16);
  lo = f2bf(x - hf);
}

// 256-thread block sum (uses 4-entry LDS scratch)
__device__ inline float block_sum256(float v, float* red){
  #pragma unroll
  for (int off=32; off>=1; off>>=1) v += __shfl_down(v, off);
  int lane = threadIdx.x & 63, wave = threadIdx.x >> 6;
  if (lane == 0) red[wave] = v;
  __syncthreads();
  return red[0]+red[1]+red[2]+red[3];
}

// ---------------------------------------------------------------------------
// Power iteration.  Matrices (nin x nout):
// 0 wq 1 wk 2 wv 3 wo (1024x1024), 4 wg 5 wu (1024x2736), 6 wd (2736x1024)
// even step: vvec = W @ u_normalized (raw out); odd: uvec += W^T @ v_normalized
// Norms recomputed by consumers (deferred normalization).
// ---------------------------------------------------------------------------
struct PowArgs {
  const float* W[7];
  float* vvec; float* uvec; int step;
};

__global__ __launch_bounds__(256) void zero_uvec(float* uvec){
  int m = blockIdx.x;
  for (int i=threadIdx.x; i<2736; i+=256) uvec[m*2736+i] = 0.f;
}

__global__ __launch_bounds__(256) void mv_notrans(PowArgs pa){
  const int NIN [7] = {1024,1024,1024,1024,1024,1024,2736};
  const int NOUT[7] = {1024,1024,1024,1024,2736,2736,1024};
  const int BST [8] = {0,256,512,768,1024,1280,1536,2220};
  __shared__ float red[4];
  int blk = blockIdx.x;
  int m = 0;
  #pragma unroll
  for (int i=1;i<7;i++) if (blk >= BST[i]) m = i;
  int nin = NIN[m], nout = NOUT[m];
  int st = pa.step;
  float inv;
  const float* x = pa.uvec + m*2736;
  if (st == 0){
    inv = 1.f/(sqrtf((float)nout)+EPSF);
  } else {
    float s = 0.f;
    for (int i=threadIdx.x; i<nout; i+=256){ float u = x[i]; s += u*u; }
    float tot = block_sum256(s, red);
    inv = 1.f/(sqrtf(tot)+EPSF);
  }
  int wave = threadIdx.x >> 6, lane = threadIdx.x & 63;
  int row = (blk - BST[m])*4 + wave;
  if (row >= nin) return;
  const float* W = pa.W[m];
  float sum = 0.f;
  for (int j=lane; j<nout; j+=64){
    float xv = (st == 0) ? 1.f : x[j];
    sum += W[(size_t)row*nout + j]*xv;
  }
  #pragma unroll
  for (int off=32; off>=1; off>>=1) sum += __shfl_down(sum, off);
  if (lane == 0) pa.vvec[m*2736+row] = sum*inv;
}

__global__ __launch_bounds__(256) void mv_trans(PowArgs pa){
  const int NIN [7] = {1024,1024,1024,1024,1024,1024,2736};
  const int NOUT[7] = {1024,1024,1024,1024,2736,2736,1024};
  const int BST [8] = {0,32,64,96,128,216,304,392};
  const int RCH [7] = {8,8,8,8,8,8,22};
  __shared__ float red[4];
  int blk = blockIdx.x;
  int m = 0;
  #pragma unroll
  for (int i=1;i<7;i++) if (blk >= BST[i]) m = i;
  int nin = NIN[m], nout = NOUT[m];
  const float* v = pa.vvec + m*2736;
  // block-reduce ||v||^2
  float s = 0.f;
  for (int i=threadIdx.x; i<nin; i+=256){ float t = v[i]; s += t*t; }
  float tot = block_sum256(s, red);
  float inv = 1.f/(sqrtf(tot)+EPSF);
  int local = blk - BST[m];
  int ct = local / RCH[m], rc = local % RCH[m];
  int col = ct*256 + threadIdx.x;
  int r0 = rc*128, r1 = min(nin, r0+128);
  if (col >= nout) return;
  const float* W = pa.W[m];
  float partial = 0.f;
  for (int r=r0; r<r1; ++r)
    partial += W[(size_t)r*nout + col]*(v[r]*inv);
  atomicAdd(&pa.uvec[m*2736+col], partial);
}

struct SigArgs {
  const float* vvec; float* scale;
  const float* sp[7];
};
__global__ __launch_bounds__(256) void sigma_scale_kernel(SigArgs sa){
  const int NIN [7] = {1024,1024,1024,1024,1024,1024,2736};
  __shared__ float red[4];
  int m = blockIdx.x;
  const float* v = sa.vvec + m*2736;
  float s = 0.f;
  for (int i=threadIdx.x; i<NIN[m]; i+=256){ float t = v[i]; s += t*t; }
  float a = block_sum256(s, red);
  if (threadIdx.x == 0){
    float S = sqrtf(a);
    float sig = a/(S+EPSF);
    sig = fmaxf(sig, EPSF);
    sa.scale[m] = sa.sp[m][0]/sig;
  }
}

// ---------------------------------------------------------------------------
// Transpose + convert: src fp32 [K][N] -> dst hi/lo bf16 [n][k], zero-padded
// ---------------------------------------------------------------------------
__global__ __launch_bounds__(256) void trans_cvt(const float* __restrict__ src,
                                                 ushort_t* __restrict__ dh,
                                                 ushort_t* __restrict__ dl,
                                                 int K, int N, int Kpad){
  __shared__ float t[32][33];
  int k0 = blockIdx.x*32, n0 = blockIdx.y*32;
  int c = threadIdx.x & 31, rb = threadIdx.x >> 5;
  #pragma unroll
  for (int i=0;i<4;i++){
    int r = rb + i*8;
    int kk = k0 + r, nn = n0 + c;
    t[r][c] = (kk<K && nn<N) ? src[(size_t)kk*N + nn] : 0.f;
  }
  __syncthreads();
  #pragma unroll
  for (int i=0;i<4;i++){
    int r = rb + i*8;
    int nn = n0 + r, kk = k0 + c;
    float v = t[c][r];
    ushort_t hi, lo; split_bf(v, hi, lo);
    size_t o = (size_t)nn*Kpad + kk;
    dh[o] = hi; dl[o] = lo;
  }
}

// ---------------------------------------------------------------------------
// RMSNorm over D=1024 -> bf16 hi/lo
// ---------------------------------------------------------------------------
__global__ __launch_bounds__(256) void rms_cvt(const float* __restrict__ in,
                                               const float* __restrict__ scale,
                                               ushort_t* __restrict__ oh,
                                               ushort_t* __restrict__ ol){
  int row = blockIdx.x;
  int tid = threadIdx.x;
  const float* p = in + (size_t)row*DD;
  float4 vx = *(const float4*)(p + tid*4);
  float ss = vx.x*vx.x + vx.y*vx.y + vx.z*vx.z + vx.w*vx.w;
  int lane = tid & 63, wave = tid >> 6;
  #pragma unroll
  for (int off=32; off>=1; off>>=1) ss += __shfl_down(ss, off);
  __shared__ float red[4];
  if (lane == 0) red[wave] = ss;
  __syncthreads();
  float tot = red[0]+red[1]+red[2]+red[3];
  float r = rsqrtf(tot*(1.f/DD)+EPSF);
  float4 sc = *(const float4*)(scale + tid*4);
  float o0 = vx.x*r*sc.x, o1 = vx.y*r*sc.y, o2 = vx.z*r*sc.z, o3 = vx.w*r*sc.w;
  ushort_t h[4], l[4];
  split_bf(o0,h[0],l[0]); split_bf(o1,h[1],l[1]);
  split_bf(o2,h[2],l[2]); split_bf(o3,h[3],l[3]);
  size_t o = (size_t)row*DD + tid*4;
  oh[o+0]=h[0]; oh[o+1]=h[1]; oh[o+2]=h[2]; oh[o+3]=h[3];
  ol[o+0]=l[0]; ol[o+1]=l[1]; ol[o+2]=l[2]; ol[o+3]=l[3];
}

// ---------------------------------------------------------------------------
// bf16x3 split MFMA GEMM with selectable epilogue.
//  EPI 0: C fp32 [M][Cstride] = s*(A@B^T) + bias0[col] (+resid), guard col<matN
//  EPI 1: QK fused per-head RMSNorm -> bf16 hi/lo head-major dst (2 mats)
//  EPI 2: VT: bf16 hi/lo out at [row][col], bias0 per ROW
// Tile BM=128, BN=FN*32, BK=32, 256 threads (2x2 waves), frags 4 x FN of 16x16.
// ---------------------------------------------------------------------------
struct GemmArgs {
  const ushort_t *Ah, *Al, *Bh, *Bl;
  float* C;
  const float *bias0, *bias1;
  const float *nrm0, *nrm1;
  ushort_t *dH0, *dL0, *dH1, *dL1;
  const float* scaleBase;
  const float* resid;
  int Kd, matN, bpm, rowsPerMat, Cstride, colOff;
};

template<int FN, int EPI>
__global__ __launch_bounds__(256) void gemm_bf3(GemmArgs g){
  constexpr int BN   = FN*32;
  constexpr int SEGB = BN/16;
  constexpr int NSEG = 16 + 2*SEGB;
  constexpr int NSEGT = NSEG/4;
  constexpr int LDSB = 16384 + 2*BN*64;
  __shared__ __align__(16) char lds[LDSB];

  const int tid = threadIdx.x;
  const int w = tid >> 6, l = tid & 63;
  const int bm = blockIdx.y*128;
  const int mat = blockIdx.x / g.bpm;
  const int n0m = (blockIdx.x % g.bpm) * BN;
  const int nrow0 = mat*g.rowsPerMat + n0m;

  const ushort_t* sp[NSEGT];
  u32 loff[NSEGT];
  #pragma unroll
  for (int i=0;i<NSEGT;i++){
    int s = w + i*4;
    int ci, r, c, csrc;
    if (s < 16){
      int abuf = s >> 3, segi = s & 7;
      ci = segi*64 + l; r = ci >> 2; c = ci & 3;
      csrc = c ^ ((r >> 1) & 3);
      sp[i] = (abuf ? g.Al : g.Ah) + (size_t)(bm + r)*g.Kd + csrc*8;
      loff[i] = (u32)(abuf*8192 + ci*16);
    } else {
      int tt = s - 16;
      int bbuf = tt / SEGB, segi = tt % SEGB;
      ci = segi*64 + l; r = ci >> 2; c = ci & 3;
      csrc = c ^ ((r >> 1) & 3);
      sp[i] = (bbuf ? g.Bl : g.Bh) + (size_t)(nrow0 + r)*g.Kd + csrc*8;
      loff[i] = (u32)(16384 + bbuf*(BN*64) + ci*16);
    }
  }

  const int wm = w >> 1, wn = w & 1;
  const int li = l & 15, kq = l >> 4;
  const int sx = kq ^ ((li >> 1) & 3);
  const char* lb = (const char*)lds;
  const u32 aOff = (u32)((wm*64 + li)*64 + sx*16);
  const u32 bOff = (u32)(16384 + (wn*(FN*16) + li)*64 + sx*16);

  f32x4 acc[4][FN];
  #pragma unroll
  for (int mi=0;mi<4;mi++)
    #pragma unroll
    for (int ni=0;ni<FN;ni++)
      acc[mi][ni] = (f32x4){0.f,0.f,0.f,0.f};

  for (int k0=0; k0<g.Kd; k0+=32){
    #pragma unroll
    for (int i=0;i<NSEGT;i++){
      __builtin_amdgcn_global_load_lds((glb_u32*)sp[i], (lds_u32*)(lds + loff[i]), 16, 0, 0);
      sp[i] += 32;
    }
    __syncthreads();
    s16x8 ah[4], al[4];
    #pragma unroll
    for (int mi=0;mi<4;mi++){
      ah[mi] = *(const s16x8*)(lb + aOff + mi*1024);
      al[mi] = *(const s16x8*)(lb + 8192 + aOff + mi*1024);
    }
    #pragma unroll
    for (int ni=0;ni<FN;ni++){
      s16x8 bh = *(const s16x8*)(lb + bOff + ni*1024);
      s16x8 bl = *(const s16x8*)(lb + BN*64 + bOff + ni*1024);
      #pragma unroll
      for (int mi=0;mi<4;mi++){
        f32x4 t = acc[mi][ni];
        t = __builtin_amdgcn_mfma_f32_16x16x32_bf16(ah[mi], bh, t, 0, 0, 0);
        t = __builtin_amdgcn_mfma_f32_16x16x32_bf16(ah[mi], bl, t, 0, 0, 0);
        t = __builtin_amdgcn_mfma_f32_16x16x32_bf16(al[mi], bh, t, 0, 0, 0);
        acc[mi][ni] = t;
      }
    }
    __syncthreads();
  }

  if constexpr (EPI == 0){
    const float s = g.scaleBase[mat];
    const float* bias = g.bias0;
    const int colBase = n0m + wn*(FN*16);
    #pragma unroll
    for (int ni=0;ni<FN;ni++){
      int cm = colBase + ni*16 + li;
      if (cm < g.matN){
        int cg = cm + g.colOff;
        float bv = bias[cm];
        #pragma unroll
        for (int mi=0;mi<4;mi++){
          f32x4 a = acc[mi][ni];
          int r0 = bm + wm*64 + mi*16 + kq*4;
          #pragma unroll
          for (int j=0;j<4;j++){
            float v = s*a[j] + bv;
            size_t off = (size_t)(r0+j)*g.Cstride + cg;
            if (g.resid) v += g.resid[off];
            g.C[off] = v;
          }
        }
      }
    }
  } else if constexpr (EPI == 1){
    // fused per-head RMSNorm -> bf16 hi/lo head-major [(b*16+h)*1024+s][64]
    const float s = g.scaleBase[mat];
    const float* bias = mat ? g.bias1 : g.bias0;
    const float* nsc  = mat ? g.nrm1  : g.nrm0;
    ushort_t* dH = mat ? g.dH1 : g.dH0;
    ushort_t* dL = mat ? g.dL1 : g.dL0;
    const int hidx = (n0m >> 6) + wn;
    float bv[FN], nv[FN];
    #pragma unroll
    for (int ni=0;ni<FN;ni++){
      int cm = n0m + wn*64 + ni*16 + li;
      bv[ni] = bias[cm];
      nv[ni] = nsc[ni*16 + li];
    }
    #pragma unroll
    for (int mi=0;mi<4;mi++){
      #pragma unroll
      for (int j=0;j<4;j++){
        float vv[FN]; float ssq = 0.f;
        #pragma unroll
        for (int ni=0;ni<FN;ni++){
          vv[ni] = s*acc[mi][ni][j] + bv[ni];
          ssq += vv[ni]*vv[ni];
        }
        ssq += __shfl_xor(ssq, 1);
        ssq += __shfl_xor(ssq, 2);
        ssq += __shfl_xor(ssq, 4);
        ssq += __shfl_xor(ssq, 8);
        float rr = rsqrtf(ssq*(1.f/64.f)+EPSF);
        int row = bm + wm*64 + mi*16 + kq*4 + j;
        size_t base = (((size_t)(row>>10)*16 + hidx)*1024 + (row & 1023))*64;
        #pragma unroll
        for (int ni=0;ni<FN;ni++){
          ushort_t hi, lo; split_bf(vv[ni]*rr*nv[ni], hi, lo);
          dH[base + ni*16 + li] = hi;
          dL[base + ni*16 + li] = lo;
        }
      }
    }
  } else {
    // EPI 2: bf16 hi/lo out [row][4096-col], bias per row
    const float s = g.scaleBase[0];
    #pragma unroll
    for (int mi=0;mi<4;mi++){
      #pragma unroll
      for (int j=0;j<4;j++){
        int row = bm + wm*64 + mi*16 + kq*4 + j;
        float bvr = g.bias0[row];
        #pragma unroll
        for (int ni=0;ni<FN;ni++){
          int cm = n0m + wn*(FN*16) + ni*16 + li;
          float v = s*acc[mi][ni][j] + bvr;
          ushort_t hi, lo; split_bf(v, hi, lo);
          g.dH0[(size_t)row*4096 + cm] = hi;
          g.dL0[(size_t)row*4096 + cm] = lo;
        }
      }
    }
  }
}

// ---------------------------------------------------------------------------
// MFMA flash attention (32x32x16 bf16, hi/lo split).
// Block: 64 q-rows x one (b,h). 4 waves: qhalf=w>>1, khalf=w&1.
// LDS rows padded to 144B. P overlays Q region (Q hoisted to regs).
// ---------------------------------------------------------------------------
#define AL_Q 0
#define AL_K 18432
#define AL_V 36864
#define AL_S 55296
__global__ __launch_bounds__(256) void attn_mfma(const ushort_t* __restrict__ qh, const ushort_t* __restrict__ ql,
                                                 const ushort_t* __restrict__ kh, const ushort_t* __restrict__ kl,
                                                 const ushort_t* __restrict__ vh, const ushort_t* __restrict__ vl,
                                                 ushort_t* __restrict__ oh, ushort_t* __restrict__ ol){
  __shared__ __align__(16) char lds[55808];
  const int qt = blockIdx.x, h = blockIdx.y, b = blockIdx.z;
  const int tid = threadIdx.x;
  const int li = tid & 31, kq = (tid >> 5) & 1;
  const int w = tid >> 6;
  const int qhalf = w >> 1, khalf = w & 1;

  // stage Q (64 rows x 64 hd, hi+lo)
  const size_t qbase = ((size_t)(b*HH + h)*SS + qt*64)*64;
  #pragma unroll
  for (int p=0;p<2;p++){
    int slot = p*256 + tid; int r = slot>>3, ch = slot&7;
    *(s16x8*)(lds + AL_Q + r*144 + ch*16)        = *(const s16x8*)(qh + qbase + r*64 + ch*8);
    *(s16x8*)(lds + AL_Q + 9216 + r*144 + ch*16) = *(const s16x8*)(ql + qbase + r*64 + ch*8);
  }
  __syncthreads();
  s16x8 aQh[4], aQl[4];
  #pragma unroll
  for (int ks=0;ks<4;ks++){
    aQh[ks] = *(const s16x8*)(lds + AL_Q + (qhalf*32+li)*144 + ks*32 + kq*16);
    aQl[ks] = *(const s16x8*)(lds + AL_Q + 9216 + (qhalf*32+li)*144 + ks*32 + kq*16);
  }

  f32x16 accO = (f32x16){0,0,0,0,0,0,0,0,0,0,0,0,0,0,0,0};
  float psum[16];
  #pragma unroll
  for (int i=0;i<16;i++) psum[i] = 0.f;

  const size_t kbase = ((size_t)(b*HH + h)*SS)*64;
  const size_t vcol  = (size_t)b*SS;   // token base

  for (int kt=0; kt<16; kt++){
    __syncthreads();
    // stage K [key][hd] and V^T [hd][key]
    #pragma unroll
    for (int p=0;p<2;p++){
      int slot = p*256 + tid; int r = slot>>3, ch = slot&7;
      *(s16x8*)(lds + AL_K + r*144 + ch*16)        = *(const s16x8*)(kh + kbase + (size_t)(kt*64+r)*64 + ch*8);
      *(s16x8*)(lds + AL_K + 9216 + r*144 + ch*16) = *(const s16x8*)(kl + kbase + (size_t)(kt*64+r)*64 + ch*8);
      *(s16x8*)(lds + AL_V + r*144 + ch*16)        = *(const s16x8*)(vh + ((size_t)(h*64+r))*4096 + vcol + kt*64 + ch*8);
      *(s16x8*)(lds + AL_V + 9216 + r*144 + ch*16) = *(const s16x8*)(vl + ((size_t)(h*64+r))*4096 + vcol + kt*64 + ch*8);
    }
    __syncthreads();
    // S = Q K^T (32x32 per wave)
    f32x16 sF = (f32x16){0,0,0,0,0,0,0,0,0,0,0,0,0,0,0,0};
    #pragma unroll
    for (int ks=0;ks<4;ks++){
      s16x8 bKh = *(const s16x8*)(lds + AL_K + (khalf*32+li)*144 + ks*32 + kq*16);
      s16x8 bKl = *(const s16x8*)(lds + AL_K + 9216 + (khalf*32+li)*144 + ks*32 + kq*16);
      sF = __builtin_amdgcn_mfma_f32_32x32x16_bf16(aQh[ks], bKh, sF, 0, 0, 0);
      sF = __builtin_amdgcn_mfma_f32_32x32x16_bf16(aQh[ks], bKl, sF, 0, 0, 0);
      sF = __builtin_amdgcn_mfma_f32_32x32x16_bf16(aQl[ks], bKh, sF, 0, 0, 0);
    }
    // softcap + exp + write P (hi/lo) into Q region
    #pragma unroll
    for (int reg=0;reg<16;reg++){
      float t  = sF[reg]*0.125f;
      float w2 = __expf(t*0.04f);                       // e^{2t/50}
      float th = __fdividef(w2-1.f, w2+1.f);            // tanh(t/50)
      float pv = __expf(50.f*th);
      psum[reg] += pv;
      ushort_t hi, lo; split_bf(pv, hi, lo);
      int qrow = qhalf*32 + (reg&3) + 8*(reg>>2) + 4*kq;
      int key  = khalf*32 + li;
      *(ushort_t*)(lds + AL_Q + qrow*144 + key*2) = hi;
      *(ushort_t*)(lds + AL_Q + 9216 + qrow*144 + key*2) = lo;
    }
    __syncthreads();
    // O += P V  (A = P rows qhalf, B = V^T rows hd khalf*32..)
    #pragma unroll
    for (int ks=0;ks<4;ks++){
      s16x8 aPh = *(const s16x8*)(lds + AL_Q + (qhalf*32+li)*144 + ks*32 + kq*16);
      s16x8 aPl = *(const s16x8*)(lds + AL_Q + 9216 + (qhalf*32+li)*144 + ks*32 + kq*16);
      s16x8 bVh = *(const s16x8*)(lds + AL_V + (khalf*32+li)*144 + ks*32 + kq*16);
      s16x8 bVl = *(const s16x8*)(lds + AL_V + 9216 + (khalf*32+li)*144 + ks*32 + kq*16);
      accO = __builtin_amdgcn_mfma_f32_32x32x16_bf16(aPh, bVh, accO, 0, 0, 0);
      accO = __builtin_amdgcn_mfma_f32_32x32x16_bf16(aPh, bVl, accO, 0, 0, 0);
      accO = __builtin_amdgcn_mfma_f32_32x32x16_bf16(aPl, bVh, accO, 0, 0, 0);
    }
  }

  // row sums: reduce over 32 lanes, combine khalf halves via LDS
  #pragma unroll
  for (int reg=0;reg<16;reg++){
    float v = psum[reg];
    v += __shfl_xor(v, 1); v += __shfl_xor(v, 2); v += __shfl_xor(v, 4);
    v += __shfl_xor(v, 8); v += __shfl_xor(v, 16);
    psum[reg] = v;
  }
  float* sm = (float*)(lds + AL_S);
  if (li == 0){
    #pragma unroll
    for (int reg=0;reg<16;reg++){
      int qrow = qhalf*32 + (reg&3) + 8*(reg>>2) + 4*kq;
      sm[qrow*2 + khalf] = psum[reg];
    }
  }
  __syncthreads();
  #pragma unroll
  for (int reg=0;reg<16;reg++){
    int qrow = qhalf*32 + (reg&3) + 8*(reg>>2) + 4*kq;
    float tot = sm[qrow*2] + sm[qrow*2+1];
    float ov = accO[reg] * __fdividef(1.f, tot);
    int hd = khalf*32 + li;
    ushort_t hi, lo; split_bf(ov, hi, lo);
    size_t off = ((size_t)(b*SS + qt*64 + qrow))*1024 + h*64 + hd;
    oh[off] = hi; ol[off] = lo;
  }
}

// ---------------------------------------------------------------------------
// h = silu(gate)*up -> bf16 hi/lo [4096][2752] (zero pad)
// ---------------------------------------------------------------------------
__global__ __launch_bounds__(256) void silu_cvt(const float* __restrict__ gu,
                                                ushort_t* __restrict__ hh,
                                                ushort_t* __restrict__ hl){
  int q = blockIdx.x*256 + threadIdx.x;
  int row = blockIdx.y;
  if (q >= 688) return;
  int j = q*4;
  ushort_t h4[4] = {0,0,0,0}, l4[4] = {0,0,0,0};
  if (j < MFF){
    float4 g4 = *(const float4*)(gu + (size_t)row*5472 + j);
    float4 u4 = *(const float4*)(gu + (size_t)row*5472 + MFF + j);
    float v0 = g4.x/(1.f+__expf(-g4.x))*u4.x;
    float v1 = g4.y/(1.f+__expf(-g4.y))*u4.y;
    float v2 = g4.z/(1.f+__expf(-g4.z))*u4.z;
    float v3 = g4.w/(1.f+__expf(-g4.w))*u4.w;
    split_bf(v0,h4[0],l4[0]); split_bf(v1,h4[1],l4[1]);
    split_bf(v2,h4[2],l4[2]); split_bf(v3,h4[3],l4[3]);
  }
  size_t o = (size_t)row*MFFP + j;
  hh[o+0]=h4[0]; hh[o+1]=h4[1]; hh[o+2]=h4[2]; hh[o+3]=h4[3];
  hl[o+0]=l4[0]; hl[o+1]=l4[1]; hl[o+2]=l4[2]; hl[o+3]=l4[3];
}

// ---------------------------------------------------------------------------
extern "C" void kernel_launch(void* const* d_in, const int* in_sizes, int n_in,
                              void* d_out, int out_size, void* d_ws, size_t ws_size,
                              hipStream_t stream) {
  const float* x   = (const float*)d_in[0];
  const float* ln1 = (const float*)d_in[1];
  const float* wq  = (const float*)d_in[2];
  const float* sq  = (const float*)d_in[3];
  const float* bq  = (const float*)d_in[4];
  const float* wk  = (const float*)d_in[5];
  const float* sk  = (const float*)d_in[6];
  const float* bk  = (const float*)d_in[7];
  const float* wv  = (const float*)d_in[8];
  const float* sv  = (const float*)d_in[9];
  const float* bv  = (const float*)d_in[10];
  const float* qn  = (const float*)d_in[11];
  const float* kn  = (const float*)d_in[12];
  const float* wo  = (const float*)d_in[13];
  const float* so  = (const float*)d_in[14];
  const float* bo  = (const float*)d_in[15];
  const float* ln2 = (const float*)d_in[16];
  const float* wg  = (const float*)d_in[17];
  const float* sg  = (const float*)d_in[18];
  const float* bg  = (const float*)d_in[19];
  const float* wu  = (const float*)d_in[20];
  const float* su  = (const float*)d_in[21];
  const float* bu  = (const float*)d_in[22];
  const float* wd  = (const float*)d_in[23];
  const float* sd  = (const float*)d_in[24];
  const float* bd  = (const float*)d_in[25];

  float* ws  = (float*)d_ws;
  float* out = (float*)d_out;

  float* x2  = ws + OFF_X2;
  float* gu  = ws + OFF_GU;
  ushort_t* vtH = (ushort_t*)(ws + OFF_VT);
  ushort_t* vtL = vtH + (size_t)1024*4096;
  ushort_t* qhH = (ushort_t*)(ws + OFF_QH);
  ushort_t* qhL = qhH + (size_t)NT*1024;
  ushort_t* khH = qhH + (size_t)2*NT*1024;
  ushort_t* khL = qhH + (size_t)3*NT*1024;
  ushort_t* oH  = (ushort_t*)(ws + OFF_O);
  ushort_t* oL  = oH + (size_t)NT*1024;
  ushort_t* hH  = (ushort_t*)(ws + OFF_H);
  ushort_t* hL  = hH + (size_t)NT*MFFP;
  ushort_t* actH = (ushort_t*)(ws + OFF_ACT);
  ushort_t* actL = actH + (size_t)NT*1024;
  ushort_t* poolH = (ushort_t*)(ws + OFF_POOL);
  float* scaleArr = ws + OFF_SCALE;

  // ---- spectral sigma ----
  PowArgs pa;
  pa.W[0]=wq; pa.W[1]=wk; pa.W[2]=wv; pa.W[3]=wo; pa.W[4]=wg; pa.W[5]=wu; pa.W[6]=wd;
  pa.vvec = ws + OFF_VV; pa.uvec = ws + OFF_UU;
  for (int s=0; s<11; s++){
    pa.step = s;
    if ((s & 1) == 0){
      mv_notrans<<<2220, 256, 0, stream>>>(pa);
    } else {
      zero_uvec<<<7, 256, 0, stream>>>(pa.uvec);
      mv_trans<<<392, 256, 0, stream>>>(pa);
    }
  }
  SigArgs sa;
  sa.vvec = pa.vvec; sa.scale = scaleArr;
  sa.sp[0]=sq; sa.sp[1]=sk; sa.sp[2]=sv; sa.sp[3]=so; sa.sp[4]=sg; sa.sp[5]=su; sa.sp[6]=sd;
  sigma_scale_kernel<<<7, 256, 0, stream>>>(sa);

  // ---- attn_in = RMSNorm(x) ----
  rms_cvt<<<NT, 256, 0, stream>>>(x, ln1, actH, actL);

  GemmArgs ga;
  ga.resid = nullptr; ga.C = nullptr; ga.bias1 = nullptr;
  ga.nrm0 = ga.nrm1 = nullptr;
  ga.dH0 = ga.dL0 = ga.dH1 = ga.dL1 = nullptr;

  // ---- QK GEMM with fused per-head RMSNorm ----
  {
    ushort_t* bpL = poolH + (size_t)2048*1024;
    trans_cvt<<<dim3(32,32), 256, 0, stream>>>(wq, poolH,           bpL,           1024, 1024, 1024);
    trans_cvt<<<dim3(32,32), 256, 0, stream>>>(wk, poolH+1024*1024, bpL+1024*1024, 1024, 1024, 1024);
    ga.Ah = actH; ga.Al = actL; ga.Bh = poolH; ga.Bl = bpL;
    ga.bias0 = bq; ga.bias1 = bk; ga.nrm0 = qn; ga.nrm1 = kn;
    ga.dH0 = qhH; ga.dL0 = qhL; ga.dH1 = khH; ga.dL1 = khL;
    ga.scaleBase = scaleArr + 0;
    ga.Kd = 1024; ga.matN = 1024; ga.bpm = 8; ga.rowsPerMat = 1024;
    ga.Cstride = 0; ga.colOff = 0;
    gemm_bf3<4,1><<<dim3(16,32), 256, 0, stream>>>(ga);
  }

  // ---- V^T GEMM (bf16 hi/lo out [vdim][token]) ----
  {
    ushort_t* bpL = poolH + (size_t)1024*1024;
    trans_cvt<<<dim3(32,32), 256, 0, stream>>>(wv, poolH, bpL, 1024, 1024, 1024);
    ga.Ah = poolH; ga.Al = bpL; ga.Bh = actH; ga.Bl = actL;
    ga.bias0 = bv; ga.bias1 = nullptr; ga.nrm0 = ga.nrm1 = nullptr;
    ga.dH0 = vtH; ga.dL0 = vtL; ga.dH1 = ga.dL1 = nullptr;
    ga.scaleBase = scaleArr + 2;
    ga.Kd = 1024; ga.matN = 4096; ga.bpm = 64; ga.rowsPerMat = 4096;
    ga.Cstride = 0; ga.colOff = 0;
    gemm_bf3<2,2><<<dim3(64,8), 256, 0, stream>>>(ga);
  }

  // ---- attention ----
  attn_mfma<<<dim3(16,16,4), 256, 0, stream>>>(qhH, qhL, khH, khL, vtH, vtL, oH, oL);

  // ---- out projection + residual ----
  {
    ushort_t* bpL = poolH + (size_t)1024*1024;
    trans_cvt<<<dim3(32,32), 256, 0, stream>>>(wo, poolH, bpL, 1024, 1024, 1024);
    ga.Ah = oH; ga.Al = oL; ga.Bh = poolH; ga.Bl = bpL;
    ga.C = x2; ga.bias0 = bo;
    ga.dH0 = ga.dL0 = nullptr;
    ga.scaleBase = scaleArr + 3; ga.resid = x;
    ga.Kd = 1024; ga.matN = 1024; ga.bpm = 16; ga.rowsPerMat = 1024;
    ga.Cstride = 1024; ga.colOff = 0;
    gemm_bf3<2,0><<<dim3(16,32), 256, 0, stream>>>(ga);
  }

  // ---- mlp_in = RMSNorm(x2) ----
  rms_cvt<<<NT, 256, 0, stream>>>(x2, ln2, actH, actL);

  // ---- gate / up GEMMs ----
  {
    ushort_t* bpL = poolH + (size_t)2816*1024;
    trans_cvt<<<dim3(32,88), 256, 0, stream>>>(wg, poolH, bpL, 1024, MFF, 1024);
    ga.Ah = actH; ga.Al = actL; ga.Bh = poolH; ga.Bl = bpL;
    ga.C = gu; ga.bias0 = bg;
    ga.scaleBase = scaleArr + 4; ga.resid = nullptr;
    ga.Kd = 1024; ga.matN = MFF; ga.bpm = 22; ga.rowsPerMat = 2816;
    ga.Cstride = 5472; ga.colOff = 0;
    gemm_bf3<4,0><<<dim3(22,32), 256, 0, stream>>>(ga);

    trans_cvt<<<dim3(32,88), 256, 0, stream>>>(wu, poolH, bpL, 1024, MFF, 1024);
    ga.bias0 = bu; ga.scaleBase = scaleArr + 5; ga.colOff = MFF;
    gemm_bf3<4,0><<<dim3(22,32), 256, 0, stream>>>(ga);
  }

  // ---- h = silu(gate)*up ----
  silu_cvt<<<dim3(3, NT), 256, 0, stream>>>(gu, hH, hL);

  // ---- down GEMM + residual -> out ----
  {
    ushort_t* bpL = poolH + (size_t)1024*MFFP;
    trans_cvt<<<dim3(86,32), 256, 0, stream>>>(wd, poolH, bpL, MFF, 1024, MFFP);
    ga.Ah = hH; ga.Al = hL; ga.Bh = poolH; ga.Bl = bpL;
    ga.C = out; ga.bias0 = bd;
    ga.scaleBase = scaleArr + 6; ga.resid = x2;
    ga.Kd = MFFP; ga.matN = 1024; ga.bpm = 16; ga.rowsPerMat = 1024;
    ga.Cstride = 1024; ga.colOff = 0;
    gemm_bf3<2,0><<<dim3(16,32), 256, 0, stream>>>(ga);
  }
}

// Round 4
// 1048.874 us; speedup vs baseline: 3.4916x; 1.0808x over previous
//
#include <hip/hip_runtime.h>
#include <math.h>
#include <stddef.h>
#include <stdint.h>

// Problem constants
#define BB   4
#define SS   1024
#define DD   1024
#define HH   16
#define HDD  64
#define NT   (BB*SS)      // 4096 tokens
#define MFF  2736
#define MFFP 2752
#define EPSF 1e-6f

typedef unsigned int   u32;
typedef unsigned short ushort_t;
typedef float  f32x4   __attribute__((ext_vector_type(4)));
typedef float  f32x16  __attribute__((ext_vector_type(16)));
typedef short  s16x8   __attribute__((ext_vector_type(8)));

typedef const __attribute__((address_space(1))) u32 glb_u32;
typedef __attribute__((address_space(3))) u32 lds_u32;

// ---------------------------------------------------------------------------
// Workspace layout (float units). Total ~163.2 MB (proven budget >= 164.26).
// Timeline: bf1(power phase)@OFF_O; vt(4-6)@OFF_VT; qh/kh(3-6)@OFF_QH;
// o(6-7)@OFF_O; gate fp32(9-10)@OFF_GU; h(10-11)@OFF_O; act(2-4,8-10)@OFF_ACT
// ---------------------------------------------------------------------------
static const size_t OFF_X2    = 0;                    // fp32 [4096][1024]
static const size_t OFF_GU    = 4194304;              // gate fp32 [4096][2736]
static const size_t OFF_VT    = 4194304;              // vtH/vtL u16 [1024][4096]
static const size_t OFF_QH    = 8388608;              // qhH,qhL,khH,khL u16
static const size_t OFF_O     = 16777216;             // oH,oL / bf1 / hH,hL
static const size_t OFF_ACT   = 26607616;             // actH,actL u16 [4096][1024]
static const size_t OFF_POOL  = 37879808;             // weight pool (2,883,584 fl)
static const size_t OFF_VV    = 40763392;             // 7*2736
static const size_t OFF_UU    = 40782544;             // 7*2736
static const size_t OFF_SCALE = 40801696;             // 7 (+pad)

// ---------------------------------------------------------------------------
__device__ inline ushort_t f2bf(float x){
  u32 u = __float_as_uint(x);
  u32 r = (u + 0x7fffu + ((u >> 16) & 1u)) >> 16;
  return (ushort_t)r;
}
__device__ inline void split_bf(float x, ushort_t& hi, ushort_t& lo){
  hi = f2bf(x);
  float hf = __uint_as_float(((u32)hi) << 16);
  lo = f2bf(x - hf);
}
__device__ inline float bf2f(ushort_t u){
  return __uint_as_float(((u32)u) << 16);
}
__device__ inline s16x8 mk8(u32 a, u32 b, u32 c, u32 d){
  union { u32 w[4]; s16x8 v; } u;
  u.w[0]=a; u.w[1]=b; u.w[2]=c; u.w[3]=d;
  return u.v;
}

// 256-thread block sum (uses 4-entry LDS scratch)
__device__ inline float block_sum256(float v, float* red){
  #pragma unroll
  for (int off=32; off>=1; off>>=1) v += __shfl_down(v, off);
  int lane = threadIdx.x & 63, wave = threadIdx.x >> 6;
  if (lane == 0) red[wave] = v;
  __syncthreads();
  return red[0]+red[1]+red[2]+red[3];
}

// ---------------------------------------------------------------------------
// Weight -> bf16 (hi) convert for power iteration. All 7 matrices.
// ---------------------------------------------------------------------------
struct W2Args { const float* W[7]; ushort_t* dst; };
__global__ __launch_bounds__(256) void w2bf(W2Args a){
  const int BST[8] = {0,512,1024,1536,2048,3416,4784,6152};
  const size_t OFFU[7] = {0,1048576,2097152,3145728,4194304,6995968,9797632};
  int blk = blockIdx.x; int m = 0;
  #pragma unroll
  for (int i=1;i<7;i++) if (blk >= BST[i]) m = i;
  size_t e = (size_t)(blk - BST[m])*2048 + threadIdx.x*8;
  const float* src = a.W[m] + e;
  float4 v0 = *(const float4*)src;
  float4 v1 = *(const float4*)(src + 4);
  union { ushort_t o[8]; s16x8 v; } u;
  u.o[0]=f2bf(v0.x); u.o[1]=f2bf(v0.y); u.o[2]=f2bf(v0.z); u.o[3]=f2bf(v0.w);
  u.o[4]=f2bf(v1.x); u.o[5]=f2bf(v1.y); u.o[6]=f2bf(v1.z); u.o[7]=f2bf(v1.w);
  *(s16x8*)(a.dst + OFFU[m] + e) = u.v;
}

// ---------------------------------------------------------------------------
// Power iteration on bf16 weights.
// even step: vvec = W @ u_normalized ; odd: uvec += W^T @ v_normalized
// ---------------------------------------------------------------------------
struct PowArgs {
  const ushort_t* Wb;
  float* vvec; float* uvec; int step;
};

__global__ __launch_bounds__(256) void zero_uvec(float* uvec){
  int m = blockIdx.x;
  for (int i=threadIdx.x; i<2736; i+=256) uvec[m*2736+i] = 0.f;
}

__global__ __launch_bounds__(256) void mv_notrans(PowArgs pa){
  const int NIN [7] = {1024,1024,1024,1024,1024,1024,2736};
  const int NOUT[7] = {1024,1024,1024,1024,2736,2736,1024};
  const int BST [8] = {0,256,512,768,1024,1280,1536,2220};
  const size_t OFFU[7] = {0,1048576,2097152,3145728,4194304,6995968,9797632};
  __shared__ float red[4];
  int blk = blockIdx.x;
  int m = 0;
  #pragma unroll
  for (int i=1;i<7;i++) if (blk >= BST[i]) m = i;
  int nin = NIN[m], nout = NOUT[m];
  int st = pa.step;
  float inv;
  const float* x = pa.uvec + m*2736;
  if (st == 0){
    inv = 1.f/(sqrtf((float)nout)+EPSF);
  } else {
    float s = 0.f;
    for (int i=threadIdx.x; i<nout; i+=256){ float u = x[i]; s += u*u; }
    float tot = block_sum256(s, red);
    inv = 1.f/(sqrtf(tot)+EPSF);
  }
  int wave = threadIdx.x >> 6, lane = threadIdx.x & 63;
  int row = (blk - BST[m])*4 + wave;
  if (row >= nin) return;
  const ushort_t* W = pa.Wb + OFFU[m];
  float sum = 0.f;
  if (st == 0){
    for (int j=lane*8; j<nout; j+=512){
      s16x8 w8 = *(const s16x8*)(W + (size_t)row*nout + j);
      #pragma unroll
      for (int e=0;e<8;e++) sum += bf2f((ushort_t)w8[e]);
    }
  } else {
    for (int j=lane*8; j<nout; j+=512){
      s16x8 w8 = *(const s16x8*)(W + (size_t)row*nout + j);
      float4 xa = *(const float4*)(x + j);
      float4 xb = *(const float4*)(x + j + 4);
      sum += bf2f((ushort_t)w8[0])*xa.x + bf2f((ushort_t)w8[1])*xa.y
           + bf2f((ushort_t)w8[2])*xa.z + bf2f((ushort_t)w8[3])*xa.w
           + bf2f((ushort_t)w8[4])*xb.x + bf2f((ushort_t)w8[5])*xb.y
           + bf2f((ushort_t)w8[6])*xb.z + bf2f((ushort_t)w8[7])*xb.w;
    }
  }
  #pragma unroll
  for (int off=32; off>=1; off>>=1) sum += __shfl_down(sum, off);
  if (lane == 0) pa.vvec[m*2736+row] = sum*inv;
}

__global__ __launch_bounds__(256) void mv_trans(PowArgs pa){
  const int NIN [7] = {1024,1024,1024,1024,1024,1024,2736};
  const int NOUT[7] = {1024,1024,1024,1024,2736,2736,1024};
  const int BST [8] = {0,32,64,96,128,216,304,392};
  const int RCH [7] = {8,8,8,8,8,8,22};
  const size_t OFFU[7] = {0,1048576,2097152,3145728,4194304,6995968,9797632};
  __shared__ float red[4];
  int blk = blockIdx.x;
  int m = 0;
  #pragma unroll
  for (int i=1;i<7;i++) if (blk >= BST[i]) m = i;
  int nin = NIN[m], nout = NOUT[m];
  const float* v = pa.vvec + m*2736;
  float s = 0.f;
  for (int i=threadIdx.x; i<nin; i+=256){ float t = v[i]; s += t*t; }
  float tot = block_sum256(s, red);
  float inv = 1.f/(sqrtf(tot)+EPSF);
  int local = blk - BST[m];
  int ct = local / RCH[m], rc = local % RCH[m];
  int col = ct*256 + threadIdx.x;
  int r0 = rc*128, r1 = min(nin, r0+128);
  if (col >= nout) return;
  const ushort_t* W = pa.Wb + OFFU[m];
  float partial = 0.f;
  for (int r=r0; r<r1; ++r)
    partial += bf2f(W[(size_t)r*nout + col])*(v[r]*inv);
  atomicAdd(&pa.uvec[m*2736+col], partial);
}

struct SigArgs {
  const float* vvec; float* scale;
  const float* sp[7];
};
__global__ __launch_bounds__(256) void sigma_scale_kernel(SigArgs sa){
  const int NIN [7] = {1024,1024,1024,1024,1024,1024,2736};
  __shared__ float red[4];
  int m = blockIdx.x;
  const float* v = sa.vvec + m*2736;
  float s = 0.f;
  for (int i=threadIdx.x; i<NIN[m]; i+=256){ float t = v[i]; s += t*t; }
  float a = block_sum256(s, red);
  if (threadIdx.x == 0){
    float S = sqrtf(a);
    float sig = a/(S+EPSF);
    sig = fmaxf(sig, EPSF);
    sa.scale[m] = sa.sp[m][0]/sig;
  }
}

// ---------------------------------------------------------------------------
// Transpose + convert: src fp32 [K][N] -> dst hi/lo bf16 [n][k], zero-padded
// ---------------------------------------------------------------------------
__global__ __launch_bounds__(256) void trans_cvt(const float* __restrict__ src,
                                                 ushort_t* __restrict__ dh,
                                                 ushort_t* __restrict__ dl,
                                                 int K, int N, int Kpad){
  __shared__ float t[32][33];
  int k0 = blockIdx.x*32, n0 = blockIdx.y*32;
  int c = threadIdx.x & 31, rb = threadIdx.x >> 5;
  #pragma unroll
  for (int i=0;i<4;i++){
    int r = rb + i*8;
    int kk = k0 + r, nn = n0 + c;
    t[r][c] = (kk<K && nn<N) ? src[(size_t)kk*N + nn] : 0.f;
  }
  __syncthreads();
  #pragma unroll
  for (int i=0;i<4;i++){
    int r = rb + i*8;
    int nn = n0 + r, kk = k0 + c;
    float v = t[c][r];
    ushort_t hi, lo; split_bf(v, hi, lo);
    size_t o = (size_t)nn*Kpad + kk;
    dh[o] = hi; dl[o] = lo;
  }
}

// ---------------------------------------------------------------------------
// RMSNorm over D=1024 -> bf16 hi/lo
// ---------------------------------------------------------------------------
__global__ __launch_bounds__(256) void rms_cvt(const float* __restrict__ in,
                                               const float* __restrict__ scale,
                                               ushort_t* __restrict__ oh,
                                               ushort_t* __restrict__ ol){
  int row = blockIdx.x;
  int tid = threadIdx.x;
  const float* p = in + (size_t)row*DD;
  float4 vx = *(const float4*)(p + tid*4);
  float ss = vx.x*vx.x + vx.y*vx.y + vx.z*vx.z + vx.w*vx.w;
  int lane = tid & 63, wave = tid >> 6;
  #pragma unroll
  for (int off=32; off>=1; off>>=1) ss += __shfl_down(ss, off);
  __shared__ float red[4];
  if (lane == 0) red[wave] = ss;
  __syncthreads();
  float tot = red[0]+red[1]+red[2]+red[3];
  float r = rsqrtf(tot*(1.f/DD)+EPSF);
  float4 sc = *(const float4*)(scale + tid*4);
  float o0 = vx.x*r*sc.x, o1 = vx.y*r*sc.y, o2 = vx.z*r*sc.z, o3 = vx.w*r*sc.w;
  ushort_t h[4], l[4];
  split_bf(o0,h[0],l[0]); split_bf(o1,h[1],l[1]);
  split_bf(o2,h[2],l[2]); split_bf(o3,h[3],l[3]);
  size_t o = (size_t)row*DD + tid*4;
  oh[o+0]=h[0]; oh[o+1]=h[1]; oh[o+2]=h[2]; oh[o+3]=h[3];
  ol[o+0]=l[0]; ol[o+1]=l[1]; ol[o+2]=l[2]; ol[o+3]=l[3];
}

// ---------------------------------------------------------------------------
// bf16x3 split MFMA GEMM with selectable epilogue.
//  EPI 0: C fp32 [M][Cstride] = s*(A@B^T) + bias0[col] (+resid)
//  EPI 1: QK fused per-head RMSNorm -> bf16 hi/lo head-major dst (2 mats)
//  EPI 2: VT: bf16 hi/lo out at [row][col], bias0 per ROW
//  EPI 3: up-proj: h = silu(gate)*v -> bf16 hi/lo [row][MFFP] (gate read from C)
// ---------------------------------------------------------------------------
struct GemmArgs {
  const ushort_t *Ah, *Al, *Bh, *Bl;
  float* C;
  const float *bias0, *bias1;
  const float *nrm0, *nrm1;
  ushort_t *dH0, *dL0, *dH1, *dL1;
  const float* scaleBase;
  const float* resid;
  int Kd, matN, bpm, rowsPerMat, Cstride, colOff;
};

template<int FN, int EPI>
__global__ __launch_bounds__(256) void gemm_bf3(GemmArgs g){
  constexpr int BN   = FN*32;
  constexpr int SEGB = BN/16;
  constexpr int NSEG = 16 + 2*SEGB;
  constexpr int NSEGT = NSEG/4;
  constexpr int LDSB = 16384 + 2*BN*64;
  __shared__ __align__(16) char lds[LDSB];

  const int tid = threadIdx.x;
  const int w = tid >> 6, l = tid & 63;
  const int bm = blockIdx.y*128;
  const int mat = blockIdx.x / g.bpm;
  const int n0m = (blockIdx.x % g.bpm) * BN;
  const int nrow0 = mat*g.rowsPerMat + n0m;

  const ushort_t* sp[NSEGT];
  u32 loff[NSEGT];
  #pragma unroll
  for (int i=0;i<NSEGT;i++){
    int s = w + i*4;
    int ci, r, c, csrc;
    if (s < 16){
      int abuf = s >> 3, segi = s & 7;
      ci = segi*64 + l; r = ci >> 2; c = ci & 3;
      csrc = c ^ ((r >> 1) & 3);
      sp[i] = (abuf ? g.Al : g.Ah) + (size_t)(bm + r)*g.Kd + csrc*8;
      loff[i] = (u32)(abuf*8192 + ci*16);
    } else {
      int tt = s - 16;
      int bbuf = tt / SEGB, segi = tt % SEGB;
      ci = segi*64 + l; r = ci >> 2; c = ci & 3;
      csrc = c ^ ((r >> 1) & 3);
      sp[i] = (bbuf ? g.Bl : g.Bh) + (size_t)(nrow0 + r)*g.Kd + csrc*8;
      loff[i] = (u32)(16384 + bbuf*(BN*64) + ci*16);
    }
  }

  const int wm = w >> 1, wn = w & 1;
  const int li = l & 15, kq = l >> 4;
  const int sx = kq ^ ((li >> 1) & 3);
  const char* lb = (const char*)lds;
  const u32 aOff = (u32)((wm*64 + li)*64 + sx*16);
  const u32 bOff = (u32)(16384 + (wn*(FN*16) + li)*64 + sx*16);

  f32x4 acc[4][FN];
  #pragma unroll
  for (int mi=0;mi<4;mi++)
    #pragma unroll
    for (int ni=0;ni<FN;ni++)
      acc[mi][ni] = (f32x4){0.f,0.f,0.f,0.f};

  for (int k0=0; k0<g.Kd; k0+=32){
    #pragma unroll
    for (int i=0;i<NSEGT;i++){
      __builtin_amdgcn_global_load_lds((glb_u32*)sp[i], (lds_u32*)(lds + loff[i]), 16, 0, 0);
      sp[i] += 32;
    }
    __syncthreads();
    s16x8 ah[4], al[4];
    #pragma unroll
    for (int mi=0;mi<4;mi++){
      ah[mi] = *(const s16x8*)(lb + aOff + mi*1024);
      al[mi] = *(const s16x8*)(lb + 8192 + aOff + mi*1024);
    }
    #pragma unroll
    for (int ni=0;ni<FN;ni++){
      s16x8 bh = *(const s16x8*)(lb + bOff + ni*1024);
      s16x8 bl = *(const s16x8*)(lb + BN*64 + bOff + ni*1024);
      #pragma unroll
      for (int mi=0;mi<4;mi++){
        f32x4 t = acc[mi][ni];
        t = __builtin_amdgcn_mfma_f32_16x16x32_bf16(ah[mi], bh, t, 0, 0, 0);
        t = __builtin_amdgcn_mfma_f32_16x16x32_bf16(ah[mi], bl, t, 0, 0, 0);
        t = __builtin_amdgcn_mfma_f32_16x16x32_bf16(al[mi], bh, t, 0, 0, 0);
        acc[mi][ni] = t;
      }
    }
    __syncthreads();
  }

  if constexpr (EPI == 0){
    const float s = g.scaleBase[mat];
    const float* bias = g.bias0;
    const int colBase = n0m + wn*(FN*16);
    #pragma unroll
    for (int ni=0;ni<FN;ni++){
      int cm = colBase + ni*16 + li;
      if (cm < g.matN){
        int cg = cm + g.colOff;
        float bv = bias[cm];
        #pragma unroll
        for (int mi=0;mi<4;mi++){
          f32x4 a = acc[mi][ni];
          int r0 = bm + wm*64 + mi*16 + kq*4;
          #pragma unroll
          for (int j=0;j<4;j++){
            float v = s*a[j] + bv;
            size_t off = (size_t)(r0+j)*g.Cstride + cg;
            if (g.resid) v += g.resid[off];
            g.C[off] = v;
          }
        }
      }
    }
  } else if constexpr (EPI == 1){
    const float s = g.scaleBase[mat];
    const float* bias = mat ? g.bias1 : g.bias0;
    const float* nsc  = mat ? g.nrm1  : g.nrm0;
    ushort_t* dH = mat ? g.dH1 : g.dH0;
    ushort_t* dL = mat ? g.dL1 : g.dL0;
    const int hidx = (n0m >> 6) + wn;
    float bv[FN], nv[FN];
    #pragma unroll
    for (int ni=0;ni<FN;ni++){
      int cm = n0m + wn*64 + ni*16 + li;
      bv[ni] = bias[cm];
      nv[ni] = nsc[ni*16 + li];
    }
    #pragma unroll
    for (int mi=0;mi<4;mi++){
      #pragma unroll
      for (int j=0;j<4;j++){
        float vv[FN]; float ssq = 0.f;
        #pragma unroll
        for (int ni=0;ni<FN;ni++){
          vv[ni] = s*acc[mi][ni][j] + bv[ni];
          ssq += vv[ni]*vv[ni];
        }
        ssq += __shfl_xor(ssq, 1);
        ssq += __shfl_xor(ssq, 2);
        ssq += __shfl_xor(ssq, 4);
        ssq += __shfl_xor(ssq, 8);
        float rr = rsqrtf(ssq*(1.f/64.f)+EPSF);
        int row = bm + wm*64 + mi*16 + kq*4 + j;
        size_t base = (((size_t)(row>>10)*16 + hidx)*1024 + (row & 1023))*64;
        #pragma unroll
        for (int ni=0;ni<FN;ni++){
          ushort_t hi, lo; split_bf(vv[ni]*rr*nv[ni], hi, lo);
          dH[base + ni*16 + li] = hi;
          dL[base + ni*16 + li] = lo;
        }
      }
    }
  } else if constexpr (EPI == 2){
    const float s = g.scaleBase[0];
    #pragma unroll
    for (int mi=0;mi<4;mi++){
      #pragma unroll
      for (int j=0;j<4;j++){
        int row = bm + wm*64 + mi*16 + kq*4 + j;
        float bvr = g.bias0[row];
        #pragma unroll
        for (int ni=0;ni<FN;ni++){
          int cm = n0m + wn*(FN*16) + ni*16 + li;
          float v = s*acc[mi][ni][j] + bvr;
          ushort_t hi, lo; split_bf(v, hi, lo);
          g.dH0[(size_t)row*4096 + cm] = hi;
          g.dL0[(size_t)row*4096 + cm] = lo;
        }
      }
    }
  } else {
    // EPI 3: h = silu(gate)*up -> bf16 hi/lo [row][MFFP]; gate fp32 from g.C
    const float s = g.scaleBase[0];
    const int colBase = n0m + wn*(FN*16);
    #pragma unroll
    for (int ni=0;ni<FN;ni++){
      int cm = colBase + ni*16 + li;
      if (cm < MFFP){
        bool ok = cm < g.matN;
        float bv = ok ? g.bias0[cm] : 0.f;
        #pragma unroll
        for (int mi=0;mi<4;mi++){
          #pragma unroll
          for (int j=0;j<4;j++){
            int row = bm + wm*64 + mi*16 + kq*4 + j;
            ushort_t hb = 0, lb2 = 0;
            if (ok){
              float uv = s*acc[mi][ni][j] + bv;
              float gv = g.C[(size_t)row*g.Cstride + cm];
              float hv = gv * __builtin_amdgcn_rcpf(1.f + __expf(-gv)) * uv;
              split_bf(hv, hb, lb2);
            }
            size_t ho = (size_t)row*MFFP + cm;
            g.dH0[ho] = hb; g.dL0[ho] = lb2;
          }
        }
      }
    }
  }
}

// ---------------------------------------------------------------------------
// MFMA flash attention, in-register P (swapped-operand QK^T).
// Block: 64 q-rows x one (b,h). 4 waves: qhalf=w>>1, khalf=w&1.
// K/V double-buffered in LDS (144B padded rows); Q in registers.
// softcap identity: exp(50*tanh(t/50)) = e^50 * exp(-100/(e^(t/25)+1));
// the e^50 constant cancels in softmax normalization.
// ---------------------------------------------------------------------------
__global__ __launch_bounds__(256) void attn_mfma(const ushort_t* __restrict__ qh, const ushort_t* __restrict__ ql,
                                                 const ushort_t* __restrict__ kh, const ushort_t* __restrict__ kl,
                                                 const ushort_t* __restrict__ vh, const ushort_t* __restrict__ vl,
                                                 ushort_t* __restrict__ oh, ushort_t* __restrict__ ol){
  __shared__ __align__(16) char lds[74240];   // K dbuf 2x18432 | V dbuf 2x18432 | 128 floats
  const int qt = blockIdx.x, h = blockIdx.y, b = blockIdx.z;
  const int tid = threadIdx.x;
  const int l = tid & 63, li = tid & 31, hi = (tid >> 5) & 1;
  const int w = tid >> 6, qhalf = w >> 1, khalf = w & 1;
  const int r0 = tid >> 3, ch = tid & 7;    // staging slot (row, 16B chunk)

  // ---- Q direct to registers ----
  const size_t qrow = ((size_t)(b*HH + h)*SS + qt*64 + qhalf*32 + li)*64;
  s16x8 aQh[4], aQl[4];
  #pragma unroll
  for (int ks=0; ks<4; ks++){
    aQh[ks] = *(const s16x8*)(qh + qrow + ks*16 + hi*8);
    aQl[ks] = *(const s16x8*)(ql + qrow + ks*16 + hi*8);
  }

  const size_t kbase = (size_t)(b*HH + h)*SS*64;
  const size_t vbase = (size_t)h*64*4096 + (size_t)b*SS;

  f32x16 accO0 = (f32x16){0,0,0,0,0,0,0,0,0,0,0,0,0,0,0,0};
  f32x16 accO1 = (f32x16){0,0,0,0,0,0,0,0,0,0,0,0,0,0,0,0};
  float psum = 0.f;

  s16x8 rKh0,rKh1,rKl0,rKl1,rVh0,rVh1,rVl0,rVl1;
  // prologue: stage kt=0
  rKh0 = *(const s16x8*)(kh + kbase + (size_t)r0*64 + ch*8);
  rKh1 = *(const s16x8*)(kh + kbase + (size_t)(r0+32)*64 + ch*8);
  rKl0 = *(const s16x8*)(kl + kbase + (size_t)r0*64 + ch*8);
  rKl1 = *(const s16x8*)(kl + kbase + (size_t)(r0+32)*64 + ch*8);
  rVh0 = *(const s16x8*)(vh + vbase + (size_t)r0*4096 + ch*8);
  rVh1 = *(const s16x8*)(vh + vbase + (size_t)(r0+32)*4096 + ch*8);
  rVl0 = *(const s16x8*)(vl + vbase + (size_t)r0*4096 + ch*8);
  rVl1 = *(const s16x8*)(vl + vbase + (size_t)(r0+32)*4096 + ch*8);
  {
    char* Kb = lds;  char* Vb = lds + 36864;
    *(s16x8*)(Kb + r0*144 + ch*16) = rKh0;
    *(s16x8*)(Kb + (r0+32)*144 + ch*16) = rKh1;
    *(s16x8*)(Kb + 9216 + r0*144 + ch*16) = rKl0;
    *(s16x8*)(Kb + 9216 + (r0+32)*144 + ch*16) = rKl1;
    *(s16x8*)(Vb + r0*144 + ch*16) = rVh0;
    *(s16x8*)(Vb + (r0+32)*144 + ch*16) = rVh1;
    *(s16x8*)(Vb + 9216 + r0*144 + ch*16) = rVl0;
    *(s16x8*)(Vb + 9216 + (r0+32)*144 + ch*16) = rVl1;
  }
  __syncthreads();

  int cur = 0;
  for (int kt=0; kt<16; kt++){
    // issue next-tile loads early (latency hides under compute)
    if (kt < 15){
      const size_t kb = kbase + (size_t)(kt+1)*64*64;
      const size_t vb = vbase + (size_t)(kt+1)*64;
      rKh0 = *(const s16x8*)(kh + kb + (size_t)r0*64 + ch*8);
      rKh1 = *(const s16x8*)(kh + kb + (size_t)(r0+32)*64 + ch*8);
      rKl0 = *(const s16x8*)(kl + kb + (size_t)r0*64 + ch*8);
      rKl1 = *(const s16x8*)(kl + kb + (size_t)(r0+32)*64 + ch*8);
      rVh0 = *(const s16x8*)(vh + vb + (size_t)r0*4096 + ch*8);
      rVh1 = *(const s16x8*)(vh + vb + (size_t)(r0+32)*4096 + ch*8);
      rVl0 = *(const s16x8*)(vl + vb + (size_t)r0*4096 + ch*8);
      rVl1 = *(const s16x8*)(vl + vb + (size_t)(r0+32)*4096 + ch*8);
    }
    const char* Kc = lds + cur*18432;
    const char* Vc = lds + 36864 + cur*18432;

    // S^T = K Q^T (swapped operands): D col = q (li), D rows = keys
    f32x16 sF = (f32x16){0,0,0,0,0,0,0,0,0,0,0,0,0,0,0,0};
    #pragma unroll
    for (int ks=0; ks<4; ks++){
      s16x8 kfh = *(const s16x8*)(Kc + (khalf*32+li)*144 + ks*32 + hi*16);
      s16x8 kfl = *(const s16x8*)(Kc + 9216 + (khalf*32+li)*144 + ks*32 + hi*16);
      sF = __builtin_amdgcn_mfma_f32_32x32x16_bf16(kfh, aQh[ks], sF, 0, 0, 0);
      sF = __builtin_amdgcn_mfma_f32_32x32x16_bf16(kfl, aQh[ks], sF, 0, 0, 0);
      sF = __builtin_amdgcn_mfma_f32_32x32x16_bf16(kfh, aQl[ks], sF, 0, 0, 0);
    }

    // softcap (scaled): p = exp(-100/(exp(s*0.005)+1))
    float p[16];
    #pragma unroll
    for (int r=0; r<16; r++){
      float wv = __expf(sF[r]*0.005f);
      float rc = __builtin_amdgcn_rcpf(wv + 1.f);
      float pv = __expf(-100.f*rc);
      p[r] = pv;
      psum += pv;
    }

    // split hi/lo (truncation) + pack into bf16 pairs per key-quad
    u32 cH[8], cL[8];
    #pragma unroll
    for (int m=0; m<4; m++){
      u32 u0 = __float_as_uint(p[4*m+0]), u1 = __float_as_uint(p[4*m+1]);
      u32 u2 = __float_as_uint(p[4*m+2]), u3 = __float_as_uint(p[4*m+3]);
      u32 m0 = u0 & 0xffff0000u, m1 = u1 & 0xffff0000u;
      u32 m2 = u2 & 0xffff0000u, m3 = u3 & 0xffff0000u;
      cH[2*m+0] = m1 | (m0 >> 16);
      cH[2*m+1] = m3 | (m2 >> 16);
      u32 k0 = __float_as_uint(p[4*m+0] - __uint_as_float(m0));
      u32 k1 = __float_as_uint(p[4*m+1] - __uint_as_float(m1));
      u32 k2 = __float_as_uint(p[4*m+2] - __uint_as_float(m2));
      u32 k3 = __float_as_uint(p[4*m+3] - __uint_as_float(m3));
      cL[2*m+0] = (k1 & 0xffff0000u) | (k0 >> 16);
      cL[2*m+1] = (k3 & 0xffff0000u) | (k2 >> 16);
    }

    // PV: build A-frags via lane<->lane+32 exchange, accumulate O
    #pragma unroll
    for (int ks2=0; ks2<2; ks2++){
      u32 A0 = cH[4*ks2+0], A1 = cH[4*ks2+1], B0 = cH[4*ks2+2], B1 = cH[4*ks2+3];
      u32 As0 = (u32)__shfl_xor((int)A0, 32), As1 = (u32)__shfl_xor((int)A1, 32);
      u32 Bs0 = (u32)__shfl_xor((int)B0, 32), Bs1 = (u32)__shfl_xor((int)B1, 32);
      s16x8 paH = mk8(hi ? Bs0 : A0, hi ? Bs1 : A1, hi ? B0 : As0, hi ? B1 : As1);
      u32 C0 = cL[4*ks2+0], C1 = cL[4*ks2+1], D0 = cL[4*ks2+2], D1 = cL[4*ks2+3];
      u32 Cs0 = (u32)__shfl_xor((int)C0, 32), Cs1 = (u32)__shfl_xor((int)C1, 32);
      u32 Ds0 = (u32)__shfl_xor((int)D0, 32), Ds1 = (u32)__shfl_xor((int)D1, 32);
      s16x8 paL = mk8(hi ? Ds0 : C0, hi ? Ds1 : C1, hi ? D0 : Cs0, hi ? D1 : Cs1);

      {
        const char* vp = Vc + (0*32+li)*144 + khalf*64 + ks2*32 + hi*16;
        s16x8 vfh = *(const s16x8*)vp;
        s16x8 vfl = *(const s16x8*)(vp + 9216);
        accO0 = __builtin_amdgcn_mfma_f32_32x32x16_bf16(paH, vfh, accO0, 0, 0, 0);
        accO0 = __builtin_amdgcn_mfma_f32_32x32x16_bf16(paH, vfl, accO0, 0, 0, 0);
        accO0 = __builtin_amdgcn_mfma_f32_32x32x16_bf16(paL, vfh, accO0, 0, 0, 0);
      }
      {
        const char* vp = Vc + (32+li)*144 + khalf*64 + ks2*32 + hi*16;
        s16x8 vfh = *(const s16x8*)vp;
        s16x8 vfl = *(const s16x8*)(vp + 9216);
        accO1 = __builtin_amdgcn_mfma_f32_32x32x16_bf16(paH, vfh, accO1, 0, 0, 0);
        accO1 = __builtin_amdgcn_mfma_f32_32x32x16_bf16(paH, vfl, accO1, 0, 0, 0);
        accO1 = __builtin_amdgcn_mfma_f32_32x32x16_bf16(paL, vfh, accO1, 0, 0, 0);
      }
    }

    __syncthreads();   // all waves done reading buf[cur]
    if (kt < 15){
      char* Kb = lds + (cur^1)*18432;
      char* Vb = lds + 36864 + (cur^1)*18432;
      *(s16x8*)(Kb + r0*144 + ch*16) = rKh0;
      *(s16x8*)(Kb + (r0+32)*144 + ch*16) = rKh1;
      *(s16x8*)(Kb + 9216 + r0*144 + ch*16) = rKl0;
      *(s16x8*)(Kb + 9216 + (r0+32)*144 + ch*16) = rKl1;
      *(s16x8*)(Vb + r0*144 + ch*16) = rVh0;
      *(s16x8*)(Vb + (r0+32)*144 + ch*16) = rVh1;
      *(s16x8*)(Vb + 9216 + r0*144 + ch*16) = rVl0;
      *(s16x8*)(Vb + 9216 + (r0+32)*144 + ch*16) = rVl1;
      __syncthreads();
      cur ^= 1;
    }
  }

  // ---- epilogue: softmax denominators + cross-wave O combine ----
  float tot = psum + __shfl_xor(psum, 32);   // full 32-key (khalf) sum for q = qhalf*32+li
  float* smA = (float*)(lds + 73728);
  float* smB = smA + 64;
  float* ex  = (float*)lds;                   // overlay on K buffers (all reads done)
  if (khalf == 1 && hi == 0) smA[qhalf*32 + li] = tot;
  __syncthreads();
  if (khalf == 0 && hi == 0) smB[qhalf*32 + li] = tot + smA[qhalf*32 + li];
  if (khalf == 1){
    #pragma unroll
    for (int reg=0; reg<16; reg++){
      ex[qhalf*2048 + reg*64 + l]        = accO0[reg];
      ex[qhalf*2048 + (16+reg)*64 + l]   = accO1[reg];
    }
  }
  __syncthreads();
  if (khalf == 0){
    #pragma unroll
    for (int reg=0; reg<16; reg++){
      int qr = qhalf*32 + (reg&3) + 8*(reg>>2) + 4*hi;
      float inv = __builtin_amdgcn_rcpf(smB[qr]);
      float o0 = (accO0[reg] + ex[qhalf*2048 + reg*64 + l]) * inv;
      float o1 = (accO1[reg] + ex[qhalf*2048 + (16+reg)*64 + l]) * inv;
      size_t obase = ((size_t)(b*SS + qt*64 + qr))*1024 + h*64;
      ushort_t hb, lb2;
      split_bf(o0, hb, lb2); oh[obase + li] = hb;      ol[obase + li] = lb2;
      split_bf(o1, hb, lb2); oh[obase + 32 + li] = hb; ol[obase + 32 + li] = lb2;
    }
  }
}

// ---------------------------------------------------------------------------
extern "C" void kernel_launch(void* const* d_in, const int* in_sizes, int n_in,
                              void* d_out, int out_size, void* d_ws, size_t ws_size,
                              hipStream_t stream) {
  const float* x   = (const float*)d_in[0];
  const float* ln1 = (const float*)d_in[1];
  const float* wq  = (const float*)d_in[2];
  const float* sq  = (const float*)d_in[3];
  const float* bq  = (const float*)d_in[4];
  const float* wk  = (const float*)d_in[5];
  const float* sk  = (const float*)d_in[6];
  const float* bk  = (const float*)d_in[7];
  const float* wv  = (const float*)d_in[8];
  const float* sv  = (const float*)d_in[9];
  const float* bv  = (const float*)d_in[10];
  const float* qn  = (const float*)d_in[11];
  const float* kn  = (const float*)d_in[12];
  const float* wo  = (const float*)d_in[13];
  const float* so  = (const float*)d_in[14];
  const float* bo  = (const float*)d_in[15];
  const float* ln2 = (const float*)d_in[16];
  const float* wg  = (const float*)d_in[17];
  const float* sg  = (const float*)d_in[18];
  const float* bg  = (const float*)d_in[19];
  const float* wu  = (const float*)d_in[20];
  const float* su  = (const float*)d_in[21];
  const float* bu  = (const float*)d_in[22];
  const float* wd  = (const float*)d_in[23];
  const float* sd  = (const float*)d_in[24];
  const float* bd  = (const float*)d_in[25];

  float* ws  = (float*)d_ws;
  float* out = (float*)d_out;

  float* x2   = ws + OFF_X2;
  float* gate = ws + OFF_GU;
  ushort_t* vtH = (ushort_t*)(ws + OFF_VT);
  ushort_t* vtL = vtH + (size_t)1024*4096;
  ushort_t* qhH = (ushort_t*)(ws + OFF_QH);
  ushort_t* qhL = qhH + (size_t)NT*1024;
  ushort_t* khH = qhH + (size_t)2*NT*1024;
  ushort_t* khL = qhH + (size_t)3*NT*1024;
  ushort_t* oH  = (ushort_t*)(ws + OFF_O);
  ushort_t* oL  = oH + (size_t)NT*1024;
  ushort_t* bf1 = (ushort_t*)(ws + OFF_O);              // power-phase bf16 weights
  ushort_t* hH  = (ushort_t*)(ws + OFF_O);              // mlp-phase h
  ushort_t* hL  = hH + (size_t)NT*MFFP;
  ushort_t* actH = (ushort_t*)(ws + OFF_ACT);
  ushort_t* actL = actH + (size_t)NT*1024;
  ushort_t* poolH = (ushort_t*)(ws + OFF_POOL);
  float* scaleArr = ws + OFF_SCALE;

  // ---- spectral sigma (bf16 power iteration) ----
  {
    W2Args wa;
    wa.W[0]=wq; wa.W[1]=wk; wa.W[2]=wv; wa.W[3]=wo; wa.W[4]=wg; wa.W[5]=wu; wa.W[6]=wd;
    wa.dst = bf1;
    w2bf<<<6152, 256, 0, stream>>>(wa);
  }
  PowArgs pa;
  pa.Wb = bf1;
  pa.vvec = ws + OFF_VV; pa.uvec = ws + OFF_UU;
  for (int s=0; s<11; s++){
    pa.step = s;
    if ((s & 1) == 0){
      mv_notrans<<<2220, 256, 0, stream>>>(pa);
    } else {
      zero_uvec<<<7, 256, 0, stream>>>(pa.uvec);
      mv_trans<<<392, 256, 0, stream>>>(pa);
    }
  }
  SigArgs sa;
  sa.vvec = pa.vvec; sa.scale = scaleArr;
  sa.sp[0]=sq; sa.sp[1]=sk; sa.sp[2]=sv; sa.sp[3]=so; sa.sp[4]=sg; sa.sp[5]=su; sa.sp[6]=sd;
  sigma_scale_kernel<<<7, 256, 0, stream>>>(sa);

  // ---- attn_in = RMSNorm(x) ----
  rms_cvt<<<NT, 256, 0, stream>>>(x, ln1, actH, actL);

  GemmArgs ga;
  ga.resid = nullptr; ga.C = nullptr; ga.bias1 = nullptr;
  ga.nrm0 = ga.nrm1 = nullptr;
  ga.dH0 = ga.dL0 = ga.dH1 = ga.dL1 = nullptr;

  // ---- QK GEMM with fused per-head RMSNorm ----
  {
    ushort_t* bpL = poolH + (size_t)2048*1024;
    trans_cvt<<<dim3(32,32), 256, 0, stream>>>(wq, poolH,           bpL,           1024, 1024, 1024);
    trans_cvt<<<dim3(32,32), 256, 0, stream>>>(wk, poolH+1024*1024, bpL+1024*1024, 1024, 1024, 1024);
    ga.Ah = actH; ga.Al = actL; ga.Bh = poolH; ga.Bl = bpL;
    ga.bias0 = bq; ga.bias1 = bk; ga.nrm0 = qn; ga.nrm1 = kn;
    ga.dH0 = qhH; ga.dL0 = qhL; ga.dH1 = khH; ga.dL1 = khL;
    ga.scaleBase = scaleArr + 0;
    ga.Kd = 1024; ga.matN = 1024; ga.bpm = 8; ga.rowsPerMat = 1024;
    ga.Cstride = 0; ga.colOff = 0;
    gemm_bf3<4,1><<<dim3(16,32), 256, 0, stream>>>(ga);
  }

  // ---- V^T GEMM (bf16 hi/lo out [vdim][token]) ----
  {
    ushort_t* bpL = poolH + (size_t)1024*1024;
    trans_cvt<<<dim3(32,32), 256, 0, stream>>>(wv, poolH, bpL, 1024, 1024, 1024);
    ga.Ah = poolH; ga.Al = bpL; ga.Bh = actH; ga.Bl = actL;
    ga.bias0 = bv; ga.bias1 = nullptr; ga.nrm0 = ga.nrm1 = nullptr;
    ga.dH0 = vtH; ga.dL0 = vtL; ga.dH1 = ga.dL1 = nullptr;
    ga.scaleBase = scaleArr + 2;
    ga.Kd = 1024; ga.matN = 4096; ga.bpm = 64; ga.rowsPerMat = 4096;
    ga.Cstride = 0; ga.colOff = 0;
    gemm_bf3<2,2><<<dim3(64,8), 256, 0, stream>>>(ga);
  }

  // ---- attention ----
  attn_mfma<<<dim3(16,16,4), 256, 0, stream>>>(qhH, qhL, khH, khL, vtH, vtL, oH, oL);

  // ---- out projection + residual ----
  {
    ushort_t* bpL = poolH + (size_t)1024*1024;
    trans_cvt<<<dim3(32,32), 256, 0, stream>>>(wo, poolH, bpL, 1024, 1024, 1024);
    ga.Ah = oH; ga.Al = oL; ga.Bh = poolH; ga.Bl = bpL;
    ga.C = x2; ga.bias0 = bo;
    ga.dH0 = ga.dL0 = nullptr;
    ga.scaleBase = scaleArr + 3; ga.resid = x;
    ga.Kd = 1024; ga.matN = 1024; ga.bpm = 16; ga.rowsPerMat = 1024;
    ga.Cstride = 1024; ga.colOff = 0;
    gemm_bf3<2,0><<<dim3(16,32), 256, 0, stream>>>(ga);
  }

  // ---- mlp_in = RMSNorm(x2) ----
  rms_cvt<<<NT, 256, 0, stream>>>(x2, ln2, actH, actL);

  // ---- gate GEMM (fp32 out) ----
  {
    ushort_t* bpL = poolH + (size_t)2816*1024;
    trans_cvt<<<dim3(32,88), 256, 0, stream>>>(wg, poolH, bpL, 1024, MFF, 1024);
    ga.Ah = actH; ga.Al = actL; ga.Bh = poolH; ga.Bl = bpL;
    ga.C = gate; ga.bias0 = bg;
    ga.scaleBase = scaleArr + 4; ga.resid = nullptr;
    ga.Kd = 1024; ga.matN = MFF; ga.bpm = 22; ga.rowsPerMat = 2816;
    ga.Cstride = MFF; ga.colOff = 0;
    gemm_bf3<4,0><<<dim3(22,32), 256, 0, stream>>>(ga);
  }
  // ---- up GEMM with fused silu -> h hi/lo ----
  {
    ushort_t* bpL = poolH + (size_t)2816*1024;
    trans_cvt<<<dim3(32,88), 256, 0, stream>>>(wu, poolH, bpL, 1024, MFF, 1024);
    ga.Ah = actH; ga.Al = actL; ga.Bh = poolH; ga.Bl = bpL;
    ga.C = gate; ga.bias0 = bu;
    ga.dH0 = hH; ga.dL0 = hL;
    ga.scaleBase = scaleArr + 5; ga.resid = nullptr;
    ga.Kd = 1024; ga.matN = MFF; ga.bpm = 22; ga.rowsPerMat = 2816;
    ga.Cstride = MFF; ga.colOff = 0;
    gemm_bf3<4,3><<<dim3(22,32), 256, 0, stream>>>(ga);
  }

  // ---- down GEMM + residual -> out ----
  {
    ushort_t* bpL = poolH + (size_t)1024*MFFP;
    trans_cvt<<<dim3(86,32), 256, 0, stream>>>(wd, poolH, bpL, MFF, 1024, MFFP);
    ga.Ah = hH; ga.Al = hL; ga.Bh = poolH; ga.Bl = bpL;
    ga.C = out; ga.bias0 = bd;
    ga.dH0 = ga.dL0 = nullptr;
    ga.scaleBase = scaleArr + 6; ga.resid = x2;
    ga.Kd = MFFP; ga.matN = 1024; ga.bpm = 16; ga.rowsPerMat = 1024;
    ga.Cstride = 1024; ga.colOff = 0;
    gemm_bf3<2,0><<<dim3(16,32), 256, 0, stream>>>(ga);
  }
}

// Round 6
// 894.447 us; speedup vs baseline: 4.0944x; 1.1727x over previous
//
#include <hip/hip_runtime.h>
#include <math.h>
#include <stddef.h>
#include <stdint.h>

// Problem constants
#define BB   4
#define SS   1024
#define DD   1024
#define HH   16
#define HDD  64
#define NT   (BB*SS)      // 4096 tokens
#define MFF  2736
#define MFFP 2752
#define EPSF 1e-6f

typedef unsigned int   u32;
typedef unsigned short ushort_t;
typedef float  f32x4   __attribute__((ext_vector_type(4)));
typedef float  f32x16  __attribute__((ext_vector_type(16)));
typedef short  s16x8   __attribute__((ext_vector_type(8)));

typedef const __attribute__((address_space(1))) u32 glb_u32;
typedef __attribute__((address_space(3))) u32 lds_u32;

// ---------------------------------------------------------------------------
// Workspace layout (float units). Total ~146.4 MB (proven budget >= 164 MB).
// steps: 1 power, 2 rms1, 3 QK, 4 VT, 5 attn, 6 wo, 7 rms2, 8 GLU, 9 wd
// Liveness audit (float ranges):
//   x2  [0,        4194304)   steps 6-9
//   vt  [4194304,  8388608)   steps 4-5
//   qh/kh [8388608,16777216)  steps 3-5   (bf1 overlay in power phase)
//   o   [16777216, 20971520)  steps 5-6
//   h   [8388608,  19660800)  steps 8-9   (qh/kh + o regions, both dead)
//   act [26607616, 30801920)  steps 2-4, 7-8
//   pool[30801920, 36569088)  per-GEMM weights (max GLU: 5,767,168 fl)
//   vv/uu/scale [36569088+)   power phase only
// NO overlap between h and act (round-5 bug fixed).
// ---------------------------------------------------------------------------
static const size_t OFF_X2    = 0;
static const size_t OFF_VT    = 4194304;
static const size_t OFF_QH    = 8388608;
static const size_t OFF_O     = 16777216;
static const size_t OFF_H     = 8388608;    // overlays qh/kh+o, both dead at step 8
static const size_t OFF_ACT   = 26607616;
static const size_t OFF_POOL  = 30801920;
static const size_t OFF_VV    = 36569088;
static const size_t OFF_UU    = 36588240;
static const size_t OFF_SCALE = 36607392;

// ---------------------------------------------------------------------------
__device__ inline ushort_t f2bf(float x){
  u32 u = __float_as_uint(x);
  u32 r = (u + 0x7fffu + ((u >> 16) & 1u)) >> 16;
  return (ushort_t)r;
}
__device__ inline void split_bf(float x, ushort_t& hi, ushort_t& lo){
  hi = f2bf(x);
  float hf = __uint_as_float(((u32)hi) << 16);
  lo = f2bf(x - hf);
}
__device__ inline float bf2f(ushort_t u){
  return __uint_as_float(((u32)u) << 16);
}
__device__ inline s16x8 mk8(u32 a, u32 b, u32 c, u32 d){
  union { u32 w[4]; s16x8 v; } u;
  u.w[0]=a; u.w[1]=b; u.w[2]=c; u.w[3]=d;
  return u.v;
}

__device__ inline float block_sum256(float v, float* red){
  #pragma unroll
  for (int off=32; off>=1; off>>=1) v += __shfl_down(v, off);
  int lane = threadIdx.x & 63, wave = threadIdx.x >> 6;
  if (lane == 0) red[wave] = v;
  __syncthreads();
  return red[0]+red[1]+red[2]+red[3];
}

// ---------------------------------------------------------------------------
// Weight -> bf16 convert for power iteration
// ---------------------------------------------------------------------------
struct W2Args { const float* W[7]; ushort_t* dst; };
__global__ __launch_bounds__(256) void w2bf(W2Args a){
  const int BST[8] = {0,512,1024,1536,2048,3416,4784,6152};
  const size_t OFFU[7] = {0,1048576,2097152,3145728,4194304,6995968,9797632};
  int blk = blockIdx.x; int m = 0;
  #pragma unroll
  for (int i=1;i<7;i++) if (blk >= BST[i]) m = i;
  size_t e = (size_t)(blk - BST[m])*2048 + threadIdx.x*8;
  const float* src = a.W[m] + e;
  float4 v0 = *(const float4*)src;
  float4 v1 = *(const float4*)(src + 4);
  union { ushort_t o[8]; s16x8 v; } u;
  u.o[0]=f2bf(v0.x); u.o[1]=f2bf(v0.y); u.o[2]=f2bf(v0.z); u.o[3]=f2bf(v0.w);
  u.o[4]=f2bf(v1.x); u.o[5]=f2bf(v1.y); u.o[6]=f2bf(v1.z); u.o[7]=f2bf(v1.w);
  *(s16x8*)(a.dst + OFFU[m] + e) = u.v;
}

// ---------------------------------------------------------------------------
// Power iteration on bf16 weights
// ---------------------------------------------------------------------------
struct PowArgs {
  const ushort_t* Wb;
  float* vvec; float* uvec; int step;
};

__global__ __launch_bounds__(256) void zero_uvec(float* uvec){
  int m = blockIdx.x;
  for (int i=threadIdx.x; i<2736; i+=256) uvec[m*2736+i] = 0.f;
}

__global__ __launch_bounds__(256) void mv_notrans(PowArgs pa){
  const int NIN [7] = {1024,1024,1024,1024,1024,1024,2736};
  const int NOUT[7] = {1024,1024,1024,1024,2736,2736,1024};
  const int BST [8] = {0,256,512,768,1024,1280,1536,2220};
  const size_t OFFU[7] = {0,1048576,2097152,3145728,4194304,6995968,9797632};
  __shared__ float red[4];
  int blk = blockIdx.x;
  int m = 0;
  #pragma unroll
  for (int i=1;i<7;i++) if (blk >= BST[i]) m = i;
  int nin = NIN[m], nout = NOUT[m];
  int st = pa.step;
  float inv;
  const float* x = pa.uvec + m*2736;
  if (st == 0){
    inv = 1.f/(sqrtf((float)nout)+EPSF);
  } else {
    float s = 0.f;
    for (int i=threadIdx.x; i<nout; i+=256){ float u = x[i]; s += u*u; }
    float tot = block_sum256(s, red);
    inv = 1.f/(sqrtf(tot)+EPSF);
  }
  int wave = threadIdx.x >> 6, lane = threadIdx.x & 63;
  int row = (blk - BST[m])*4 + wave;
  if (row >= nin) return;
  const ushort_t* W = pa.Wb + OFFU[m];
  float sum = 0.f;
  if (st == 0){
    for (int j=lane*8; j<nout; j+=512){
      s16x8 w8 = *(const s16x8*)(W + (size_t)row*nout + j);
      #pragma unroll
      for (int e=0;e<8;e++) sum += bf2f((ushort_t)w8[e]);
    }
  } else {
    for (int j=lane*8; j<nout; j+=512){
      s16x8 w8 = *(const s16x8*)(W + (size_t)row*nout + j);
      float4 xa = *(const float4*)(x + j);
      float4 xb = *(const float4*)(x + j + 4);
      sum += bf2f((ushort_t)w8[0])*xa.x + bf2f((ushort_t)w8[1])*xa.y
           + bf2f((ushort_t)w8[2])*xa.z + bf2f((ushort_t)w8[3])*xa.w
           + bf2f((ushort_t)w8[4])*xb.x + bf2f((ushort_t)w8[5])*xb.y
           + bf2f((ushort_t)w8[6])*xb.z + bf2f((ushort_t)w8[7])*xb.w;
    }
  }
  #pragma unroll
  for (int off=32; off>=1; off>>=1) sum += __shfl_down(sum, off);
  if (lane == 0) pa.vvec[m*2736+row] = sum*inv;
}

__global__ __launch_bounds__(256) void mv_trans(PowArgs pa){
  const int NIN [7] = {1024,1024,1024,1024,1024,1024,2736};
  const int NOUT[7] = {1024,1024,1024,1024,2736,2736,1024};
  const int BST [8] = {0,32,64,96,128,216,304,392};
  const int RCH [7] = {8,8,8,8,8,8,22};
  const size_t OFFU[7] = {0,1048576,2097152,3145728,4194304,6995968,9797632};
  __shared__ float red[4];
  int blk = blockIdx.x;
  int m = 0;
  #pragma unroll
  for (int i=1;i<7;i++) if (blk >= BST[i]) m = i;
  int nin = NIN[m], nout = NOUT[m];
  const float* v = pa.vvec + m*2736;
  float s = 0.f;
  for (int i=threadIdx.x; i<nin; i+=256){ float t = v[i]; s += t*t; }
  float tot = block_sum256(s, red);
  float inv = 1.f/(sqrtf(tot)+EPSF);
  int local = blk - BST[m];
  int ct = local / RCH[m], rc = local % RCH[m];
  int col = ct*256 + threadIdx.x;
  int r0 = rc*128, r1 = min(nin, r0+128);
  if (col >= nout) return;
  const ushort_t* W = pa.Wb + OFFU[m];
  float partial = 0.f;
  for (int r=r0; r<r1; ++r)
    partial += bf2f(W[(size_t)r*nout + col])*(v[r]*inv);
  atomicAdd(&pa.uvec[m*2736+col], partial);
}

struct SigArgs {
  const float* vvec; float* scale;
  const float* sp[7];
};
__global__ __launch_bounds__(256) void sigma_scale_kernel(SigArgs sa){
  const int NIN [7] = {1024,1024,1024,1024,1024,1024,2736};
  __shared__ float red[4];
  int m = blockIdx.x;
  const float* v = sa.vvec + m*2736;
  float s = 0.f;
  for (int i=threadIdx.x; i<NIN[m]; i+=256){ float t = v[i]; s += t*t; }
  float a = block_sum256(s, red);
  if (threadIdx.x == 0){
    float S = sqrtf(a);
    float sig = a/(S+EPSF);
    sig = fmaxf(sig, EPSF);
    sa.scale[m] = sa.sp[m][0]/sig;
  }
}

// ---------------------------------------------------------------------------
// Transpose + convert: src fp32 [K][N] -> dst hi/lo bf16 [n][k], zero-padded.
// trans_cvt2: two sources via blockIdx.z (dst offset z*zoff u16 elements).
// ---------------------------------------------------------------------------
struct TCArgs {
  const float* src0; const float* src1;
  ushort_t* dh; ushort_t* dl;
  size_t zoff; int K; int N; int Kpad;
};
__global__ __launch_bounds__(256) void trans_cvt2(TCArgs a){
  __shared__ float t[32][33];
  const float* src = blockIdx.z ? a.src1 : a.src0;
  ushort_t* dh = a.dh + blockIdx.z*a.zoff;
  ushort_t* dl = a.dl + blockIdx.z*a.zoff;
  int k0 = blockIdx.x*32, n0 = blockIdx.y*32;
  int c = threadIdx.x & 31, rb = threadIdx.x >> 5;
  #pragma unroll
  for (int i=0;i<4;i++){
    int r = rb + i*8;
    int kk = k0 + r, nn = n0 + c;
    t[r][c] = (kk<a.K && nn<a.N) ? src[(size_t)kk*a.N + nn] : 0.f;
  }
  __syncthreads();
  #pragma unroll
  for (int i=0;i<4;i++){
    int r = rb + i*8;
    int nn = n0 + r, kk = k0 + c;
    float v = t[c][r];
    ushort_t hi, lo; split_bf(v, hi, lo);
    size_t o = (size_t)nn*a.Kpad + kk;
    dh[o] = hi; dl[o] = lo;
  }
}

// ---------------------------------------------------------------------------
// RMSNorm over D=1024 -> bf16 hi/lo
// ---------------------------------------------------------------------------
__global__ __launch_bounds__(256) void rms_cvt(const float* __restrict__ in,
                                               const float* __restrict__ scale,
                                               ushort_t* __restrict__ oh,
                                               ushort_t* __restrict__ ol){
  int row = blockIdx.x;
  int tid = threadIdx.x;
  const float* p = in + (size_t)row*DD;
  float4 vx = *(const float4*)(p + tid*4);
  float ss = vx.x*vx.x + vx.y*vx.y + vx.z*vx.z + vx.w*vx.w;
  int lane = tid & 63, wave = tid >> 6;
  #pragma unroll
  for (int off=32; off>=1; off>>=1) ss += __shfl_down(ss, off);
  __shared__ float red[4];
  if (lane == 0) red[wave] = ss;
  __syncthreads();
  float tot = red[0]+red[1]+red[2]+red[3];
  float r = rsqrtf(tot*(1.f/DD)+EPSF);
  float4 sc = *(const float4*)(scale + tid*4);
  float o0 = vx.x*r*sc.x, o1 = vx.y*r*sc.y, o2 = vx.z*r*sc.z, o3 = vx.w*r*sc.w;
  ushort_t h[4], l[4];
  split_bf(o0,h[0],l[0]); split_bf(o1,h[1],l[1]);
  split_bf(o2,h[2],l[2]); split_bf(o3,h[3],l[3]);
  size_t o = (size_t)row*DD + tid*4;
  oh[o+0]=h[0]; oh[o+1]=h[1]; oh[o+2]=h[2]; oh[o+3]=h[3];
  ol[o+0]=l[0]; ol[o+1]=l[1]; ol[o+2]=l[2]; ol[o+3]=l[3];
}

// ---------------------------------------------------------------------------
// bf16x3 split MFMA GEMM, double-buffered LDS prefetch.
//  EPI 0: C fp32 = s*(A@B^T) + bias0[col] (+resid)
//  EPI 1: QK fused per-head RMSNorm -> bf16 hi/lo head-major (2 mats)
//  EPI 2: VT: bf16 hi/lo out at [row][col], bias0 per ROW
// ---------------------------------------------------------------------------
struct GemmArgs {
  const ushort_t *Ah, *Al, *Bh, *Bl;
  float* C;
  const float *bias0, *bias1;
  const float *nrm0, *nrm1;
  ushort_t *dH0, *dL0, *dH1, *dL1;
  const float* scaleBase;
  const float* resid;
  int Kd, matN, bpm, rowsPerMat, Cstride, colOff;
};

template<int FN, int EPI>
__global__ __launch_bounds__(256) void gemm_bf3(GemmArgs g){
  constexpr int BN   = FN*32;
  constexpr int SEGB = BN/16;
  constexpr int NSEG = 16 + 2*SEGB;
  constexpr int NSEGT = NSEG/4;
  constexpr int HALF = 16384 + 2*BN*64;
  __shared__ __align__(16) char lds[2*HALF];

  const int tid = threadIdx.x;
  const int w = tid >> 6, l = tid & 63;
  const int bm = blockIdx.y*128;
  const int mat = blockIdx.x / g.bpm;
  const int n0m = (blockIdx.x % g.bpm) * BN;
  const int nrow0 = mat*g.rowsPerMat + n0m;

  const ushort_t* sp[NSEGT];
  u32 loff[NSEGT];
  #pragma unroll
  for (int i=0;i<NSEGT;i++){
    int s = w + i*4;
    int ci, r, c, csrc;
    if (s < 16){
      int abuf = s >> 3, segi = s & 7;
      ci = segi*64 + l; r = ci >> 2; c = ci & 3;
      csrc = c ^ ((r >> 1) & 3);
      sp[i] = (abuf ? g.Al : g.Ah) + (size_t)(bm + r)*g.Kd + csrc*8;
      loff[i] = (u32)(abuf*8192 + ci*16);
    } else {
      int tt = s - 16;
      int bbuf = tt / SEGB, segi = tt % SEGB;
      ci = segi*64 + l; r = ci >> 2; c = ci & 3;
      csrc = c ^ ((r >> 1) & 3);
      sp[i] = (bbuf ? g.Bl : g.Bh) + (size_t)(nrow0 + r)*g.Kd + csrc*8;
      loff[i] = (u32)(16384 + bbuf*(BN*64) + ci*16);
    }
  }

  const int wm = w >> 1, wn = w & 1;
  const int li = l & 15, kq = l >> 4;
  const int sx = kq ^ ((li >> 1) & 3);
  const u32 aOff = (u32)((wm*64 + li)*64 + sx*16);
  const u32 bOff = (u32)(16384 + (wn*(FN*16) + li)*64 + sx*16);

  f32x4 acc[4][FN];
  #pragma unroll
  for (int mi=0;mi<4;mi++)
    #pragma unroll
    for (int ni=0;ni<FN;ni++)
      acc[mi][ni] = (f32x4){0.f,0.f,0.f,0.f};

  const int nt = g.Kd >> 5;
  // prologue: stage tile 0 into buffer 0
  #pragma unroll
  for (int i=0;i<NSEGT;i++){
    __builtin_amdgcn_global_load_lds((glb_u32*)sp[i], (lds_u32*)(lds + loff[i]), 16, 0, 0);
    sp[i] += 32;
  }
  __syncthreads();

  for (int t=0; t<nt; t++){
    if (t+1 < nt){
      char* sb = lds + ((t+1)&1)*HALF;
      #pragma unroll
      for (int i=0;i<NSEGT;i++){
        __builtin_amdgcn_global_load_lds((glb_u32*)sp[i], (lds_u32*)(sb + loff[i]), 16, 0, 0);
        sp[i] += 32;
      }
    }
    const char* lb = lds + (t&1)*HALF;
    s16x8 ah[4], al[4];
    #pragma unroll
    for (int mi=0;mi<4;mi++){
      ah[mi] = *(const s16x8*)(lb + aOff + mi*1024);
      al[mi] = *(const s16x8*)(lb + 8192 + aOff + mi*1024);
    }
    #pragma unroll
    for (int ni=0;ni<FN;ni++){
      s16x8 bh = *(const s16x8*)(lb + bOff + ni*1024);
      s16x8 bl = *(const s16x8*)(lb + BN*64 + bOff + ni*1024);
      #pragma unroll
      for (int mi=0;mi<4;mi++){
        f32x4 tacc = acc[mi][ni];
        tacc = __builtin_amdgcn_mfma_f32_16x16x32_bf16(ah[mi], bh, tacc, 0, 0, 0);
        tacc = __builtin_amdgcn_mfma_f32_16x16x32_bf16(ah[mi], bl, tacc, 0, 0, 0);
        tacc = __builtin_amdgcn_mfma_f32_16x16x32_bf16(al[mi], bh, tacc, 0, 0, 0);
        acc[mi][ni] = tacc;
      }
    }
    __syncthreads();
  }

  if constexpr (EPI == 0){
    const float s = g.scaleBase[mat];
    const float* bias = g.bias0;
    const int colBase = n0m + wn*(FN*16);
    #pragma unroll
    for (int ni=0;ni<FN;ni++){
      int cm = colBase + ni*16 + li;
      if (cm < g.matN){
        int cg = cm + g.colOff;
        float bv = bias[cm];
        #pragma unroll
        for (int mi=0;mi<4;mi++){
          f32x4 a = acc[mi][ni];
          int r0 = bm + wm*64 + mi*16 + kq*4;
          #pragma unroll
          for (int j=0;j<4;j++){
            float v = s*a[j] + bv;
            size_t off = (size_t)(r0+j)*g.Cstride + cg;
            if (g.resid) v += g.resid[off];
            g.C[off] = v;
          }
        }
      }
    }
  } else if constexpr (EPI == 1){
    const float s = g.scaleBase[mat];
    const float* bias = mat ? g.bias1 : g.bias0;
    const float* nsc  = mat ? g.nrm1  : g.nrm0;
    ushort_t* dH = mat ? g.dH1 : g.dH0;
    ushort_t* dL = mat ? g.dL1 : g.dL0;
    const int hidx = (n0m >> 6) + wn;
    float bv[FN], nv[FN];
    #pragma unroll
    for (int ni=0;ni<FN;ni++){
      int cm = n0m + wn*64 + ni*16 + li;
      bv[ni] = bias[cm];
      nv[ni] = nsc[ni*16 + li];
    }
    #pragma unroll
    for (int mi=0;mi<4;mi++){
      #pragma unroll
      for (int j=0;j<4;j++){
        float vv[FN]; float ssq = 0.f;
        #pragma unroll
        for (int ni=0;ni<FN;ni++){
          vv[ni] = s*acc[mi][ni][j] + bv[ni];
          ssq += vv[ni]*vv[ni];
        }
        ssq += __shfl_xor(ssq, 1);
        ssq += __shfl_xor(ssq, 2);
        ssq += __shfl_xor(ssq, 4);
        ssq += __shfl_xor(ssq, 8);
        float rr = rsqrtf(ssq*(1.f/64.f)+EPSF);
        int row = bm + wm*64 + mi*16 + kq*4 + j;
        size_t base = (((size_t)(row>>10)*16 + hidx)*1024 + (row & 1023))*64;
        #pragma unroll
        for (int ni=0;ni<FN;ni++){
          ushort_t hi, lo; split_bf(vv[ni]*rr*nv[ni], hi, lo);
          dH[base + ni*16 + li] = hi;
          dL[base + ni*16 + li] = lo;
        }
      }
    }
  } else {
    const float s = g.scaleBase[0];
    #pragma unroll
    for (int mi=0;mi<4;mi++){
      #pragma unroll
      for (int j=0;j<4;j++){
        int row = bm + wm*64 + mi*16 + kq*4 + j;
        float bvr = g.bias0[row];
        #pragma unroll
        for (int ni=0;ni<FN;ni++){
          int cm = n0m + wn*(FN*16) + ni*16 + li;
          float v = s*acc[mi][ni][j] + bvr;
          ushort_t hi, lo; split_bf(v, hi, lo);
          g.dH0[(size_t)row*4096 + cm] = hi;
          g.dL0[(size_t)row*4096 + cm] = lo;
        }
      }
    }
  }
}

// ---------------------------------------------------------------------------
// Fused gate+up GEMM with in-register SiLU: h = silu(gate)*up -> bf16 hi/lo.
// Per block: BM=128 rows x BN=64 cols of BOTH wg and wu. Double-buffered.
// ---------------------------------------------------------------------------
struct GluArgs {
  const ushort_t *Ah, *Al;
  const ushort_t *GH, *GL, *UH, *UL;   // transposed [2816][1024] each
  const float *bg, *bu;
  const float* scaleBase;              // [0]=sg, [1]=su
  ushort_t *hH, *hL;
};

__global__ __launch_bounds__(256) void gemm_glu(GluArgs g){
  constexpr int HALF = 32768;
  __shared__ __align__(16) char lds[2*HALF];
  const int tid = threadIdx.x;
  const int w = tid >> 6, l = tid & 63;
  const int bm = blockIdx.y*128;
  const int n0 = blockIdx.x*64;

  const ushort_t* sp[8];
  u32 loff[8];
  #pragma unroll
  for (int i=0;i<8;i++){
    int s = w + i*4;
    if (s < 16){
      int abuf = s >> 3, segi = s & 7;
      int ci = segi*64 + l, r = ci >> 2, c = ci & 3;
      int csrc = c ^ ((r >> 1) & 3);
      sp[i] = (abuf ? g.Al : g.Ah) + (size_t)(bm + r)*1024 + csrc*8;
      loff[i] = (u32)(abuf*8192 + ci*16);
    } else {
      int tt = s - 16;                 // 0..15
      int msel = tt >> 3;              // 0:wg 1:wu
      int half = (tt >> 2) & 1;        // 0:hi 1:lo
      int segi = tt & 3;
      int ci = segi*64 + l, r = ci >> 2, c = ci & 3;
      int csrc = c ^ ((r >> 1) & 3);
      const ushort_t* base = msel ? (half ? g.UL : g.UH) : (half ? g.GL : g.GH);
      sp[i] = base + (size_t)(n0 + r)*1024 + csrc*8;
      loff[i] = (u32)(16384 + msel*8192 + half*4096 + ci*16);
    }
  }

  const int wm = w >> 1, wn = w & 1;
  const int li = l & 15, kq = l >> 4;
  const int sx = kq ^ ((li >> 1) & 3);
  const u32 aOff = (u32)((wm*64 + li)*64 + sx*16);
  const u32 bOff = (u32)(16384 + (wn*32 + li)*64 + sx*16);

  f32x4 accG[4][2], accU[4][2];
  #pragma unroll
  for (int mi=0;mi<4;mi++)
    #pragma unroll
    for (int ni=0;ni<2;ni++){
      accG[mi][ni] = (f32x4){0.f,0.f,0.f,0.f};
      accU[mi][ni] = (f32x4){0.f,0.f,0.f,0.f};
    }

  #pragma unroll
  for (int i=0;i<8;i++){
    __builtin_amdgcn_global_load_lds((glb_u32*)sp[i], (lds_u32*)(lds + loff[i]), 16, 0, 0);
    sp[i] += 32;
  }
  __syncthreads();

  for (int t=0; t<32; t++){
    if (t+1 < 32){
      char* sb = lds + ((t+1)&1)*HALF;
      #pragma unroll
      for (int i=0;i<8;i++){
        __builtin_amdgcn_global_load_lds((glb_u32*)sp[i], (lds_u32*)(sb + loff[i]), 16, 0, 0);
        sp[i] += 32;
      }
    }
    const char* lb = lds + (t&1)*HALF;
    s16x8 ah[4], al[4];
    #pragma unroll
    for (int mi=0;mi<4;mi++){
      ah[mi] = *(const s16x8*)(lb + aOff + mi*1024);
      al[mi] = *(const s16x8*)(lb + 8192 + aOff + mi*1024);
    }
    #pragma unroll
    for (int ni=0;ni<2;ni++){
      s16x8 gh = *(const s16x8*)(lb + bOff + ni*1024);
      s16x8 gl = *(const s16x8*)(lb + 4096 + bOff + ni*1024);
      s16x8 uh = *(const s16x8*)(lb + 8192 + bOff + ni*1024);
      s16x8 ul = *(const s16x8*)(lb + 12288 + bOff + ni*1024);
      #pragma unroll
      for (int mi=0;mi<4;mi++){
        f32x4 tg = accG[mi][ni];
        tg = __builtin_amdgcn_mfma_f32_16x16x32_bf16(ah[mi], gh, tg, 0, 0, 0);
        tg = __builtin_amdgcn_mfma_f32_16x16x32_bf16(ah[mi], gl, tg, 0, 0, 0);
        tg = __builtin_amdgcn_mfma_f32_16x16x32_bf16(al[mi], gh, tg, 0, 0, 0);
        accG[mi][ni] = tg;
        f32x4 tu = accU[mi][ni];
        tu = __builtin_amdgcn_mfma_f32_16x16x32_bf16(ah[mi], uh, tu, 0, 0, 0);
        tu = __builtin_amdgcn_mfma_f32_16x16x32_bf16(ah[mi], ul, tu, 0, 0, 0);
        tu = __builtin_amdgcn_mfma_f32_16x16x32_bf16(al[mi], uh, tu, 0, 0, 0);
        accU[mi][ni] = tu;
      }
    }
    __syncthreads();
  }

  const float sG = g.scaleBase[0], sU = g.scaleBase[1];
  #pragma unroll
  for (int ni=0;ni<2;ni++){
    int cm = n0 + wn*32 + ni*16 + li;
    bool ok = cm < MFF;
    float bgv = ok ? g.bg[cm] : 0.f;
    float buv = ok ? g.bu[cm] : 0.f;
    #pragma unroll
    for (int mi=0;mi<4;mi++){
      #pragma unroll
      for (int j=0;j<4;j++){
        int row = bm + wm*64 + mi*16 + kq*4 + j;
        ushort_t hb = 0, lb2 = 0;
        if (ok){
          float gv = sG*accG[mi][ni][j] + bgv;
          float uv = sU*accU[mi][ni][j] + buv;
          float hv = gv * __builtin_amdgcn_rcpf(1.f + __expf(-gv)) * uv;
          split_bf(hv, hb, lb2);
        }
        size_t ho = (size_t)row*MFFP + cm;
        g.hH[ho] = hb; g.hL[ho] = lb2;
      }
    }
  }
}

// ---------------------------------------------------------------------------
// MFMA flash attention, in-register P (swapped-operand QK^T).
// ---------------------------------------------------------------------------
__global__ __launch_bounds__(256) void attn_mfma(const ushort_t* __restrict__ qh, const ushort_t* __restrict__ ql,
                                                 const ushort_t* __restrict__ kh, const ushort_t* __restrict__ kl,
                                                 const ushort_t* __restrict__ vh, const ushort_t* __restrict__ vl,
                                                 ushort_t* __restrict__ oh, ushort_t* __restrict__ ol){
  __shared__ __align__(16) char lds[74240];
  const int qt = blockIdx.x, h = blockIdx.y, b = blockIdx.z;
  const int tid = threadIdx.x;
  const int l = tid & 63, li = tid & 31, hi = (tid >> 5) & 1;
  const int w = tid >> 6, qhalf = w >> 1, khalf = w & 1;
  const int r0 = tid >> 3, ch = tid & 7;

  const size_t qrow = ((size_t)(b*HH + h)*SS + qt*64 + qhalf*32 + li)*64;
  s16x8 aQh[4], aQl[4];
  #pragma unroll
  for (int ks=0; ks<4; ks++){
    aQh[ks] = *(const s16x8*)(qh + qrow + ks*16 + hi*8);
    aQl[ks] = *(const s16x8*)(ql + qrow + ks*16 + hi*8);
  }

  const size_t kbase = (size_t)(b*HH + h)*SS*64;
  const size_t vbase = (size_t)h*64*4096 + (size_t)b*SS;

  f32x16 accO0 = (f32x16){0,0,0,0,0,0,0,0,0,0,0,0,0,0,0,0};
  f32x16 accO1 = (f32x16){0,0,0,0,0,0,0,0,0,0,0,0,0,0,0,0};
  float psum = 0.f;

  s16x8 rKh0,rKh1,rKl0,rKl1,rVh0,rVh1,rVl0,rVl1;
  rKh0 = *(const s16x8*)(kh + kbase + (size_t)r0*64 + ch*8);
  rKh1 = *(const s16x8*)(kh + kbase + (size_t)(r0+32)*64 + ch*8);
  rKl0 = *(const s16x8*)(kl + kbase + (size_t)r0*64 + ch*8);
  rKl1 = *(const s16x8*)(kl + kbase + (size_t)(r0+32)*64 + ch*8);
  rVh0 = *(const s16x8*)(vh + vbase + (size_t)r0*4096 + ch*8);
  rVh1 = *(const s16x8*)(vh + vbase + (size_t)(r0+32)*4096 + ch*8);
  rVl0 = *(const s16x8*)(vl + vbase + (size_t)r0*4096 + ch*8);
  rVl1 = *(const s16x8*)(vl + vbase + (size_t)(r0+32)*4096 + ch*8);
  {
    char* Kb = lds;  char* Vb = lds + 36864;
    *(s16x8*)(Kb + r0*144 + ch*16) = rKh0;
    *(s16x8*)(Kb + (r0+32)*144 + ch*16) = rKh1;
    *(s16x8*)(Kb + 9216 + r0*144 + ch*16) = rKl0;
    *(s16x8*)(Kb + 9216 + (r0+32)*144 + ch*16) = rKl1;
    *(s16x8*)(Vb + r0*144 + ch*16) = rVh0;
    *(s16x8*)(Vb + (r0+32)*144 + ch*16) = rVh1;
    *(s16x8*)(Vb + 9216 + r0*144 + ch*16) = rVl0;
    *(s16x8*)(Vb + 9216 + (r0+32)*144 + ch*16) = rVl1;
  }
  __syncthreads();

  int cur = 0;
  for (int kt=0; kt<16; kt++){
    if (kt < 15){
      const size_t kb = kbase + (size_t)(kt+1)*64*64;
      const size_t vb = vbase + (size_t)(kt+1)*64;
      rKh0 = *(const s16x8*)(kh + kb + (size_t)r0*64 + ch*8);
      rKh1 = *(const s16x8*)(kh + kb + (size_t)(r0+32)*64 + ch*8);
      rKl0 = *(const s16x8*)(kl + kb + (size_t)r0*64 + ch*8);
      rKl1 = *(const s16x8*)(kl + kb + (size_t)(r0+32)*64 + ch*8);
      rVh0 = *(const s16x8*)(vh + vb + (size_t)r0*4096 + ch*8);
      rVh1 = *(const s16x8*)(vh + vb + (size_t)(r0+32)*4096 + ch*8);
      rVl0 = *(const s16x8*)(vl + vb + (size_t)r0*4096 + ch*8);
      rVl1 = *(const s16x8*)(vl + vb + (size_t)(r0+32)*4096 + ch*8);
    }
    const char* Kc = lds + cur*18432;
    const char* Vc = lds + 36864 + cur*18432;

    f32x16 sF = (f32x16){0,0,0,0,0,0,0,0,0,0,0,0,0,0,0,0};
    #pragma unroll
    for (int ks=0; ks<4; ks++){
      s16x8 kfh = *(const s16x8*)(Kc + (khalf*32+li)*144 + ks*32 + hi*16);
      s16x8 kfl = *(const s16x8*)(Kc + 9216 + (khalf*32+li)*144 + ks*32 + hi*16);
      sF = __builtin_amdgcn_mfma_f32_32x32x16_bf16(kfh, aQh[ks], sF, 0, 0, 0);
      sF = __builtin_amdgcn_mfma_f32_32x32x16_bf16(kfl, aQh[ks], sF, 0, 0, 0);
      sF = __builtin_amdgcn_mfma_f32_32x32x16_bf16(kfh, aQl[ks], sF, 0, 0, 0);
    }

    float p[16];
    #pragma unroll
    for (int r=0; r<16; r++){
      float wv = __expf(sF[r]*0.005f);
      float rc = __builtin_amdgcn_rcpf(wv + 1.f);
      float pv = __expf(-100.f*rc);
      p[r] = pv;
      psum += pv;
    }

    u32 cH[8], cL[8];
    #pragma unroll
    for (int m=0; m<4; m++){
      u32 u0 = __float_as_uint(p[4*m+0]), u1 = __float_as_uint(p[4*m+1]);
      u32 u2 = __float_as_uint(p[4*m+2]), u3 = __float_as_uint(p[4*m+3]);
      u32 m0 = u0 & 0xffff0000u, m1 = u1 & 0xffff0000u;
      u32 m2 = u2 & 0xffff0000u, m3 = u3 & 0xffff0000u;
      cH[2*m+0] = m1 | (m0 >> 16);
      cH[2*m+1] = m3 | (m2 >> 16);
      u32 k0 = __float_as_uint(p[4*m+0] - __uint_as_float(m0));
      u32 k1 = __float_as_uint(p[4*m+1] - __uint_as_float(m1));
      u32 k2 = __float_as_uint(p[4*m+2] - __uint_as_float(m2));
      u32 k3 = __float_as_uint(p[4*m+3] - __uint_as_float(m3));
      cL[2*m+0] = (k1 & 0xffff0000u) | (k0 >> 16);
      cL[2*m+1] = (k3 & 0xffff0000u) | (k2 >> 16);
    }

    #pragma unroll
    for (int ks2=0; ks2<2; ks2++){
      u32 A0 = cH[4*ks2+0], A1 = cH[4*ks2+1], B0 = cH[4*ks2+2], B1 = cH[4*ks2+3];
      u32 As0 = (u32)__shfl_xor((int)A0, 32), As1 = (u32)__shfl_xor((int)A1, 32);
      u32 Bs0 = (u32)__shfl_xor((int)B0, 32), Bs1 = (u32)__shfl_xor((int)B1, 32);
      s16x8 paH = mk8(hi ? Bs0 : A0, hi ? Bs1 : A1, hi ? B0 : As0, hi ? B1 : As1);
      u32 C0 = cL[4*ks2+0], C1 = cL[4*ks2+1], D0 = cL[4*ks2+2], D1 = cL[4*ks2+3];
      u32 Cs0 = (u32)__shfl_xor((int)C0, 32), Cs1 = (u32)__shfl_xor((int)C1, 32);
      u32 Ds0 = (u32)__shfl_xor((int)D0, 32), Ds1 = (u32)__shfl_xor((int)D1, 32);
      s16x8 paL = mk8(hi ? Ds0 : C0, hi ? Ds1 : C1, hi ? D0 : Cs0, hi ? D1 : Cs1);

      {
        const char* vp = Vc + (0*32+li)*144 + khalf*64 + ks2*32 + hi*16;
        s16x8 vfh = *(const s16x8*)vp;
        s16x8 vfl = *(const s16x8*)(vp + 9216);
        accO0 = __builtin_amdgcn_mfma_f32_32x32x16_bf16(paH, vfh, accO0, 0, 0, 0);
        accO0 = __builtin_amdgcn_mfma_f32_32x32x16_bf16(paH, vfl, accO0, 0, 0, 0);
        accO0 = __builtin_amdgcn_mfma_f32_32x32x16_bf16(paL, vfh, accO0, 0, 0, 0);
      }
      {
        const char* vp = Vc + (32+li)*144 + khalf*64 + ks2*32 + hi*16;
        s16x8 vfh = *(const s16x8*)vp;
        s16x8 vfl = *(const s16x8*)(vp + 9216);
        accO1 = __builtin_amdgcn_mfma_f32_32x32x16_bf16(paH, vfh, accO1, 0, 0, 0);
        accO1 = __builtin_amdgcn_mfma_f32_32x32x16_bf16(paH, vfl, accO1, 0, 0, 0);
        accO1 = __builtin_amdgcn_mfma_f32_32x32x16_bf16(paL, vfh, accO1, 0, 0, 0);
      }
    }

    __syncthreads();
    if (kt < 15){
      char* Kb = lds + (cur^1)*18432;
      char* Vb = lds + 36864 + (cur^1)*18432;
      *(s16x8*)(Kb + r0*144 + ch*16) = rKh0;
      *(s16x8*)(Kb + (r0+32)*144 + ch*16) = rKh1;
      *(s16x8*)(Kb + 9216 + r0*144 + ch*16) = rKl0;
      *(s16x8*)(Kb + 9216 + (r0+32)*144 + ch*16) = rKl1;
      *(s16x8*)(Vb + r0*144 + ch*16) = rVh0;
      *(s16x8*)(Vb + (r0+32)*144 + ch*16) = rVh1;
      *(s16x8*)(Vb + 9216 + r0*144 + ch*16) = rVl0;
      *(s16x8*)(Vb + 9216 + (r0+32)*144 + ch*16) = rVl1;
      __syncthreads();
      cur ^= 1;
    }
  }

  float tot = psum + __shfl_xor(psum, 32);
  float* smA = (float*)(lds + 73728);
  float* smB = smA + 64;
  float* ex  = (float*)lds;
  if (khalf == 1 && hi == 0) smA[qhalf*32 + li] = tot;
  __syncthreads();
  if (khalf == 0 && hi == 0) smB[qhalf*32 + li] = tot + smA[qhalf*32 + li];
  if (khalf == 1){
    #pragma unroll
    for (int reg=0; reg<16; reg++){
      ex[qhalf*2048 + reg*64 + l]        = accO0[reg];
      ex[qhalf*2048 + (16+reg)*64 + l]   = accO1[reg];
    }
  }
  __syncthreads();
  if (khalf == 0){
    #pragma unroll
    for (int reg=0; reg<16; reg++){
      int qr = qhalf*32 + (reg&3) + 8*(reg>>2) + 4*hi;
      float inv = __builtin_amdgcn_rcpf(smB[qr]);
      float o0 = (accO0[reg] + ex[qhalf*2048 + reg*64 + l]) * inv;
      float o1 = (accO1[reg] + ex[qhalf*2048 + (16+reg)*64 + l]) * inv;
      size_t obase = ((size_t)(b*SS + qt*64 + qr))*1024 + h*64;
      ushort_t hb, lb2;
      split_bf(o0, hb, lb2); oh[obase + li] = hb;      ol[obase + li] = lb2;
      split_bf(o1, hb, lb2); oh[obase + 32 + li] = hb; ol[obase + 32 + li] = lb2;
    }
  }
}

// ---------------------------------------------------------------------------
extern "C" void kernel_launch(void* const* d_in, const int* in_sizes, int n_in,
                              void* d_out, int out_size, void* d_ws, size_t ws_size,
                              hipStream_t stream) {
  const float* x   = (const float*)d_in[0];
  const float* ln1 = (const float*)d_in[1];
  const float* wq  = (const float*)d_in[2];
  const float* sq  = (const float*)d_in[3];
  const float* bq  = (const float*)d_in[4];
  const float* wk  = (const float*)d_in[5];
  const float* sk  = (const float*)d_in[6];
  const float* bk  = (const float*)d_in[7];
  const float* wv  = (const float*)d_in[8];
  const float* sv  = (const float*)d_in[9];
  const float* bv  = (const float*)d_in[10];
  const float* qn  = (const float*)d_in[11];
  const float* kn  = (const float*)d_in[12];
  const float* wo  = (const float*)d_in[13];
  const float* so  = (const float*)d_in[14];
  const float* bo  = (const float*)d_in[15];
  const float* ln2 = (const float*)d_in[16];
  const float* wg  = (const float*)d_in[17];
  const float* sg  = (const float*)d_in[18];
  const float* bg  = (const float*)d_in[19];
  const float* wu  = (const float*)d_in[20];
  const float* su  = (const float*)d_in[21];
  const float* bu  = (const float*)d_in[22];
  const float* wd  = (const float*)d_in[23];
  const float* sd  = (const float*)d_in[24];
  const float* bd  = (const float*)d_in[25];

  float* ws  = (float*)d_ws;
  float* out = (float*)d_out;

  float* x2   = ws + OFF_X2;
  ushort_t* vtH = (ushort_t*)(ws + OFF_VT);
  ushort_t* vtL = vtH + (size_t)1024*4096;
  ushort_t* qhH = (ushort_t*)(ws + OFF_QH);
  ushort_t* qhL = qhH + (size_t)NT*1024;
  ushort_t* khH = qhH + (size_t)2*NT*1024;
  ushort_t* khL = qhH + (size_t)3*NT*1024;
  ushort_t* bf1 = (ushort_t*)(ws + OFF_QH);   // power phase only
  ushort_t* oH  = (ushort_t*)(ws + OFF_O);
  ushort_t* oL  = oH + (size_t)NT*1024;
  ushort_t* hH  = (ushort_t*)(ws + OFF_H);    // overlays qh/kh+o (dead at step 8)
  ushort_t* hL  = hH + (size_t)NT*MFFP;
  ushort_t* actH = (ushort_t*)(ws + OFF_ACT);
  ushort_t* actL = actH + (size_t)NT*1024;
  ushort_t* poolH = (ushort_t*)(ws + OFF_POOL);
  float* scaleArr = ws + OFF_SCALE;

  // ---- spectral sigma (bf16 power iteration) ----
  {
    W2Args wa;
    wa.W[0]=wq; wa.W[1]=wk; wa.W[2]=wv; wa.W[3]=wo; wa.W[4]=wg; wa.W[5]=wu; wa.W[6]=wd;
    wa.dst = bf1;
    w2bf<<<6152, 256, 0, stream>>>(wa);
  }
  PowArgs pa;
  pa.Wb = bf1;
  pa.vvec = ws + OFF_VV; pa.uvec = ws + OFF_UU;
  for (int s=0; s<11; s++){
    pa.step = s;
    if ((s & 1) == 0){
      mv_notrans<<<2220, 256, 0, stream>>>(pa);
    } else {
      zero_uvec<<<7, 256, 0, stream>>>(pa.uvec);
      mv_trans<<<392, 256, 0, stream>>>(pa);
    }
  }
  SigArgs sa;
  sa.vvec = pa.vvec; sa.scale = scaleArr;
  sa.sp[0]=sq; sa.sp[1]=sk; sa.sp[2]=sv; sa.sp[3]=so; sa.sp[4]=sg; sa.sp[5]=su; sa.sp[6]=sd;
  sigma_scale_kernel<<<7, 256, 0, stream>>>(sa);

  // ---- attn_in = RMSNorm(x) ----
  rms_cvt<<<NT, 256, 0, stream>>>(x, ln1, actH, actL);

  GemmArgs ga;
  ga.resid = nullptr; ga.C = nullptr; ga.bias1 = nullptr;
  ga.nrm0 = ga.nrm1 = nullptr;
  ga.dH0 = ga.dL0 = ga.dH1 = ga.dL1 = nullptr;

  // ---- QK GEMM with fused per-head RMSNorm ----
  {
    ushort_t* bpL = poolH + (size_t)2048*1024;
    TCArgs tc; tc.src0 = wq; tc.src1 = wk;
    tc.dh = poolH; tc.dl = bpL; tc.zoff = (size_t)1024*1024;
    tc.K = 1024; tc.N = 1024; tc.Kpad = 1024;
    trans_cvt2<<<dim3(32,32,2), 256, 0, stream>>>(tc);
    ga.Ah = actH; ga.Al = actL; ga.Bh = poolH; ga.Bl = bpL;
    ga.bias0 = bq; ga.bias1 = bk; ga.nrm0 = qn; ga.nrm1 = kn;
    ga.dH0 = qhH; ga.dL0 = qhL; ga.dH1 = khH; ga.dL1 = khL;
    ga.scaleBase = scaleArr + 0;
    ga.Kd = 1024; ga.matN = 1024; ga.bpm = 8; ga.rowsPerMat = 1024;
    ga.Cstride = 0; ga.colOff = 0;
    gemm_bf3<4,1><<<dim3(16,32), 256, 0, stream>>>(ga);
  }

  // ---- V^T GEMM (bf16 hi/lo out [vdim][token]) ----
  {
    ushort_t* bpL = poolH + (size_t)1024*1024;
    TCArgs tc; tc.src0 = wv; tc.src1 = wv;
    tc.dh = poolH; tc.dl = bpL; tc.zoff = 0;
    tc.K = 1024; tc.N = 1024; tc.Kpad = 1024;
    trans_cvt2<<<dim3(32,32,1), 256, 0, stream>>>(tc);
    ga.Ah = poolH; ga.Al = bpL; ga.Bh = actH; ga.Bl = actL;
    ga.bias0 = bv; ga.bias1 = nullptr; ga.nrm0 = ga.nrm1 = nullptr;
    ga.dH0 = vtH; ga.dL0 = vtL; ga.dH1 = ga.dL1 = nullptr;
    ga.scaleBase = scaleArr + 2;
    ga.Kd = 1024; ga.matN = 4096; ga.bpm = 64; ga.rowsPerMat = 4096;
    ga.Cstride = 0; ga.colOff = 0;
    gemm_bf3<2,2><<<dim3(64,8), 256, 0, stream>>>(ga);
  }

  // ---- attention ----
  attn_mfma<<<dim3(16,16,4), 256, 0, stream>>>(qhH, qhL, khH, khL, vtH, vtL, oH, oL);

  // ---- out projection + residual ----
  {
    ushort_t* bpL = poolH + (size_t)1024*1024;
    TCArgs tc; tc.src0 = wo; tc.src1 = wo;
    tc.dh = poolH; tc.dl = bpL; tc.zoff = 0;
    tc.K = 1024; tc.N = 1024; tc.Kpad = 1024;
    trans_cvt2<<<dim3(32,32,1), 256, 0, stream>>>(tc);
    ga.Ah = oH; ga.Al = oL; ga.Bh = poolH; ga.Bl = bpL;
    ga.C = x2; ga.bias0 = bo;
    ga.dH0 = ga.dL0 = nullptr;
    ga.scaleBase = scaleArr + 3; ga.resid = x;
    ga.Kd = 1024; ga.matN = 1024; ga.bpm = 16; ga.rowsPerMat = 1024;
    ga.Cstride = 1024; ga.colOff = 0;
    gemm_bf3<2,0><<<dim3(16,32), 256, 0, stream>>>(ga);
  }

  // ---- mlp_in = RMSNorm(x2) ----
  rms_cvt<<<NT, 256, 0, stream>>>(x2, ln2, actH, actL);

  // ---- fused gate+up+SiLU GEMM -> h hi/lo ----
  {
    ushort_t* gH = poolH;
    ushort_t* gL = poolH + (size_t)2816*1024;
    ushort_t* uH = poolH + (size_t)2*2816*1024;
    ushort_t* uL = poolH + (size_t)3*2816*1024;
    TCArgs tc; tc.src0 = wg; tc.src1 = wu;
    tc.dh = gH; tc.dl = gL; tc.zoff = (size_t)2*2816*1024;
    tc.K = 1024; tc.N = MFF; tc.Kpad = 1024;
    trans_cvt2<<<dim3(32,88,2), 256, 0, stream>>>(tc);
    GluArgs gl;
    gl.Ah = actH; gl.Al = actL;
    gl.GH = gH; gl.GL = gL; gl.UH = uH; gl.UL = uL;
    gl.bg = bg; gl.bu = bu; gl.scaleBase = scaleArr + 4;
    gl.hH = hH; gl.hL = hL;
    gemm_glu<<<dim3(43,32), 256, 0, stream>>>(gl);
  }

  // ---- down GEMM + residual -> out ----
  {
    ushort_t* bpL = poolH + (size_t)1024*MFFP;
    TCArgs tc; tc.src0 = wd; tc.src1 = wd;
    tc.dh = poolH; tc.dl = bpL; tc.zoff = 0;
    tc.K = MFF; tc.N = 1024; tc.Kpad = MFFP;
    trans_cvt2<<<dim3(86,32,1), 256, 0, stream>>>(tc);
    ga.Ah = hH; ga.Al = hL; ga.Bh = poolH; ga.Bl = bpL;
    ga.C = out; ga.bias0 = bd;
    ga.dH0 = ga.dL0 = nullptr;
    ga.scaleBase = scaleArr + 6; ga.resid = x2;
    ga.Kd = MFFP; ga.matN = 1024; ga.bpm = 16; ga.rowsPerMat = 1024;
    ga.Cstride = 1024; ga.colOff = 0;
    gemm_bf3<2,0><<<dim3(16,32), 256, 0, stream>>>(ga);
  }
}

// Round 7
// 833.373 us; speedup vs baseline: 4.3944x; 1.0733x over previous
//
#include <hip/hip_runtime.h>
#include <hip/hip_fp16.h>
#include <math.h>
#include <stddef.h>
#include <stdint.h>

// Problem constants
#define BB   4
#define SS   1024
#define DD   1024
#define HH   16
#define HDD  64
#define NT   (BB*SS)      // 4096 tokens
#define MFF  2736
#define MFFP 2752
#define EPSF 1e-6f

typedef unsigned int   u32;
typedef unsigned short ushort_t;
typedef float    f32x4   __attribute__((ext_vector_type(4)));
typedef float    f32x16  __attribute__((ext_vector_type(16)));
typedef short    s16x8   __attribute__((ext_vector_type(8)));
typedef _Float16 h16x8   __attribute__((ext_vector_type(8)));

typedef const __attribute__((address_space(1))) u32 glb_u32;
typedef __attribute__((address_space(3))) u32 lds_u32;

// ---------------------------------------------------------------------------
// Workspace layout (float units) — IDENTICAL to round 6 (passed liveness audit).
//   x2  [0,        4194304)   steps 6-9
//   vt  [4194304,  8388608)   steps 4-5
//   qh/kh [8388608,16777216)  steps 3-5   (bf1 overlay in power phase)
//   o   [16777216, 20971520)  steps 5-6
//   h   [8388608,  19660800)  steps 8-9   (qh/kh + o regions, both dead)
//   act [26607616, 30801920)  steps 2-4, 7-8
//   pool[30801920, 36569088)  per-GEMM weights (now single-fp16: max 2.88M fl)
//   vv/uu/scale [36569088+)   power phase only
// ---------------------------------------------------------------------------
static const size_t OFF_X2    = 0;
static const size_t OFF_VT    = 4194304;
static const size_t OFF_QH    = 8388608;
static const size_t OFF_O     = 16777216;
static const size_t OFF_H     = 8388608;
static const size_t OFF_ACT   = 26607616;
static const size_t OFF_POOL  = 30801920;
static const size_t OFF_VV    = 36569088;
static const size_t OFF_UU    = 36588240;
static const size_t OFF_SCALE = 36607392;

// ---------------------------------------------------------------------------
// bf16 helpers (attention internals + power iteration)
__device__ inline ushort_t f2bf(float x){
  u32 u = __float_as_uint(x);
  u32 r = (u + 0x7fffu + ((u >> 16) & 1u)) >> 16;
  return (ushort_t)r;
}
__device__ inline void split_bf(float x, ushort_t& hi, ushort_t& lo){
  hi = f2bf(x);
  float hf = __uint_as_float(((u32)hi) << 16);
  lo = f2bf(x - hf);
}
__device__ inline float bf2f(ushort_t u){
  return __uint_as_float(((u32)u) << 16);
}
// fp16 helpers (linear-GEMM operands)
__device__ inline ushort_t f2h(float x){
  __half h = __float2half(x);
  return *reinterpret_cast<ushort_t*>(&h);
}
__device__ inline float h2f(ushort_t u){
  __half h;
  *reinterpret_cast<ushort_t*>(&h) = u;
  return __half2float(h);
}
__device__ inline void split_h(float x, ushort_t& hi, ushort_t& lo){
  hi = f2h(x);
  lo = f2h(x - h2f(hi));
}
__device__ inline s16x8 mk8(u32 a, u32 b, u32 c, u32 d){
  union { u32 w[4]; s16x8 v; } u;
  u.w[0]=a; u.w[1]=b; u.w[2]=c; u.w[3]=d;
  return u.v;
}

__device__ inline float block_sum256(float v, float* red){
  #pragma unroll
  for (int off=32; off>=1; off>>=1) v += __shfl_down(v, off);
  int lane = threadIdx.x & 63, wave = threadIdx.x >> 6;
  if (lane == 0) red[wave] = v;
  __syncthreads();
  return red[0]+red[1]+red[2]+red[3];
}

// XCD-aware bijective block swizzle (T1): each XCD gets a contiguous chunk of
// tiles in column-major order so B-panels stay L2-resident. nwg%8==0 for all
// our grids; identity fallback otherwise. Pure permutation — correctness-safe.
__device__ inline void xcd_swz(int nbx, int nby, int& bx, int& by){
  int nwg = nbx * nby;
  if (nwg & 7){ bx = blockIdx.x; by = blockIdx.y; return; }
  int lin = blockIdx.x + blockIdx.y * nbx;
  int q = nwg >> 3;
  int wg = (lin & 7) * q + (lin >> 3);
  bx = wg / nby;
  by = wg - bx*nby;
}

// ---------------------------------------------------------------------------
// Weight -> bf16 convert for power iteration (unchanged)
// ---------------------------------------------------------------------------
struct W2Args { const float* W[7]; ushort_t* dst; };
__global__ __launch_bounds__(256) void w2bf(W2Args a){
  const int BST[8] = {0,512,1024,1536,2048,3416,4784,6152};
  const size_t OFFU[7] = {0,1048576,2097152,3145728,4194304,6995968,9797632};
  int blk = blockIdx.x; int m = 0;
  #pragma unroll
  for (int i=1;i<7;i++) if (blk >= BST[i]) m = i;
  size_t e = (size_t)(blk - BST[m])*2048 + threadIdx.x*8;
  const float* src = a.W[m] + e;
  float4 v0 = *(const float4*)src;
  float4 v1 = *(const float4*)(src + 4);
  union { ushort_t o[8]; s16x8 v; } u;
  u.o[0]=f2bf(v0.x); u.o[1]=f2bf(v0.y); u.o[2]=f2bf(v0.z); u.o[3]=f2bf(v0.w);
  u.o[4]=f2bf(v1.x); u.o[5]=f2bf(v1.y); u.o[6]=f2bf(v1.z); u.o[7]=f2bf(v1.w);
  *(s16x8*)(a.dst + OFFU[m] + e) = u.v;
}

// ---------------------------------------------------------------------------
// Power iteration on bf16 weights (unchanged from round 6)
// ---------------------------------------------------------------------------
struct PowArgs {
  const ushort_t* Wb;
  float* vvec; float* uvec; int step;
};

__global__ __launch_bounds__(256) void zero_uvec(float* uvec){
  int m = blockIdx.x;
  for (int i=threadIdx.x; i<2736; i+=256) uvec[m*2736+i] = 0.f;
}

__global__ __launch_bounds__(256) void mv_notrans(PowArgs pa){
  const int NIN [7] = {1024,1024,1024,1024,1024,1024,2736};
  const int NOUT[7] = {1024,1024,1024,1024,2736,2736,1024};
  const int BST [8] = {0,256,512,768,1024,1280,1536,2220};
  const size_t OFFU[7] = {0,1048576,2097152,3145728,4194304,6995968,9797632};
  __shared__ float red[4];
  int blk = blockIdx.x;
  int m = 0;
  #pragma unroll
  for (int i=1;i<7;i++) if (blk >= BST[i]) m = i;
  int nin = NIN[m], nout = NOUT[m];
  int st = pa.step;
  float inv;
  const float* x = pa.uvec + m*2736;
  if (st == 0){
    inv = 1.f/(sqrtf((float)nout)+EPSF);
  } else {
    float s = 0.f;
    for (int i=threadIdx.x; i<nout; i+=256){ float u = x[i]; s += u*u; }
    float tot = block_sum256(s, red);
    inv = 1.f/(sqrtf(tot)+EPSF);
  }
  int wave = threadIdx.x >> 6, lane = threadIdx.x & 63;
  int row = (blk - BST[m])*4 + wave;
  if (row >= nin) return;
  const ushort_t* W = pa.Wb + OFFU[m];
  float sum = 0.f;
  if (st == 0){
    for (int j=lane*8; j<nout; j+=512){
      s16x8 w8 = *(const s16x8*)(W + (size_t)row*nout + j);
      #pragma unroll
      for (int e=0;e<8;e++) sum += bf2f((ushort_t)w8[e]);
    }
  } else {
    for (int j=lane*8; j<nout; j+=512){
      s16x8 w8 = *(const s16x8*)(W + (size_t)row*nout + j);
      float4 xa = *(const float4*)(x + j);
      float4 xb = *(const float4*)(x + j + 4);
      sum += bf2f((ushort_t)w8[0])*xa.x + bf2f((ushort_t)w8[1])*xa.y
           + bf2f((ushort_t)w8[2])*xa.z + bf2f((ushort_t)w8[3])*xa.w
           + bf2f((ushort_t)w8[4])*xb.x + bf2f((ushort_t)w8[5])*xb.y
           + bf2f((ushort_t)w8[6])*xb.z + bf2f((ushort_t)w8[7])*xb.w;
    }
  }
  #pragma unroll
  for (int off=32; off>=1; off>>=1) sum += __shfl_down(sum, off);
  if (lane == 0) pa.vvec[m*2736+row] = sum*inv;
}

__global__ __launch_bounds__(256) void mv_trans(PowArgs pa){
  const int NIN [7] = {1024,1024,1024,1024,1024,1024,2736};
  const int NOUT[7] = {1024,1024,1024,1024,2736,2736,1024};
  const int BST [8] = {0,32,64,96,128,216,304,392};
  const int RCH [7] = {8,8,8,8,8,8,22};
  const size_t OFFU[7] = {0,1048576,2097152,3145728,4194304,6995968,9797632};
  __shared__ float red[4];
  int blk = blockIdx.x;
  int m = 0;
  #pragma unroll
  for (int i=1;i<7;i++) if (blk >= BST[i]) m = i;
  int nin = NIN[m], nout = NOUT[m];
  const float* v = pa.vvec + m*2736;
  float s = 0.f;
  for (int i=threadIdx.x; i<nin; i+=256){ float t = v[i]; s += t*t; }
  float tot = block_sum256(s, red);
  float inv = 1.f/(sqrtf(tot)+EPSF);
  int local = blk - BST[m];
  int ct = local / RCH[m], rc = local % RCH[m];
  int col = ct*256 + threadIdx.x;
  int r0 = rc*128, r1 = min(nin, r0+128);
  if (col >= nout) return;
  const ushort_t* W = pa.Wb + OFFU[m];
  float partial = 0.f;
  for (int r=r0; r<r1; ++r)
    partial += bf2f(W[(size_t)r*nout + col])*(v[r]*inv);
  atomicAdd(&pa.uvec[m*2736+col], partial);
}

struct SigArgs {
  const float* vvec; float* scale;
  const float* sp[7];
};
__global__ __launch_bounds__(256) void sigma_scale_kernel(SigArgs sa){
  const int NIN [7] = {1024,1024,1024,1024,1024,1024,2736};
  __shared__ float red[4];
  int m = blockIdx.x;
  const float* v = sa.vvec + m*2736;
  float s = 0.f;
  for (int i=threadIdx.x; i<NIN[m]; i+=256){ float t = v[i]; s += t*t; }
  float a = block_sum256(s, red);
  if (threadIdx.x == 0){
    float S = sqrtf(a);
    float sig = a/(S+EPSF);
    sig = fmaxf(sig, EPSF);
    sa.scale[m] = sa.sp[m][0]/sig;
  }
}

// ---------------------------------------------------------------------------
// Transpose + convert: src fp32 [K][N] -> dst SINGLE fp16 [n][k], zero-padded.
// Two sources via blockIdx.z (dst offset z*zoff u16 elements).
// ---------------------------------------------------------------------------
struct TCArgs {
  const float* src0; const float* src1;
  ushort_t* dh;
  size_t zoff; int K; int N; int Kpad;
};
__global__ __launch_bounds__(256) void trans_cvt2(TCArgs a){
  __shared__ float t[32][33];
  const float* src = blockIdx.z ? a.src1 : a.src0;
  ushort_t* dh = a.dh + blockIdx.z*a.zoff;
  int k0 = blockIdx.x*32, n0 = blockIdx.y*32;
  int c = threadIdx.x & 31, rb = threadIdx.x >> 5;
  #pragma unroll
  for (int i=0;i<4;i++){
    int r = rb + i*8;
    int kk = k0 + r, nn = n0 + c;
    t[r][c] = (kk<a.K && nn<a.N) ? src[(size_t)kk*a.N + nn] : 0.f;
  }
  __syncthreads();
  #pragma unroll
  for (int i=0;i<4;i++){
    int r = rb + i*8;
    int nn = n0 + r, kk = k0 + c;
    dh[(size_t)nn*a.Kpad + kk] = f2h(t[c][r]);
  }
}

// ---------------------------------------------------------------------------
// RMSNorm over D=1024 -> fp16 hi/lo
// ---------------------------------------------------------------------------
__global__ __launch_bounds__(256) void rms_cvt(const float* __restrict__ in,
                                               const float* __restrict__ scale,
                                               ushort_t* __restrict__ oh,
                                               ushort_t* __restrict__ ol){
  int row = blockIdx.x;
  int tid = threadIdx.x;
  const float* p = in + (size_t)row*DD;
  float4 vx = *(const float4*)(p + tid*4);
  float ss = vx.x*vx.x + vx.y*vx.y + vx.z*vx.z + vx.w*vx.w;
  int lane = tid & 63, wave = tid >> 6;
  #pragma unroll
  for (int off=32; off>=1; off>>=1) ss += __shfl_down(ss, off);
  __shared__ float red[4];
  if (lane == 0) red[wave] = ss;
  __syncthreads();
  float tot = red[0]+red[1]+red[2]+red[3];
  float r = rsqrtf(tot*(1.f/DD)+EPSF);
  float4 sc = *(const float4*)(scale + tid*4);
  float o0 = vx.x*r*sc.x, o1 = vx.y*r*sc.y, o2 = vx.z*r*sc.z, o3 = vx.w*r*sc.w;
  ushort_t h[4], l[4];
  split_h(o0,h[0],l[0]); split_h(o1,h[1],l[1]);
  split_h(o2,h[2],l[2]); split_h(o3,h[3],l[3]);
  size_t o = (size_t)row*DD + tid*4;
  oh[o+0]=h[0]; oh[o+1]=h[1]; oh[o+2]=h[2]; oh[o+3]=h[3];
  ol[o+0]=l[0]; ol[o+1]=l[1]; ol[o+2]=l[2]; ol[o+3]=l[3];
}

// ---------------------------------------------------------------------------
// fp16 2-term split MFMA GEMM, double-buffered LDS prefetch + XCD swizzle.
//  A-side split (hi/lo fp16) x single-fp16 B   : acc += Ah*B + Al*B   (EPI 0/1)
//  EPI 2 (VT): A single-fp16 weight, B split   : acc += A*Bh + A*Bl
//  EPI 0: C fp32 = s*(A@B^T) + bias0[col] (+resid)
//  EPI 1: QK fused per-head RMSNorm -> BF16 hi/lo head-major (2 mats, attn input)
//  EPI 2: VT: BF16 hi/lo out at [row][col], bias0 per ROW (attn input)
// ---------------------------------------------------------------------------
struct GemmArgs {
  const ushort_t *Ah, *Al, *Bh, *Bl;
  float* C;
  const float *bias0, *bias1;
  const float *nrm0, *nrm1;
  ushort_t *dH0, *dL0, *dH1, *dL1;
  const float* scaleBase;
  const float* resid;
  int Kd, matN, bpm, rowsPerMat, Cstride, colOff;
};

template<int FN, int EPI>
__global__ __launch_bounds__(256) void gemm_h(GemmArgs g){
  constexpr bool BSPLIT = (EPI == 2);
  constexpr int BN    = FN*32;
  constexpr int SEGB  = BN/16;                  // 1KB segments per B buffer
  constexpr int SEGA  = BSPLIT ? 8 : 16;
  constexpr int NBB   = BSPLIT ? 2*SEGB : SEGB;
  constexpr int NSEG  = SEGA + NBB;
  constexpr int NSEGT = NSEG/4;
  constexpr int ABYTES = SEGA*1024;
  constexpr int HALF  = ABYTES + NBB*1024;
  __shared__ __align__(16) char lds[2*HALF];

  const int tid = threadIdx.x;
  const int w = tid >> 6, l = tid & 63;
  int bxs, bys;
  xcd_swz(gridDim.x, gridDim.y, bxs, bys);
  const int bm = bys*128;
  const int mat = bxs / g.bpm;
  const int n0m = (bxs % g.bpm) * BN;
  const int nrow0 = mat*g.rowsPerMat + n0m;

  const ushort_t* sp[NSEGT];
  u32 loff[NSEGT];
  #pragma unroll
  for (int i=0;i<NSEGT;i++){
    int s = w + i*4;
    int ci, r, c, csrc;
    if (s < SEGA){
      int abuf, segi;
      if (BSPLIT){ abuf = 0; segi = s; }
      else       { abuf = s >> 3; segi = s & 7; }
      ci = segi*64 + l; r = ci >> 2; c = ci & 3;
      csrc = c ^ ((r >> 1) & 3);
      sp[i] = (abuf ? g.Al : g.Ah) + (size_t)(bm + r)*g.Kd + csrc*8;
      loff[i] = (u32)(abuf*8192 + ci*16);
    } else {
      int tt = s - SEGA;
      int bbuf, segi;
      if (BSPLIT){ bbuf = tt / SEGB; segi = tt % SEGB; }
      else       { bbuf = 0; segi = tt; }
      ci = segi*64 + l; r = ci >> 2; c = ci & 3;
      csrc = c ^ ((r >> 1) & 3);
      sp[i] = (bbuf ? g.Bl : g.Bh) + (size_t)(nrow0 + r)*g.Kd + csrc*8;
      loff[i] = (u32)(ABYTES + bbuf*(BN*64) + ci*16);
    }
  }

  const int wm = w >> 1, wn = w & 1;
  const int li = l & 15, kq = l >> 4;
  const int sx = kq ^ ((li >> 1) & 3);
  const u32 aOff = (u32)((wm*64 + li)*64 + sx*16);
  const u32 bOff = (u32)(ABYTES + (wn*(FN*16) + li)*64 + sx*16);

  f32x4 acc[4][FN];
  #pragma unroll
  for (int mi=0;mi<4;mi++)
    #pragma unroll
    for (int ni=0;ni<FN;ni++)
      acc[mi][ni] = (f32x4){0.f,0.f,0.f,0.f};

  const int nt = g.Kd >> 5;
  #pragma unroll
  for (int i=0;i<NSEGT;i++){
    __builtin_amdgcn_global_load_lds((glb_u32*)sp[i], (lds_u32*)(lds + loff[i]), 16, 0, 0);
    sp[i] += 32;
  }
  __syncthreads();

  for (int t=0; t<nt; t++){
    if (t+1 < nt){
      char* sb = lds + ((t+1)&1)*HALF;
      #pragma unroll
      for (int i=0;i<NSEGT;i++){
        __builtin_amdgcn_global_load_lds((glb_u32*)sp[i], (lds_u32*)(sb + loff[i]), 16, 0, 0);
        sp[i] += 32;
      }
    }
    const char* lb = lds + (t&1)*HALF;
    if (!BSPLIT){
      h16x8 ah[4], al[4];
      #pragma unroll
      for (int mi=0;mi<4;mi++){
        ah[mi] = *(const h16x8*)(lb + aOff + mi*1024);
        al[mi] = *(const h16x8*)(lb + 8192 + aOff + mi*1024);
      }
      #pragma unroll
      for (int ni=0;ni<FN;ni++){
        h16x8 bh = *(const h16x8*)(lb + bOff + ni*1024);
        #pragma unroll
        for (int mi=0;mi<4;mi++){
          f32x4 tacc = acc[mi][ni];
          tacc = __builtin_amdgcn_mfma_f32_16x16x32_f16(ah[mi], bh, tacc, 0, 0, 0);
          tacc = __builtin_amdgcn_mfma_f32_16x16x32_f16(al[mi], bh, tacc, 0, 0, 0);
          acc[mi][ni] = tacc;
        }
      }
    } else {
      h16x8 ah[4];
      #pragma unroll
      for (int mi=0;mi<4;mi++)
        ah[mi] = *(const h16x8*)(lb + aOff + mi*1024);
      #pragma unroll
      for (int ni=0;ni<FN;ni++){
        h16x8 bh = *(const h16x8*)(lb + bOff + ni*1024);
        h16x8 bl = *(const h16x8*)(lb + BN*64 + bOff + ni*1024);
        #pragma unroll
        for (int mi=0;mi<4;mi++){
          f32x4 tacc = acc[mi][ni];
          tacc = __builtin_amdgcn_mfma_f32_16x16x32_f16(ah[mi], bh, tacc, 0, 0, 0);
          tacc = __builtin_amdgcn_mfma_f32_16x16x32_f16(ah[mi], bl, tacc, 0, 0, 0);
          acc[mi][ni] = tacc;
        }
      }
    }
    __syncthreads();
  }

  if constexpr (EPI == 0){
    const float s = g.scaleBase[mat];
    const float* bias = g.bias0;
    const int colBase = n0m + wn*(FN*16);
    #pragma unroll
    for (int ni=0;ni<FN;ni++){
      int cm = colBase + ni*16 + li;
      if (cm < g.matN){
        int cg = cm + g.colOff;
        float bv = bias[cm];
        #pragma unroll
        for (int mi=0;mi<4;mi++){
          f32x4 a = acc[mi][ni];
          int r0 = bm + wm*64 + mi*16 + kq*4;
          #pragma unroll
          for (int j=0;j<4;j++){
            float v = s*a[j] + bv;
            size_t off = (size_t)(r0+j)*g.Cstride + cg;
            if (g.resid) v += g.resid[off];
            g.C[off] = v;
          }
        }
      }
    }
  } else if constexpr (EPI == 1){
    const float s = g.scaleBase[mat];
    const float* bias = mat ? g.bias1 : g.bias0;
    const float* nsc  = mat ? g.nrm1  : g.nrm0;
    ushort_t* dH = mat ? g.dH1 : g.dH0;
    ushort_t* dL = mat ? g.dL1 : g.dL0;
    const int hidx = (n0m >> 6) + wn;
    float bv[FN], nv[FN];
    #pragma unroll
    for (int ni=0;ni<FN;ni++){
      int cm = n0m + wn*64 + ni*16 + li;
      bv[ni] = bias[cm];
      nv[ni] = nsc[ni*16 + li];
    }
    #pragma unroll
    for (int mi=0;mi<4;mi++){
      #pragma unroll
      for (int j=0;j<4;j++){
        float vv[FN]; float ssq = 0.f;
        #pragma unroll
        for (int ni=0;ni<FN;ni++){
          vv[ni] = s*acc[mi][ni][j] + bv[ni];
          ssq += vv[ni]*vv[ni];
        }
        ssq += __shfl_xor(ssq, 1);
        ssq += __shfl_xor(ssq, 2);
        ssq += __shfl_xor(ssq, 4);
        ssq += __shfl_xor(ssq, 8);
        float rr = rsqrtf(ssq*(1.f/64.f)+EPSF);
        int row = bm + wm*64 + mi*16 + kq*4 + j;
        size_t base = (((size_t)(row>>10)*16 + hidx)*1024 + (row & 1023))*64;
        #pragma unroll
        for (int ni=0;ni<FN;ni++){
          ushort_t hi, lo; split_bf(vv[ni]*rr*nv[ni], hi, lo);
          dH[base + ni*16 + li] = hi;
          dL[base + ni*16 + li] = lo;
        }
      }
    }
  } else {
    const float s = g.scaleBase[0];
    #pragma unroll
    for (int mi=0;mi<4;mi++){
      #pragma unroll
      for (int j=0;j<4;j++){
        int row = bm + wm*64 + mi*16 + kq*4 + j;
        float bvr = g.bias0[row];
        #pragma unroll
        for (int ni=0;ni<FN;ni++){
          int cm = n0m + wn*(FN*16) + ni*16 + li;
          float v = s*acc[mi][ni][j] + bvr;
          ushort_t hi, lo; split_bf(v, hi, lo);
          g.dH0[(size_t)row*4096 + cm] = hi;
          g.dL0[(size_t)row*4096 + cm] = lo;
        }
      }
    }
  }
}

// ---------------------------------------------------------------------------
// Fused gate+up GEMM (fp16 2-term) with in-register SiLU -> h fp16 hi/lo.
// A split fp16 (act); G,U single fp16. LDS/half: A 16K | G 4K | U 4K = 24K.
// ---------------------------------------------------------------------------
struct GluArgs {
  const ushort_t *Ah, *Al;
  const ushort_t *GH, *UH;            // transposed [2816][1024] each, fp16
  const float *bg, *bu;
  const float* scaleBase;             // [0]=sg, [1]=su
  ushort_t *hH, *hL;
};

__global__ __launch_bounds__(256) void gemm_glu(GluArgs g){
  constexpr int HALF = 24576;
  __shared__ __align__(16) char lds[2*HALF];
  const int tid = threadIdx.x;
  const int w = tid >> 6, l = tid & 63;
  int bxs, bys;
  xcd_swz(gridDim.x, gridDim.y, bxs, bys);
  const int bm = bys*128;
  const int n0 = bxs*64;

  const ushort_t* sp[6];
  u32 loff[6];
  #pragma unroll
  for (int i=0;i<6;i++){
    int s = w + i*4;
    if (s < 16){
      int abuf = s >> 3, segi = s & 7;
      int ci = segi*64 + l, r = ci >> 2, c = ci & 3;
      int csrc = c ^ ((r >> 1) & 3);
      sp[i] = (abuf ? g.Al : g.Ah) + (size_t)(bm + r)*1024 + csrc*8;
      loff[i] = (u32)(abuf*8192 + ci*16);
    } else {
      int tt = s - 16;                 // 0..7
      int msel = tt >> 2;              // 0:G 1:U
      int segi = tt & 3;
      int ci = segi*64 + l, r = ci >> 2, c = ci & 3;
      int csrc = c ^ ((r >> 1) & 3);
      const ushort_t* base = msel ? g.UH : g.GH;
      sp[i] = base + (size_t)(n0 + r)*1024 + csrc*8;
      loff[i] = (u32)(16384 + msel*4096 + ci*16);
    }
  }

  const int wm = w >> 1, wn = w & 1;
  const int li = l & 15, kq = l >> 4;
  const int sx = kq ^ ((li >> 1) & 3);
  const u32 aOff = (u32)((wm*64 + li)*64 + sx*16);
  const u32 bOff = (u32)(16384 + (wn*32 + li)*64 + sx*16);

  f32x4 accG[4][2], accU[4][2];
  #pragma unroll
  for (int mi=0;mi<4;mi++)
    #pragma unroll
    for (int ni=0;ni<2;ni++){
      accG[mi][ni] = (f32x4){0.f,0.f,0.f,0.f};
      accU[mi][ni] = (f32x4){0.f,0.f,0.f,0.f};
    }

  #pragma unroll
  for (int i=0;i<6;i++){
    __builtin_amdgcn_global_load_lds((glb_u32*)sp[i], (lds_u32*)(lds + loff[i]), 16, 0, 0);
    sp[i] += 32;
  }
  __syncthreads();

  for (int t=0; t<32; t++){
    if (t+1 < 32){
      char* sb = lds + ((t+1)&1)*HALF;
      #pragma unroll
      for (int i=0;i<6;i++){
        __builtin_amdgcn_global_load_lds((glb_u32*)sp[i], (lds_u32*)(sb + loff[i]), 16, 0, 0);
        sp[i] += 32;
      }
    }
    const char* lb = lds + (t&1)*HALF;
    h16x8 ah[4], al[4];
    #pragma unroll
    for (int mi=0;mi<4;mi++){
      ah[mi] = *(const h16x8*)(lb + aOff + mi*1024);
      al[mi] = *(const h16x8*)(lb + 8192 + aOff + mi*1024);
    }
    #pragma unroll
    for (int ni=0;ni<2;ni++){
      h16x8 gh = *(const h16x8*)(lb + bOff + ni*1024);
      h16x8 uh = *(const h16x8*)(lb + 4096 + bOff + ni*1024);
      #pragma unroll
      for (int mi=0;mi<4;mi++){
        f32x4 tg = accG[mi][ni];
        tg = __builtin_amdgcn_mfma_f32_16x16x32_f16(ah[mi], gh, tg, 0, 0, 0);
        tg = __builtin_amdgcn_mfma_f32_16x16x32_f16(al[mi], gh, tg, 0, 0, 0);
        accG[mi][ni] = tg;
        f32x4 tu = accU[mi][ni];
        tu = __builtin_amdgcn_mfma_f32_16x16x32_f16(ah[mi], uh, tu, 0, 0, 0);
        tu = __builtin_amdgcn_mfma_f32_16x16x32_f16(al[mi], uh, tu, 0, 0, 0);
        accU[mi][ni] = tu;
      }
    }
    __syncthreads();
  }

  const float sG = g.scaleBase[0], sU = g.scaleBase[1];
  #pragma unroll
  for (int ni=0;ni<2;ni++){
    int cm = n0 + wn*32 + ni*16 + li;
    bool ok = cm < MFF;
    float bgv = ok ? g.bg[cm] : 0.f;
    float buv = ok ? g.bu[cm] : 0.f;
    #pragma unroll
    for (int mi=0;mi<4;mi++){
      #pragma unroll
      for (int j=0;j<4;j++){
        int row = bm + wm*64 + mi*16 + kq*4 + j;
        ushort_t hb = 0, lb2 = 0;
        if (ok){
          float gv = sG*accG[mi][ni][j] + bgv;
          float uv = sU*accU[mi][ni][j] + buv;
          float hv = gv * __builtin_amdgcn_rcpf(1.f + __expf(-gv)) * uv;
          split_h(hv, hb, lb2);
        }
        size_t ho = (size_t)row*MFFP + cm;
        g.hH[ho] = hb; g.hL[ho] = lb2;
      }
    }
  }
}

// ---------------------------------------------------------------------------
// MFMA flash attention, in-register P (swapped-operand QK^T). bf16 internals
// unchanged; output split -> fp16 hi/lo (wo GEMM operand). + T5 setprio.
// ---------------------------------------------------------------------------
__global__ __launch_bounds__(256) void attn_mfma(const ushort_t* __restrict__ qh, const ushort_t* __restrict__ ql,
                                                 const ushort_t* __restrict__ kh, const ushort_t* __restrict__ kl,
                                                 const ushort_t* __restrict__ vh, const ushort_t* __restrict__ vl,
                                                 ushort_t* __restrict__ oh, ushort_t* __restrict__ ol){
  __shared__ __align__(16) char lds[74240];
  const int qt = blockIdx.x, h = blockIdx.y, b = blockIdx.z;
  const int tid = threadIdx.x;
  const int l = tid & 63, li = tid & 31, hi = (tid >> 5) & 1;
  const int w = tid >> 6, qhalf = w >> 1, khalf = w & 1;
  const int r0 = tid >> 3, ch = tid & 7;

  const size_t qrow = ((size_t)(b*HH + h)*SS + qt*64 + qhalf*32 + li)*64;
  s16x8 aQh[4], aQl[4];
  #pragma unroll
  for (int ks=0; ks<4; ks++){
    aQh[ks] = *(const s16x8*)(qh + qrow + ks*16 + hi*8);
    aQl[ks] = *(const s16x8*)(ql + qrow + ks*16 + hi*8);
  }

  const size_t kbase = (size_t)(b*HH + h)*SS*64;
  const size_t vbase = (size_t)h*64*4096 + (size_t)b*SS;

  f32x16 accO0 = (f32x16){0,0,0,0,0,0,0,0,0,0,0,0,0,0,0,0};
  f32x16 accO1 = (f32x16){0,0,0,0,0,0,0,0,0,0,0,0,0,0,0,0};
  float psum = 0.f;

  s16x8 rKh0,rKh1,rKl0,rKl1,rVh0,rVh1,rVl0,rVl1;
  rKh0 = *(const s16x8*)(kh + kbase + (size_t)r0*64 + ch*8);
  rKh1 = *(const s16x8*)(kh + kbase + (size_t)(r0+32)*64 + ch*8);
  rKl0 = *(const s16x8*)(kl + kbase + (size_t)r0*64 + ch*8);
  rKl1 = *(const s16x8*)(kl + kbase + (size_t)(r0+32)*64 + ch*8);
  rVh0 = *(const s16x8*)(vh + vbase + (size_t)r0*4096 + ch*8);
  rVh1 = *(const s16x8*)(vh + vbase + (size_t)(r0+32)*4096 + ch*8);
  rVl0 = *(const s16x8*)(vl + vbase + (size_t)r0*4096 + ch*8);
  rVl1 = *(const s16x8*)(vl + vbase + (size_t)(r0+32)*4096 + ch*8);
  {
    char* Kb = lds;  char* Vb = lds + 36864;
    *(s16x8*)(Kb + r0*144 + ch*16) = rKh0;
    *(s16x8*)(Kb + (r0+32)*144 + ch*16) = rKh1;
    *(s16x8*)(Kb + 9216 + r0*144 + ch*16) = rKl0;
    *(s16x8*)(Kb + 9216 + (r0+32)*144 + ch*16) = rKl1;
    *(s16x8*)(Vb + r0*144 + ch*16) = rVh0;
    *(s16x8*)(Vb + (r0+32)*144 + ch*16) = rVh1;
    *(s16x8*)(Vb + 9216 + r0*144 + ch*16) = rVl0;
    *(s16x8*)(Vb + 9216 + (r0+32)*144 + ch*16) = rVl1;
  }
  __syncthreads();

  int cur = 0;
  for (int kt=0; kt<16; kt++){
    if (kt < 15){
      const size_t kb = kbase + (size_t)(kt+1)*64*64;
      const size_t vb = vbase + (size_t)(kt+1)*64;
      rKh0 = *(const s16x8*)(kh + kb + (size_t)r0*64 + ch*8);
      rKh1 = *(const s16x8*)(kh + kb + (size_t)(r0+32)*64 + ch*8);
      rKl0 = *(const s16x8*)(kl + kb + (size_t)r0*64 + ch*8);
      rKl1 = *(const s16x8*)(kl + kb + (size_t)(r0+32)*64 + ch*8);
      rVh0 = *(const s16x8*)(vh + vb + (size_t)r0*4096 + ch*8);
      rVh1 = *(const s16x8*)(vh + vb + (size_t)(r0+32)*4096 + ch*8);
      rVl0 = *(const s16x8*)(vl + vb + (size_t)r0*4096 + ch*8);
      rVl1 = *(const s16x8*)(vl + vb + (size_t)(r0+32)*4096 + ch*8);
    }
    const char* Kc = lds + cur*18432;
    const char* Vc = lds + 36864 + cur*18432;

    f32x16 sF = (f32x16){0,0,0,0,0,0,0,0,0,0,0,0,0,0,0,0};
    __builtin_amdgcn_s_setprio(1);
    #pragma unroll
    for (int ks=0; ks<4; ks++){
      s16x8 kfh = *(const s16x8*)(Kc + (khalf*32+li)*144 + ks*32 + hi*16);
      s16x8 kfl = *(const s16x8*)(Kc + 9216 + (khalf*32+li)*144 + ks*32 + hi*16);
      sF = __builtin_amdgcn_mfma_f32_32x32x16_bf16(kfh, aQh[ks], sF, 0, 0, 0);
      sF = __builtin_amdgcn_mfma_f32_32x32x16_bf16(kfl, aQh[ks], sF, 0, 0, 0);
      sF = __builtin_amdgcn_mfma_f32_32x32x16_bf16(kfh, aQl[ks], sF, 0, 0, 0);
    }
    __builtin_amdgcn_s_setprio(0);

    float p[16];
    #pragma unroll
    for (int r=0; r<16; r++){
      float wv = __expf(sF[r]*0.005f);
      float rc = __builtin_amdgcn_rcpf(wv + 1.f);
      float pv = __expf(-100.f*rc);
      p[r] = pv;
      psum += pv;
    }

    u32 cH[8], cL[8];
    #pragma unroll
    for (int m=0; m<4; m++){
      u32 u0 = __float_as_uint(p[4*m+0]), u1 = __float_as_uint(p[4*m+1]);
      u32 u2 = __float_as_uint(p[4*m+2]), u3 = __float_as_uint(p[4*m+3]);
      u32 m0 = u0 & 0xffff0000u, m1 = u1 & 0xffff0000u;
      u32 m2 = u2 & 0xffff0000u, m3 = u3 & 0xffff0000u;
      cH[2*m+0] = m1 | (m0 >> 16);
      cH[2*m+1] = m3 | (m2 >> 16);
      u32 k0 = __float_as_uint(p[4*m+0] - __uint_as_float(m0));
      u32 k1 = __float_as_uint(p[4*m+1] - __uint_as_float(m1));
      u32 k2 = __float_as_uint(p[4*m+2] - __uint_as_float(m2));
      u32 k3 = __float_as_uint(p[4*m+3] - __uint_as_float(m3));
      cL[2*m+0] = (k1 & 0xffff0000u) | (k0 >> 16);
      cL[2*m+1] = (k3 & 0xffff0000u) | (k2 >> 16);
    }

    __builtin_amdgcn_s_setprio(1);
    #pragma unroll
    for (int ks2=0; ks2<2; ks2++){
      u32 A0 = cH[4*ks2+0], A1 = cH[4*ks2+1], B0 = cH[4*ks2+2], B1 = cH[4*ks2+3];
      u32 As0 = (u32)__shfl_xor((int)A0, 32), As1 = (u32)__shfl_xor((int)A1, 32);
      u32 Bs0 = (u32)__shfl_xor((int)B0, 32), Bs1 = (u32)__shfl_xor((int)B1, 32);
      s16x8 paH = mk8(hi ? Bs0 : A0, hi ? Bs1 : A1, hi ? B0 : As0, hi ? B1 : As1);
      u32 C0 = cL[4*ks2+0], C1 = cL[4*ks2+1], D0 = cL[4*ks2+2], D1 = cL[4*ks2+3];
      u32 Cs0 = (u32)__shfl_xor((int)C0, 32), Cs1 = (u32)__shfl_xor((int)C1, 32);
      u32 Ds0 = (u32)__shfl_xor((int)D0, 32), Ds1 = (u32)__shfl_xor((int)D1, 32);
      s16x8 paL = mk8(hi ? Ds0 : C0, hi ? Ds1 : C1, hi ? D0 : Cs0, hi ? D1 : Cs1);

      {
        const char* vp = Vc + (0*32+li)*144 + khalf*64 + ks2*32 + hi*16;
        s16x8 vfh = *(const s16x8*)vp;
        s16x8 vfl = *(const s16x8*)(vp + 9216);
        accO0 = __builtin_amdgcn_mfma_f32_32x32x16_bf16(paH, vfh, accO0, 0, 0, 0);
        accO0 = __builtin_amdgcn_mfma_f32_32x32x16_bf16(paH, vfl, accO0, 0, 0, 0);
        accO0 = __builtin_amdgcn_mfma_f32_32x32x16_bf16(paL, vfh, accO0, 0, 0, 0);
      }
      {
        const char* vp = Vc + (32+li)*144 + khalf*64 + ks2*32 + hi*16;
        s16x8 vfh = *(const s16x8*)vp;
        s16x8 vfl = *(const s16x8*)(vp + 9216);
        accO1 = __builtin_amdgcn_mfma_f32_32x32x16_bf16(paH, vfh, accO1, 0, 0, 0);
        accO1 = __builtin_amdgcn_mfma_f32_32x32x16_bf16(paH, vfl, accO1, 0, 0, 0);
        accO1 = __builtin_amdgcn_mfma_f32_32x32x16_bf16(paL, vfh, accO1, 0, 0, 0);
      }
    }
    __builtin_amdgcn_s_setprio(0);

    __syncthreads();
    if (kt < 15){
      char* Kb = lds + (cur^1)*18432;
      char* Vb = lds + 36864 + (cur^1)*18432;
      *(s16x8*)(Kb + r0*144 + ch*16) = rKh0;
      *(s16x8*)(Kb + (r0+32)*144 + ch*16) = rKh1;
      *(s16x8*)(Kb + 9216 + r0*144 + ch*16) = rKl0;
      *(s16x8*)(Kb + 9216 + (r0+32)*144 + ch*16) = rKl1;
      *(s16x8*)(Vb + r0*144 + ch*16) = rVh0;
      *(s16x8*)(Vb + (r0+32)*144 + ch*16) = rVh1;
      *(s16x8*)(Vb + 9216 + r0*144 + ch*16) = rVl0;
      *(s16x8*)(Vb + 9216 + (r0+32)*144 + ch*16) = rVl1;
      __syncthreads();
      cur ^= 1;
    }
  }

  float tot = psum + __shfl_xor(psum, 32);
  float* smA = (float*)(lds + 73728);
  float* smB = smA + 64;
  float* ex  = (float*)lds;
  if (khalf == 1 && hi == 0) smA[qhalf*32 + li] = tot;
  __syncthreads();
  if (khalf == 0 && hi == 0) smB[qhalf*32 + li] = tot + smA[qhalf*32 + li];
  if (khalf == 1){
    #pragma unroll
    for (int reg=0; reg<16; reg++){
      ex[qhalf*2048 + reg*64 + l]        = accO0[reg];
      ex[qhalf*2048 + (16+reg)*64 + l]   = accO1[reg];
    }
  }
  __syncthreads();
  if (khalf == 0){
    #pragma unroll
    for (int reg=0; reg<16; reg++){
      int qr = qhalf*32 + (reg&3) + 8*(reg>>2) + 4*hi;
      float inv = __builtin_amdgcn_rcpf(smB[qr]);
      float o0 = (accO0[reg] + ex[qhalf*2048 + reg*64 + l]) * inv;
      float o1 = (accO1[reg] + ex[qhalf*2048 + (16+reg)*64 + l]) * inv;
      size_t obase = ((size_t)(b*SS + qt*64 + qr))*1024 + h*64;
      ushort_t hb, lb2;
      split_h(o0, hb, lb2); oh[obase + li] = hb;      ol[obase + li] = lb2;
      split_h(o1, hb, lb2); oh[obase + 32 + li] = hb; ol[obase + 32 + li] = lb2;
    }
  }
}

// ---------------------------------------------------------------------------
extern "C" void kernel_launch(void* const* d_in, const int* in_sizes, int n_in,
                              void* d_out, int out_size, void* d_ws, size_t ws_size,
                              hipStream_t stream) {
  const float* x   = (const float*)d_in[0];
  const float* ln1 = (const float*)d_in[1];
  const float* wq  = (const float*)d_in[2];
  const float* sq  = (const float*)d_in[3];
  const float* bq  = (const float*)d_in[4];
  const float* wk  = (const float*)d_in[5];
  const float* sk  = (const float*)d_in[6];
  const float* bk  = (const float*)d_in[7];
  const float* wv  = (const float*)d_in[8];
  const float* sv  = (const float*)d_in[9];
  const float* bv  = (const float*)d_in[10];
  const float* qn  = (const float*)d_in[11];
  const float* kn  = (const float*)d_in[12];
  const float* wo  = (const float*)d_in[13];
  const float* so  = (const float*)d_in[14];
  const float* bo  = (const float*)d_in[15];
  const float* ln2 = (const float*)d_in[16];
  const float* wg  = (const float*)d_in[17];
  const float* sg  = (const float*)d_in[18];
  const float* bg  = (const float*)d_in[19];
  const float* wu  = (const float*)d_in[20];
  const float* su  = (const float*)d_in[21];
  const float* bu  = (const float*)d_in[22];
  const float* wd  = (const float*)d_in[23];
  const float* sd  = (const float*)d_in[24];
  const float* bd  = (const float*)d_in[25];

  float* ws  = (float*)d_ws;
  float* out = (float*)d_out;

  float* x2   = ws + OFF_X2;
  ushort_t* vtH = (ushort_t*)(ws + OFF_VT);
  ushort_t* vtL = vtH + (size_t)1024*4096;
  ushort_t* qhH = (ushort_t*)(ws + OFF_QH);
  ushort_t* qhL = qhH + (size_t)NT*1024;
  ushort_t* khH = qhH + (size_t)2*NT*1024;
  ushort_t* khL = qhH + (size_t)3*NT*1024;
  ushort_t* bf1 = (ushort_t*)(ws + OFF_QH);   // power phase only
  ushort_t* oH  = (ushort_t*)(ws + OFF_O);
  ushort_t* oL  = oH + (size_t)NT*1024;
  ushort_t* hH  = (ushort_t*)(ws + OFF_H);    // overlays qh/kh+o (dead at step 8)
  ushort_t* hL  = hH + (size_t)NT*MFFP;
  ushort_t* actH = (ushort_t*)(ws + OFF_ACT);
  ushort_t* actL = actH + (size_t)NT*1024;
  ushort_t* poolH = (ushort_t*)(ws + OFF_POOL);
  float* scaleArr = ws + OFF_SCALE;

  // ---- spectral sigma (bf16 power iteration, unchanged) ----
  {
    W2Args wa;
    wa.W[0]=wq; wa.W[1]=wk; wa.W[2]=wv; wa.W[3]=wo; wa.W[4]=wg; wa.W[5]=wu; wa.W[6]=wd;
    wa.dst = bf1;
    w2bf<<<6152, 256, 0, stream>>>(wa);
  }
  PowArgs pa;
  pa.Wb = bf1;
  pa.vvec = ws + OFF_VV; pa.uvec = ws + OFF_UU;
  for (int s=0; s<11; s++){
    pa.step = s;
    if ((s & 1) == 0){
      mv_notrans<<<2220, 256, 0, stream>>>(pa);
    } else {
      zero_uvec<<<7, 256, 0, stream>>>(pa.uvec);
      mv_trans<<<392, 256, 0, stream>>>(pa);
    }
  }
  SigArgs sa;
  sa.vvec = pa.vvec; sa.scale = scaleArr;
  sa.sp[0]=sq; sa.sp[1]=sk; sa.sp[2]=sv; sa.sp[3]=so; sa.sp[4]=sg; sa.sp[5]=su; sa.sp[6]=sd;
  sigma_scale_kernel<<<7, 256, 0, stream>>>(sa);

  // ---- attn_in = RMSNorm(x) -> fp16 hi/lo ----
  rms_cvt<<<NT, 256, 0, stream>>>(x, ln1, actH, actL);

  GemmArgs ga;
  ga.resid = nullptr; ga.C = nullptr; ga.bias1 = nullptr;
  ga.nrm0 = ga.nrm1 = nullptr;
  ga.dH0 = ga.dL0 = ga.dH1 = ga.dL1 = nullptr;
  ga.Bl = nullptr; ga.Al = nullptr;

  // ---- QK GEMM (fp16 2-term) with fused per-head RMSNorm -> bf16 ----
  {
    TCArgs tc; tc.src0 = wq; tc.src1 = wk;
    tc.dh = poolH; tc.zoff = (size_t)1024*1024;
    tc.K = 1024; tc.N = 1024; tc.Kpad = 1024;
    trans_cvt2<<<dim3(32,32,2), 256, 0, stream>>>(tc);
    ga.Ah = actH; ga.Al = actL; ga.Bh = poolH; ga.Bl = nullptr;
    ga.bias0 = bq; ga.bias1 = bk; ga.nrm0 = qn; ga.nrm1 = kn;
    ga.dH0 = qhH; ga.dL0 = qhL; ga.dH1 = khH; ga.dL1 = khL;
    ga.scaleBase = scaleArr + 0;
    ga.Kd = 1024; ga.matN = 1024; ga.bpm = 8; ga.rowsPerMat = 1024;
    ga.Cstride = 0; ga.colOff = 0;
    gemm_h<4,1><<<dim3(16,32), 256, 0, stream>>>(ga);
  }

  // ---- V^T GEMM (A = wv single fp16, B = act split) -> bf16 [vdim][token] ----
  {
    TCArgs tc; tc.src0 = wv; tc.src1 = wv;
    tc.dh = poolH; tc.zoff = 0;
    tc.K = 1024; tc.N = 1024; tc.Kpad = 1024;
    trans_cvt2<<<dim3(32,32,1), 256, 0, stream>>>(tc);
    ga.Ah = poolH; ga.Al = nullptr; ga.Bh = actH; ga.Bl = actL;
    ga.bias0 = bv; ga.bias1 = nullptr; ga.nrm0 = ga.nrm1 = nullptr;
    ga.dH0 = vtH; ga.dL0 = vtL; ga.dH1 = ga.dL1 = nullptr;
    ga.scaleBase = scaleArr + 2;
    ga.Kd = 1024; ga.matN = 4096; ga.bpm = 64; ga.rowsPerMat = 4096;
    ga.Cstride = 0; ga.colOff = 0;
    gemm_h<2,2><<<dim3(64,8), 256, 0, stream>>>(ga);
  }

  // ---- attention (bf16 internals, fp16 output) ----
  attn_mfma<<<dim3(16,16,4), 256, 0, stream>>>(qhH, qhL, khH, khL, vtH, vtL, oH, oL);

  // ---- out projection + residual ----
  {
    TCArgs tc; tc.src0 = wo; tc.src1 = wo;
    tc.dh = poolH; tc.zoff = 0;
    tc.K = 1024; tc.N = 1024; tc.Kpad = 1024;
    trans_cvt2<<<dim3(32,32,1), 256, 0, stream>>>(tc);
    ga.Ah = oH; ga.Al = oL; ga.Bh = poolH; ga.Bl = nullptr;
    ga.C = x2; ga.bias0 = bo;
    ga.dH0 = ga.dL0 = nullptr;
    ga.scaleBase = scaleArr + 3; ga.resid = x;
    ga.Kd = 1024; ga.matN = 1024; ga.bpm = 16; ga.rowsPerMat = 1024;
    ga.Cstride = 1024; ga.colOff = 0;
    gemm_h<2,0><<<dim3(16,32), 256, 0, stream>>>(ga);
  }

  // ---- mlp_in = RMSNorm(x2) -> fp16 hi/lo ----
  rms_cvt<<<NT, 256, 0, stream>>>(x2, ln2, actH, actL);

  // ---- fused gate+up+SiLU GEMM -> h fp16 hi/lo ----
  {
    ushort_t* gH = poolH;
    ushort_t* uH = poolH + (size_t)2816*1024;
    TCArgs tc; tc.src0 = wg; tc.src1 = wu;
    tc.dh = gH; tc.zoff = (size_t)2816*1024;
    tc.K = 1024; tc.N = MFF; tc.Kpad = 1024;
    trans_cvt2<<<dim3(32,88,2), 256, 0, stream>>>(tc);
    GluArgs gl;
    gl.Ah = actH; gl.Al = actL;
    gl.GH = gH; gl.UH = uH;
    gl.bg = bg; gl.bu = bu; gl.scaleBase = scaleArr + 4;
    gl.hH = hH; gl.hL = hL;
    gemm_glu<<<dim3(43,32), 256, 0, stream>>>(gl);
  }

  // ---- down GEMM + residual -> out ----
  {
    TCArgs tc; tc.src0 = wd; tc.src1 = wd;
    tc.dh = poolH; tc.zoff = 0;
    tc.K = MFF; tc.N = 1024; tc.Kpad = MFFP;
    trans_cvt2<<<dim3(86,32,1), 256, 0, stream>>>(tc);
    ga.Ah = hH; ga.Al = hL; ga.Bh = poolH; ga.Bl = nullptr;
    ga.C = out; ga.bias0 = bd;
    ga.dH0 = ga.dL0 = nullptr;
    ga.scaleBase = scaleArr + 6; ga.resid = x2;
    ga.Kd = MFFP; ga.matN = 1024; ga.bpm = 16; ga.rowsPerMat = 1024;
    ga.Cstride = 1024; ga.colOff = 0;
    gemm_h<2,0><<<dim3(16,32), 256, 0, stream>>>(ga);
  }
}